// Round 7
// baseline (1082.864 us; speedup 1.0000x reference)
//
#include <hip/hip_runtime.h>
#include <hip/hip_bf16.h>
#include <math.h>

#define EPSV 1e-10f
#define BNEPS 1e-5f
#define INV_SQRT2 0.70710678118654752440f

typedef __attribute__((ext_vector_type(8))) short short8;
typedef __attribute__((ext_vector_type(4))) float f32x4;

__device__ __forceinline__ float bf2f(unsigned short u) {
    union { unsigned int i; float f; } c; c.i = ((unsigned int)u) << 16; return c.f;
}
__device__ __forceinline__ unsigned short f2bf(float f) {
    unsigned int u = __float_as_uint(f);
    return (unsigned short)((u + 0x7FFFu + ((u >> 16) & 1u)) >> 16);
}
// packed bf16 square using v_cvt_pk_bf16_f32 (gfx950): ~20 insts vs ~56
__device__ __forceinline__ short8 sq8(short8 v) {
    short8 r;
    unsigned int* vp = (unsigned int*)&v;
    unsigned int* rp = (unsigned int*)&r;
#pragma unroll
    for (int e = 0; e < 4; e++) {
        unsigned int u = vp[e];
        float lo = __uint_as_float(u << 16);
        float hi = __uint_as_float(u & 0xffff0000u);
        unsigned int o;
        asm("v_cvt_pk_bf16_f32 %0, %1, %2" : "=v"(o) : "v"(lo * lo), "v"(hi * hi));
        rp[e] = o;
    }
    return r;
}

// ---------------------------------------------------------------------------
// L1 weight prep
// ---------------------------------------------------------------------------
__global__ void prep_w(const float* __restrict__ a, const float* __restrict__ b,
                       float* __restrict__ WA, float* __restrict__ WB, int n) {
    for (int i = blockIdx.x * blockDim.x + threadIdx.x; i < n; i += gridDim.x * blockDim.x) {
        float p0 = 1.f / (1.f + expf(-a[i]));
        float sb = 1.f / (1.f + expf(-b[i]));
        float p1 = (1.f - p0) * sb;
        float ew = 2.f * p1 - (1.f - p0);
        float ew2 = 1.f - p0;
        WA[i] = ew;
        WB[i] = ew2 - ew * ew;
    }
}

// ---------------------------------------------------------------------------
// Pack ternary-stat weights into MFMA A-fragment order (bf16).
// ---------------------------------------------------------------------------
__global__ void prep_pack(const float* __restrict__ a, const float* __restrict__ b,
                          unsigned short* __restrict__ pk, int Ci, int Co, int ver2, int total) {
    int idx = blockIdx.x * 256 + threadIdx.x;
    if (idx >= total) return;
    int lane = idx & 63;
    int MFg = Co >> 4, NCH = Ci >> 5;
    int mfch = idx >> 6;
    int mf = mfch % MFg;
    int chpos = mfch / MFg;
    int ch = chpos % NCH;
    int pos = chpos / NCH;
    int co = mf * 16 + (lane & 15);
    int cib = ch * 32 + (lane >> 4) * 8;
    unsigned int wa[4], wb[4];
#pragma unroll
    for (int j = 0; j < 8; j++) {
        long s = ((long)co * Ci + cib + j) * 9 + pos;
        float p0 = 1.f / (1.f + expf(-a[s]));
        float sb = 1.f / (1.f + expf(-b[s]));
        float p1 = (1.f - p0) * sb;
        float ew = 2.f * p1 - (1.f - p0);
        float ew2 = 1.f - p0;
        unsigned int ha = f2bf(ew);
        unsigned int hb = f2bf(ver2 ? ew * ew : ew2 - ew * ew);
        if (j & 1) { wa[j >> 1] |= ha << 16; wb[j >> 1] |= hb << 16; }
        else       { wa[j >> 1] = ha;        wb[j >> 1] = hb; }
    }
    long b0 = (((long)(0 * 9 + pos) * NCH + ch) * MFg + mf) * 64 + lane;
    long b1 = (((long)(1 * 9 + pos) * NCH + ch) * MFg + mf) * 64 + lane;
    uint4 va; va.x = wa[0]; va.y = wa[1]; va.z = wa[2]; va.w = wa[3];
    uint4 vb; vb.x = wb[0]; vb.y = wb[1]; vb.z = wb[2]; vb.w = wb[3];
    *(uint4*)(pk + b0 * 8) = va;
    *(uint4*)(pk + b1 * 8) = vb;
}

// ssum[co][k] = sum_ci sigmoid(-alpha)
__global__ void prep_s(const float* __restrict__ alpha, float* __restrict__ s, int Ci) {
    int co = blockIdx.x;
    int lane = threadIdx.x;
    float acc[9];
#pragma unroll
    for (int k = 0; k < 9; k++) acc[k] = 0.f;
    for (int ci = lane; ci < Ci; ci += 64) {
        const float* p = alpha + ((long)co * Ci + ci) * 9;
#pragma unroll
        for (int k = 0; k < 9; k++) acc[k] += 1.f / (1.f + expf(p[k]));
    }
#pragma unroll
    for (int k = 0; k < 9; k++) {
        for (int off = 32; off > 0; off >>= 1) acc[k] += __shfl_down(acc[k], off);
    }
    if (lane == 0) {
#pragma unroll
        for (int k = 0; k < 9; k++) s[co * 9 + k] = acc[k];
    }
}

__global__ void prep_ones(const float* __restrict__ ssum, float* __restrict__ og,
                          int Co, int Hout, int Wout, int Hin, int Win, int stride, int total) {
    int idx = blockIdx.x * 256 + threadIdx.x;
    if (idx >= total) return;
    int x = idx % Wout, y = (idx / Wout) % Hout, co = idx / (Wout * Hout);
    float s = 0.f;
    for (int ky = 0; ky < 3; ky++) {
        int yi = stride * y - 1 + ky;
        if (yi < 0 || yi >= Hin) continue;
        for (int kx = 0; kx < 3; kx++) {
            int xi = stride * x - 1 + kx;
            if (xi < 0 || xi >= Win) continue;
            s += ssum[co * 9 + ky * 3 + kx];
        }
    }
    og[idx] = s;
}

// ---------------------------------------------------------------------------
// FC1 weight pack: fp32 [1024][8192] -> bf16 A-fragment order
// ---------------------------------------------------------------------------
__global__ void prep_fc1(const float* __restrict__ W, unsigned short* __restrict__ pk) {
    int idx = blockIdx.x * 256 + threadIdx.x;
    int lane = idx & 63;
    int mf = (idx >> 6) & 63;
    int kt = idx >> 12;
    int o = mf * 16 + (lane & 15);
    long k = (long)kt * 32 + (lane >> 4) * 8;
    const float* src = W + (long)o * 8192 + k;
    float4 f0 = *(const float4*)src;
    float4 f1 = *(const float4*)(src + 4);
    uint4 v;
    v.x = (unsigned)f2bf(f0.x) | ((unsigned)f2bf(f0.y) << 16);
    v.y = (unsigned)f2bf(f0.z) | ((unsigned)f2bf(f0.w) << 16);
    v.z = (unsigned)f2bf(f1.x) | ((unsigned)f2bf(f1.y) << 16);
    v.w = (unsigned)f2bf(f1.z) | ((unsigned)f2bf(f1.w) << 16);
    *(uint4*)(pk + (long)idx * 8) = v;
}

// ---------------------------------------------------------------------------
// L1: fp32 vector conv (Ci=3) -> erf -> NHWC bf16.
// ---------------------------------------------------------------------------
__global__ __launch_bounds__(256) void conv1_k(const float* __restrict__ x,
        const float* __restrict__ wa, const float* __restrict__ wb,
        const float* __restrict__ bias, unsigned short* __restrict__ out) {
    __shared__ float win[3 * 4 * 34];
    __shared__ float wl[128 * 56];
    int b = blockIdx.x >> 4;
    int y0 = (blockIdx.x & 15) * 2;
    int tid = threadIdx.x;
    for (int i = tid; i < 408; i += 256) {
        int ci = i / 136, r = (i % 136) / 34, px = i % 34;
        int yy = y0 - 1 + r, xx = px - 1;
        float v = 0.f;
        if (yy >= 0 && yy < 32 && xx >= 0 && xx < 32)
            v = x[((b * 3 + ci) * 32 + yy) * 32 + xx];
        win[i] = v;
    }
    for (int i = tid; i < 128 * 56; i += 256) {
        int co = i / 56, q = i % 56, j = q >> 1;
        float v = 0.f;
        if (j < 27) v = (q & 1) ? wb[co * 27 + j] : wa[co * 27 + j];
        wl[i] = v;
    }
    __syncthreads();
    int xo = tid & 31;
    int cog = tid >> 5;
    float iv[2][28], sq[2][28];
#pragma unroll
    for (int r = 0; r < 2; r++) {
#pragma unroll
        for (int ci = 0; ci < 3; ci++)
#pragma unroll
        for (int ky = 0; ky < 3; ky++)
#pragma unroll
        for (int kx = 0; kx < 3; kx++) {
            float v = win[(ci * 4 + r + ky) * 34 + xo + kx];
            iv[r][ci * 9 + ky * 3 + kx] = v;
            sq[r][ci * 9 + ky * 3 + kx] = v * v;
        }
        iv[r][27] = 0.f; sq[r][27] = 0.f;
    }
    unsigned int pk[2][8];
#pragma unroll
    for (int k = 0; k < 16; k++) {
        int co = cog * 16 + k;
        const float4* wp = (const float4*)&wl[co * 56];
        float bs = bias[co];
        float m0 = bs, v0 = 0.f, m1 = bs, v1 = 0.f;
#pragma unroll
        for (int q = 0; q < 14; q++) {
            float4 w4 = wp[q];
            m0 = fmaf(iv[0][2 * q], w4.x, m0);     v0 = fmaf(sq[0][2 * q], w4.y, v0);
            m0 = fmaf(iv[0][2 * q + 1], w4.z, m0); v0 = fmaf(sq[0][2 * q + 1], w4.w, v0);
            m1 = fmaf(iv[1][2 * q], w4.x, m1);     v1 = fmaf(sq[1][2 * q], w4.y, v1);
            m1 = fmaf(iv[1][2 * q + 1], w4.z, m1); v1 = fmaf(sq[1][2 * q + 1], w4.w, v1);
        }
        unsigned int h0 = f2bf(erff(m0 * rsqrtf(v0 + EPSV) * INV_SQRT2));
        unsigned int h1 = f2bf(erff(m1 * rsqrtf(v1 + EPSV) * INV_SQRT2));
        if (k & 1) { pk[0][k >> 1] |= h0 << 16; pk[1][k >> 1] |= h1 << 16; }
        else       { pk[0][k >> 1] = h0;        pk[1][k >> 1] = h1; }
    }
#pragma unroll
    for (int r = 0; r < 2; r++) {
        long oa = (((long)b * 32 + y0 + r) * 32 + xo) * 128 + cog * 16;
        uint4 u0; u0.x = pk[r][0]; u0.y = pk[r][1]; u0.z = pk[r][2]; u0.w = pk[r][3];
        uint4 u1; u1.x = pk[r][4]; u1.y = pk[r][5]; u1.z = pk[r][6]; u1.w = pk[r][7];
        *(uint4*)(out + oa) = u0;
        *(uint4*)(out + oa + 8) = u1;
    }
}

// ---------------------------------------------------------------------------
// MFMA implicit-GEMM fused LRnet conv. NHWC bf16 input. 512 thr (wm2 x wn4).
// MODE 0: lrconv  -> erf -> NHWC bf16   (v = convB)
// MODE 1: ver2    -> erf -> NHWC bf16   (v = ones - convB)
// MODE 3: ver2 + sample -> NHWC bf16    (out = m + sqrt(v+eps)*epsb)
// MODE 4: ver2 + sample -> NCHW bf16
// ---------------------------------------------------------------------------
template<int Ci, int Hin, int Win, int Co, int Hout, int Wout, int STRIDE,
         int ROWS, int IPB, int NTILE, int CHUNK, int MODE>
__global__ __launch_bounds__(512) void conv_mfma(
    const unsigned short* __restrict__ in,
    const unsigned short* __restrict__ wpk,
    const float* __restrict__ bias,
    const float* __restrict__ ones_g,
    const float* __restrict__ epsb,
    void* __restrict__ outp)
{
    constexpr int BLK = 512;
    constexpr int MTILE = 128;
    constexpr int PROWS = STRIDE * (ROWS - 1) + 3;
    constexpr int PW = Win + 2;
    constexpr int POS = IPB * PROWS * PW;
    constexpr int NCH32 = Ci / 32;
    constexpr int NCHL = Ci / CHUNK;
    constexpr int KS = CHUNK / 32;
    constexpr int MFg = Co / 16;
    constexpr int NF = NTILE / 16;
    constexpr int WMF = 4;
    constexpr int WNF = NF / 4;
    constexpr int CT = Co / MTILE;
    constexpr int RG = Hout / ROWS;
    constexpr int LINE = CHUNK * 2 + 16;
    constexpr int TSTR = MTILE + 8;
    constexpr int PASSN = (NTILE < 128) ? NTILE : 128;
    constexpr int NPASS = (MODE == 4) ? 0 : NTILE / PASSN;
    constexpr int STAGE_B = POS * LINE;
    constexpr int TR_B = (MODE == 4) ? 0 : PASSN * TSTR * 2;
    constexpr int LDS_B = STAGE_B > TR_B ? STAGE_B : TR_B;
    static_assert(8 % CT == 0, "ct swizzle");
    static_assert(WNF * 4 == NF, "wnf");
    static_assert(NCHL * CHUNK == Ci, "chunk");
    static_assert(LDS_B <= 65536, "lds");
    __shared__ char lds[LDS_B];

    const int tid = threadIdx.x;
    const int lane = tid & 63;
    const int wv = tid >> 6;
    const int wm = wv & 1, wn = wv >> 1;
    const int g = lane >> 4, ln = lane & 15;

    const int bid = blockIdx.x;
    const int xcd = bid & 7;
    constexpr int XPC = 8 / CT;
    const int ct = xcd % CT;
    const int nt = (bid >> 3) * XPC + xcd / CT;
    const int b0 = (nt / RG) * IPB;
    const int y0 = (nt % RG) * ROWS;

    int pbase[WNF];
#pragma unroll
    for (int nf = 0; nf < WNF; nf++) {
        int n = (wn * WNF + nf) * 16 + ln;
        int img = n / (ROWS * Wout);
        int rem = n % (ROWS * Wout);
        int yr = rem / Wout, xo = rem % Wout;
        pbase[nf] = (img * PROWS + STRIDE * yr) * PW + STRIDE * xo;
    }

    f32x4 accA[WMF][WNF], accB[WMF][WNF];
#pragma unroll
    for (int mf = 0; mf < WMF; mf++)
#pragma unroll
    for (int nf = 0; nf < WNF; nf++) {
        accA[mf][nf] = (f32x4){0.f, 0.f, 0.f, 0.f};
        accB[mf][nf] = (f32x4){0.f, 0.f, 0.f, 0.f};
    }

    const unsigned short* wbase = wpk + ((long)(ct * 8 + wm * WMF) * 64 + lane) * 8;

    for (int ch = 0; ch < NCHL; ch++) {
        // ---- stage CHUNK channels (bf16) into LDS ----
        for (int i = tid; i < POS * (CHUNK / 8); i += BLK) {
            int p = i / (CHUNK / 8), c = i % (CHUNK / 8);
            int img = p / (PROWS * PW);
            int r = p % (PROWS * PW);
            int prow = r / PW, px = r % PW;
            int yin = STRIDE * y0 - 1 + prow;
            int xin = px - 1;
            uint4 v; v.x = 0; v.y = 0; v.z = 0; v.w = 0;
            if (yin >= 0 && yin < Hin && xin >= 0 && xin < Win) {
                long a = (((long)(b0 + img) * Hin + yin) * Win + xin) * Ci + ch * CHUNK + c * 8;
                v = *(const uint4*)(in + a);
            }
            *(uint4*)(lds + p * LINE + c * 16) = v;
        }
        __syncthreads();
        // ---- 9 kernel positions x KS k-substeps ----
#pragma unroll 3
        for (int pos = 0; pos < 9; pos++) {
            const int ky = pos / 3, kx = pos % 3;
#pragma unroll
            for (int ks = 0; ks < KS; ks++) {
                const int ch32 = ch * KS + ks;
                short8 af[2][WMF];
#pragma unroll
                for (int cv = 0; cv < 2; cv++)
#pragma unroll
                for (int mf = 0; mf < WMF; mf++)
                    af[cv][mf] = *(const short8*)(wbase +
                        ((long)(((cv * 9 + pos) * NCH32 + ch32) * MFg + mf)) * 512);
#pragma unroll
                for (int nf = 0; nf < WNF; nf++) {
                    int po = (pbase[nf] + ky * PW + kx) * LINE + ks * 64 + g * 16;
                    short8 b1 = *(const short8*)(lds + po);
                    short8 b2 = sq8(b1);
#pragma unroll
                    for (int mf = 0; mf < WMF; mf++) {
                        accA[mf][nf] = __builtin_amdgcn_mfma_f32_16x16x32_bf16(af[0][mf], b1, accA[mf][nf], 0, 0, 0);
                        accB[mf][nf] = __builtin_amdgcn_mfma_f32_16x16x32_bf16(af[1][mf], b2, accB[mf][nf], 0, 0, 0);
                    }
                }
            }
        }
        __syncthreads();
    }

    // ---- epilogue ----
    if constexpr (MODE == 4) {
        unsigned short* out = (unsigned short*)outp;
#pragma unroll
        for (int mf = 0; mf < WMF; mf++) {
            int co = ct * MTILE + (wm * WMF + mf) * 16 + g * 4;
#pragma unroll
            for (int nf = 0; nf < WNF; nf++) {
                int n = (wn * WNF + nf) * 16 + ln;
                int img = n / (ROWS * Wout), rem = n % (ROWS * Wout);
                int y = y0 + rem / Wout, x = rem % Wout;
                int b = b0 + img;
#pragma unroll
                for (int r = 0; r < 4; r++) {
                    int c = co + r;
                    float m = accA[mf][nf][r] + bias[c];
                    float v = ones_g[(c * Hout + y) * Wout + x] - accB[mf][nf][r];
                    long oi = (((long)b * Co + c) * Hout + y) * Wout + x;
                    out[oi] = f2bf(m + sqrtf(v + EPSV) * epsb[oi]);
                }
            }
        }
    } else {
        unsigned short* out = (unsigned short*)outp;
#pragma unroll
        for (int pass = 0; pass < NPASS; pass++) {
            __syncthreads();
#pragma unroll
            for (int mf = 0; mf < WMF; mf++) {
                int cob = (wm * WMF + mf) * 16 + g * 4;
                int cg = ct * MTILE + cob;
#pragma unroll
                for (int nf = 0; nf < WNF; nf++) {
                    int nb = (wn * WNF + nf) * 16;
                    if (nb < pass * PASSN || nb >= (pass + 1) * PASSN) continue;
                    int n = nb + ln;
                    int img = n / (ROWS * Wout), rem = n % (ROWS * Wout);
                    int y = y0 + rem / Wout, x = rem % Wout;
                    int b = b0 + img;
                    unsigned int pk2[2];
#pragma unroll
                    for (int r = 0; r < 4; r++) {
                        int c = cg + r;
                        float m = accA[mf][nf][r] + bias[c];
                        float val;
                        if constexpr (MODE == 0) {
                            val = erff(m * rsqrtf(accB[mf][nf][r] + EPSV) * INV_SQRT2);
                        } else if constexpr (MODE == 1) {
                            float v = ones_g[(c * Hout + y) * Wout + x] - accB[mf][nf][r];
                            val = erff(m * rsqrtf(v + EPSV) * INV_SQRT2);
                        } else { // MODE 3
                            float v = ones_g[(c * Hout + y) * Wout + x] - accB[mf][nf][r];
                            float ev = epsb[(((long)b * Co + c) * Hout + y) * Wout + x];
                            val = m + sqrtf(v + EPSV) * ev;
                        }
                        unsigned int hv = f2bf(val);
                        if (r & 1) pk2[r >> 1] |= hv << 16; else pk2[r >> 1] = hv;
                    }
                    int nl = n - pass * PASSN;
                    *(unsigned int*)(lds + (nl * TSTR + cob) * 2) = pk2[0];
                    *(unsigned int*)(lds + (nl * TSTR + cob) * 2 + 4) = pk2[1];
                }
            }
            __syncthreads();
            for (int i = tid; i < PASSN * (MTILE / 8); i += BLK) {
                int nl = i / (MTILE / 8);
                int n = pass * PASSN + nl;
                int c8 = (i % (MTILE / 8)) * 8;
                int img = n / (ROWS * Wout), rem = n % (ROWS * Wout);
                int y = y0 + rem / Wout, x = rem % Wout;
                int b = b0 + img;
                uint4 val = *(const uint4*)(lds + (nl * TSTR + c8) * 2);
                long oa = (((long)b * Hout + y) * Wout + x) * Co + ct * MTILE + c8;
                *(uint4*)(out + oa) = val;
            }
        }
    }
}

// ---------------------------------------------------------------------------
// BatchNorm (bf16, partial-sum based, no atomics)
// ---------------------------------------------------------------------------
__global__ void bn_part_nhwc(const unsigned short* __restrict__ h, float* __restrict__ part,
                             int C, int rpc) {
    int c = threadIdx.x;
    long r0 = (long)blockIdx.x * rpc;
    float s = 0.f, s2 = 0.f;
    for (int r = 0; r < rpc; r++) {
        float v = bf2f(h[(r0 + r) * C + c]);
        s += v; s2 += v * v;
    }
    part[(long)blockIdx.x * 2 * C + c] = s;
    part[(long)blockIdx.x * 2 * C + C + c] = s2;
}

__global__ void bn_part_nchw(const unsigned short* __restrict__ h, float* __restrict__ part,
                             int ipc) {
    int c = threadIdx.x;
    int b0 = blockIdx.x * ipc;
    float s = 0.f, s2 = 0.f;
    for (int b = 0; b < ipc; b++) {
        const unsigned short* p = h + ((long)(b0 + b) * 512 + c) * 16;
        uint4 v0 = *(const uint4*)p;
        uint4 v1 = *(const uint4*)(p + 8);
        unsigned int* vp0 = (unsigned int*)&v0;
        unsigned int* vp1 = (unsigned int*)&v1;
#pragma unroll
        for (int e = 0; e < 4; e++) {
            float a = bf2f((unsigned short)(vp0[e] & 0xffffu)), bb = bf2f((unsigned short)(vp0[e] >> 16));
            float cc = bf2f((unsigned short)(vp1[e] & 0xffffu)), d = bf2f((unsigned short)(vp1[e] >> 16));
            s += a + bb + cc + d;
            s2 += a * a + bb * bb + cc * cc + d * d;
        }
    }
    part[(long)blockIdx.x * 1024 + c] = s;
    part[(long)blockIdx.x * 1024 + 512 + c] = s2;
}

__global__ void bn_fin(const float* __restrict__ part, const float* __restrict__ gamma,
                       const float* __restrict__ beta, float* __restrict__ sc,
                       float* __restrict__ sh, int C, int chunks, float invN) {
    int c = blockIdx.x * 256 + threadIdx.x;
    if (c >= C) return;
    float s = 0.f, s2 = 0.f;
    for (int j = 0; j < chunks; j++) {
        s += part[(long)j * 2 * C + c];
        s2 += part[(long)j * 2 * C + C + c];
    }
    float mean = s * invN;
    float var = s2 * invN - mean * mean;
    float k = gamma[c] * rsqrtf(var + BNEPS);
    sc[c] = k;
    sh[c] = beta[c] - mean * k;
}

__global__ void bn_app_nhwc(unsigned short* __restrict__ h, const float* __restrict__ sc,
                            const float* __restrict__ sh) {
    int i = blockIdx.x * 256 + threadIdx.x;   // 2097152 total
    int cb = (i & 31) * 8;
    uint4 v = *(uint4*)(h + (long)i * 8);
    float4 s0 = *(const float4*)(sc + cb), s1 = *(const float4*)(sc + cb + 4);
    float4 t0 = *(const float4*)(sh + cb), t1 = *(const float4*)(sh + cb + 4);
    float scl[8] = {s0.x, s0.y, s0.z, s0.w, s1.x, s1.y, s1.z, s1.w};
    float shf[8] = {t0.x, t0.y, t0.z, t0.w, t1.x, t1.y, t1.z, t1.w};
    unsigned int* vp = (unsigned int*)&v;
#pragma unroll
    for (int e = 0; e < 4; e++) {
        float lo = bf2f((unsigned short)(vp[e] & 0xffffu));
        float hi = bf2f((unsigned short)(vp[e] >> 16));
        lo = fmaf(lo, scl[2 * e], shf[2 * e]);     lo = lo > 0.f ? lo : 0.f;
        hi = fmaf(hi, scl[2 * e + 1], shf[2 * e + 1]); hi = hi > 0.f ? hi : 0.f;
        vp[e] = (unsigned int)f2bf(lo) | (((unsigned int)f2bf(hi)) << 16);
    }
    *(uint4*)(h + (long)i * 8) = v;
}

__global__ void bn_app_nchw(unsigned short* __restrict__ h, const float* __restrict__ sc,
                            const float* __restrict__ sh) {
    int i = blockIdx.x * 256 + threadIdx.x;   // 524288 total
    int c = (i >> 1) & 511;
    float k = sc[c], t = sh[c];
    uint4 v = *(uint4*)(h + (long)i * 8);
    unsigned int* vp = (unsigned int*)&v;
#pragma unroll
    for (int e = 0; e < 4; e++) {
        float lo = bf2f((unsigned short)(vp[e] & 0xffffu));
        float hi = bf2f((unsigned short)(vp[e] >> 16));
        lo = fmaf(lo, k, t); lo = lo > 0.f ? lo : 0.f;
        hi = fmaf(hi, k, t); hi = hi > 0.f ? hi : 0.f;
        vp[e] = (unsigned int)f2bf(lo) | (((unsigned int)f2bf(hi)) << 16);
    }
    *(uint4*)(h + (long)i * 8) = v;
}

// ---------------------------------------------------------------------------
// FC1 bf16 MFMA split-K + reduce
// ---------------------------------------------------------------------------
__global__ __launch_bounds__(256) void fc1_mfma(const unsigned short* __restrict__ Ab,
                                                const unsigned short* __restrict__ Wp,
                                                float* __restrict__ pbuf) {
    __shared__ char lds[2 * 64 * 80];
    const int tid = threadIdx.x;
    const int lane = tid & 63;
    const int wv = tid >> 6;
    const int g = lane >> 4, ln = lane & 15;
    const int ot = blockIdx.x, bt = blockIdx.y, s = blockIdx.z;
    const int b0 = bt * 64;
    const int k0g = s * 1024;

    f32x4 acc[2][4];
#pragma unroll
    for (int c = 0; c < 2; c++)
#pragma unroll
    for (int nf = 0; nf < 4; nf++) acc[c][nf] = (f32x4){0.f, 0.f, 0.f, 0.f};

    for (int k0 = 0; k0 < 1024; k0 += 64) {
        __syncthreads();
        for (int i = tid; i < 512; i += 256) {
            int row = i >> 3, kk = (i >> 2) & 1, seg = i & 3;
            uint4 v = *(const uint4*)(Ab + ((long)(b0 + row) * 8192 + k0g + k0 + kk * 32 + seg * 8));
            *(uint4*)(lds + (kk * 64 + row) * 80 + seg * 16) = v;
        }
        __syncthreads();
#pragma unroll
        for (int kk = 0; kk < 2; kk++) {
            int kt = (k0g + k0) / 32 + kk;
            short8 af[2];
#pragma unroll
            for (int c = 0; c < 2; c++) {
                int mf = ot * 8 + wv * 2 + c;
                af[c] = *(const short8*)(Wp + (((long)kt * 64 + mf) * 64 + lane) * 8);
            }
            short8 bf[4];
#pragma unroll
            for (int nf = 0; nf < 4; nf++)
                bf[nf] = *(const short8*)(lds + (kk * 64 + nf * 16 + ln) * 80 + g * 16);
#pragma unroll
            for (int c = 0; c < 2; c++)
#pragma unroll
            for (int nf = 0; nf < 4; nf++)
                acc[c][nf] = __builtin_amdgcn_mfma_f32_16x16x32_bf16(af[c], bf[nf], acc[c][nf], 0, 0, 0);
        }
    }
#pragma unroll
    for (int c = 0; c < 2; c++) {
        int o = ot * 128 + (wv * 2 + c) * 16 + g * 4;
#pragma unroll
        for (int nf = 0; nf < 4; nf++) {
            int b = b0 + nf * 16 + ln;
            *(f32x4*)(pbuf + ((long)s * 256 + b) * 1024 + o) = acc[c][nf];
        }
    }
}

__global__ void fc1_reduce(const float* __restrict__ pbuf, const float* __restrict__ bias,
                           float* __restrict__ out) {
    int idx = blockIdx.x * 256 + threadIdx.x;
    float s = 0.f;
#pragma unroll
    for (int j = 0; j < 8; j++) s += pbuf[(long)j * 262144 + idx];
    s += bias[idx & 1023];
    out[idx] = s > 0.f ? s : 0.f;
}

__global__ void fc2_k(const float* __restrict__ A, const float* __restrict__ W,
                      const float* __restrict__ b2, float* __restrict__ out) {
    int bb = blockIdx.x;
    int tid = threadIdx.x;
    float acc[10];
#pragma unroll
    for (int o = 0; o < 10; o++) acc[o] = 0.f;
    const float* arow = A + (long)bb * 1024;
    for (int k = tid; k < 1024; k += 256) {
        float a = arow[k];
#pragma unroll
        for (int o = 0; o < 10; o++) acc[o] = fmaf(a, W[o * 1024 + k], acc[o]);
    }
#pragma unroll
    for (int o = 0; o < 10; o++)
        for (int off = 32; off > 0; off >>= 1) acc[o] += __shfl_down(acc[o], off);
    __shared__ float red[10][4];
    int wid = tid >> 6, lane = tid & 63;
    if (lane == 0) {
#pragma unroll
        for (int o = 0; o < 10; o++) red[o][wid] = acc[o];
    }
    __syncthreads();
    if (tid < 10)
        out[bb * 10 + tid] = red[tid][0] + red[tid][1] + red[tid][2] + red[tid][3] + b2[tid];
}

// ---------------------------------------------------------------------------
extern "C" void kernel_launch(void* const* d_in, const int* in_sizes, int n_in,
                              void* d_out, int out_size, void* d_ws, size_t ws_size,
                              hipStream_t stream) {
    const float* x  = (const float*)d_in[0];
    const float* a1 = (const float*)d_in[1];  const float* b1 = (const float*)d_in[2];  const float* c1 = (const float*)d_in[3];
    const float* a2 = (const float*)d_in[4];  const float* b2 = (const float*)d_in[5];  const float* c2 = (const float*)d_in[6];
    const float* a3 = (const float*)d_in[7];  const float* b3 = (const float*)d_in[8];  const float* c3 = (const float*)d_in[9];
    const float* a4 = (const float*)d_in[10]; const float* b4 = (const float*)d_in[11]; const float* c4 = (const float*)d_in[12];
    const float* a5 = (const float*)d_in[13]; const float* b5 = (const float*)d_in[14]; const float* c5 = (const float*)d_in[15];
    const float* a6 = (const float*)d_in[16]; const float* b6 = (const float*)d_in[17]; const float* c6 = (const float*)d_in[18];
    const float* g3 = (const float*)d_in[19]; const float* be3 = (const float*)d_in[20];
    const float* g6 = (const float*)d_in[21]; const float* be6 = (const float*)d_in[22];
    const float* fc1w = (const float*)d_in[23]; const float* fc1b = (const float*)d_in[24];
    const float* fc2w = (const float*)d_in[25]; const float* fc2b = (const float*)d_in[26];
    const float* eps3 = (const float*)d_in[27]; const float* eps6 = (const float*)d_in[28];
    (void)in_sizes; (void)n_in; (void)out_size; (void)ws_size;

    float* w = (float*)d_ws;
    size_t off = 0;
    auto alloc = [&](size_t n) { float* p = w + off; off += n; return p; };
    unsigned short* pk2 = (unsigned short*)alloc(147456);
    unsigned short* pk3 = (unsigned short*)alloc(294912);
    unsigned short* pk4 = (unsigned short*)alloc(589824);
    unsigned short* pk5 = (unsigned short*)alloc(1179648);
    unsigned short* pk6 = (unsigned short*)alloc(2359296);
    float* wa1 = alloc(3456); float* wb1 = alloc(3456);
    float* ss2 = alloc(1152); float* ss3 = alloc(2304);
    float* ss5 = alloc(4608); float* ss6 = alloc(4608);
    float* og2 = alloc(32768); float* og3 = alloc(65536);
    float* og5 = alloc(32768); float* og6 = alloc(8192);
    float* part3 = alloc(131072);
    float* part6 = alloc(65536);
    float* sc3 = alloc(256); float* sh3 = alloc(256);
    float* sc6 = alloc(512); float* sh6 = alloc(512);
    float* A  = alloc(16777216);
    float* Bb = alloc(4194304);
    float* Cc = alloc(8388608);
    float* Dd = alloc(2097152);
    float* Ee = alloc(4194304);

    unsigned short* ex1 = (unsigned short*)A;
    unsigned short* pkF = (unsigned short*)A;
    float*          pbuf = A + 4194304;
    unsigned short* ex2 = (unsigned short*)Bb;
    float*          fco = Bb;
    unsigned short* h6b = (unsigned short*)(Bb + 524288);
    unsigned short* h3b = (unsigned short*)Cc;
    unsigned short* ex4 = (unsigned short*)Dd;
    unsigned short* ex5 = (unsigned short*)Ee;

    // ---- prep ----
    prep_w<<<14, 256, 0, stream>>>(a1, b1, wa1, wb1, 3456);
    prep_pack<<<72,  256, 0, stream>>>(a2, b2, pk2, 128, 128, 1, 18432);
    prep_pack<<<144, 256, 0, stream>>>(a3, b3, pk3, 128, 256, 1, 36864);
    prep_pack<<<288, 256, 0, stream>>>(a4, b4, pk4, 256, 256, 0, 73728);
    prep_pack<<<576, 256, 0, stream>>>(a5, b5, pk5, 256, 512, 1, 147456);
    prep_pack<<<1152,256, 0, stream>>>(a6, b6, pk6, 512, 512, 1, 294912);
    prep_s<<<128, 64, 0, stream>>>(a2, ss2, 128);
    prep_s<<<256, 64, 0, stream>>>(a3, ss3, 128);
    prep_s<<<512, 64, 0, stream>>>(a5, ss5, 256);
    prep_s<<<512, 64, 0, stream>>>(a6, ss6, 512);
    prep_ones<<<128, 256, 0, stream>>>(ss2, og2, 128, 16, 16, 32, 32, 2, 32768);
    prep_ones<<<256, 256, 0, stream>>>(ss3, og3, 256, 16, 16, 16, 16, 1, 65536);
    prep_ones<<<128, 256, 0, stream>>>(ss5, og5, 512, 8, 8, 8, 8, 1, 32768);
    prep_ones<<<32,  256, 0, stream>>>(ss6, og6, 512, 4, 4, 8, 8, 2, 8192);

    // ---- network ----
    conv1_k<<<4096, 256, 0, stream>>>(x, wa1, wb1, c1, ex1);
    // L2: [256,32,32,128] -> [256,16,16,128]
    conv_mfma<128,32,32,128,16,16,2, 8,1,128,32,1><<<512, 512, 0, stream>>>(ex1, pk2, c2, og2, nullptr, ex2);
    // L3: -> h3b [256,16,16,256] NHWC bf16 (sampled)
    conv_mfma<128,16,16,256,16,16,1, 8,2,256,64,3><<<512, 512, 0, stream>>>(ex2, pk3, c3, og3, eps3, h3b);
    // FC1 weight pack into A (ex1 dead after L2)
    prep_fc1<<<4096, 256, 0, stream>>>(fc1w, pkF);
    // BN3 (bf16 NHWC, in place)
    bn_part_nhwc<<<256, 256, 0, stream>>>(h3b, part3, 256, 256);
    bn_fin<<<1, 256, 0, stream>>>(part3, g3, be3, sc3, sh3, 256, 256, 1.f / 65536.f);
    bn_app_nhwc<<<8192, 256, 0, stream>>>(h3b, sc3, sh3);
    // L4: [256,16,16,256] -> [256,8,8,256]   grid 512
    conv_mfma<256,16,16,256, 8, 8,2, 8,1,64,64,0><<<512, 512, 0, stream>>>(h3b, pk4, c4, nullptr, nullptr, ex4);
    // L5: -> [256,8,8,512]                   grid 512
    conv_mfma<256, 8, 8,512, 8, 8,1, 8,2,128,64,1><<<512, 512, 0, stream>>>(ex4, pk5, c5, og5, nullptr, ex5);
    // L6: -> h6b [256,512,4,4] NCHW bf16 (sampled)  grid 256
    conv_mfma<512, 8, 8,512, 4, 4,2, 4,4,64,64,4><<<256, 512, 0, stream>>>(ex5, pk6, c6, og6, eps6, h6b);
    // BN6 (bf16 NCHW, in place)
    bn_part_nchw<<<64, 512, 0, stream>>>(h6b, part6, 4);
    bn_fin<<<2, 256, 0, stream>>>(part6, g6, be6, sc6, sh6, 512, 64, 1.f / 4096.f);
    bn_app_nchw<<<2048, 256, 0, stream>>>(h6b, sc6, sh6);
    // FC1 + FC2
    fc1_mfma<<<dim3(8, 4, 8), 256, 0, stream>>>(h6b, pkF, pbuf);
    fc1_reduce<<<1024, 256, 0, stream>>>(pbuf, fc1b, fco);
    fc2_k<<<256, 256, 0, stream>>>(fco, fc2w, fc2b, (float*)d_out);
}

// Round 8
// 976.085 us; speedup vs baseline: 1.1094x; 1.1094x over previous
//
#include <hip/hip_runtime.h>
#include <hip/hip_bf16.h>
#include <math.h>

#define EPSV 1e-10f
#define BNEPS 1e-5f
#define INV_SQRT2 0.70710678118654752440f

typedef __attribute__((ext_vector_type(8))) short short8;
typedef __attribute__((ext_vector_type(4))) float f32x4;

__device__ __forceinline__ float bf2f(unsigned short u) {
    union { unsigned int i; float f; } c; c.i = ((unsigned int)u) << 16; return c.f;
}
__device__ __forceinline__ unsigned short f2bf(float f) {
    unsigned int u = __float_as_uint(f);
    return (unsigned short)((u + 0x7FFFu + ((u >> 16) & 1u)) >> 16);
}
// packed bf16 square using v_cvt_pk_bf16_f32 (gfx950)
__device__ __forceinline__ short8 sq8(short8 v) {
    short8 r;
    unsigned int* vp = (unsigned int*)&v;
    unsigned int* rp = (unsigned int*)&r;
#pragma unroll
    for (int e = 0; e < 4; e++) {
        unsigned int u = vp[e];
        float lo = __uint_as_float(u << 16);
        float hi = __uint_as_float(u & 0xffff0000u);
        unsigned int o;
        asm("v_cvt_pk_bf16_f32 %0, %1, %2" : "=v"(o) : "v"(lo * lo), "v"(hi * hi));
        rp[e] = o;
    }
    return r;
}

// ---------------------------------------------------------------------------
// L1 weight prep
// ---------------------------------------------------------------------------
__global__ void prep_w(const float* __restrict__ a, const float* __restrict__ b,
                       float* __restrict__ WA, float* __restrict__ WB, int n) {
    for (int i = blockIdx.x * blockDim.x + threadIdx.x; i < n; i += gridDim.x * blockDim.x) {
        float p0 = 1.f / (1.f + expf(-a[i]));
        float sb = 1.f / (1.f + expf(-b[i]));
        float p1 = (1.f - p0) * sb;
        float ew = 2.f * p1 - (1.f - p0);
        float ew2 = 1.f - p0;
        WA[i] = ew;
        WB[i] = ew2 - ew * ew;
    }
}

// ---------------------------------------------------------------------------
// Pack ternary-stat weights into MFMA A-fragment order (bf16).
// ---------------------------------------------------------------------------
__global__ void prep_pack(const float* __restrict__ a, const float* __restrict__ b,
                          unsigned short* __restrict__ pk, int Ci, int Co, int ver2, int total) {
    int idx = blockIdx.x * 256 + threadIdx.x;
    if (idx >= total) return;
    int lane = idx & 63;
    int MFg = Co >> 4, NCH = Ci >> 5;
    int mfch = idx >> 6;
    int mf = mfch % MFg;
    int chpos = mfch / MFg;
    int ch = chpos % NCH;
    int pos = chpos / NCH;
    int co = mf * 16 + (lane & 15);
    int cib = ch * 32 + (lane >> 4) * 8;
    unsigned int wa[4], wb[4];
#pragma unroll
    for (int j = 0; j < 8; j++) {
        long s = ((long)co * Ci + cib + j) * 9 + pos;
        float p0 = 1.f / (1.f + expf(-a[s]));
        float sb = 1.f / (1.f + expf(-b[s]));
        float p1 = (1.f - p0) * sb;
        float ew = 2.f * p1 - (1.f - p0);
        float ew2 = 1.f - p0;
        unsigned int ha = f2bf(ew);
        unsigned int hb = f2bf(ver2 ? ew * ew : ew2 - ew * ew);
        if (j & 1) { wa[j >> 1] |= ha << 16; wb[j >> 1] |= hb << 16; }
        else       { wa[j >> 1] = ha;        wb[j >> 1] = hb; }
    }
    long b0 = (((long)(0 * 9 + pos) * NCH + ch) * MFg + mf) * 64 + lane;
    long b1 = (((long)(1 * 9 + pos) * NCH + ch) * MFg + mf) * 64 + lane;
    uint4 va; va.x = wa[0]; va.y = wa[1]; va.z = wa[2]; va.w = wa[3];
    uint4 vb; vb.x = wb[0]; vb.y = wb[1]; vb.z = wb[2]; vb.w = wb[3];
    *(uint4*)(pk + b0 * 8) = va;
    *(uint4*)(pk + b1 * 8) = vb;
}

// ssum[co][k] = sum_ci sigmoid(-alpha)
__global__ void prep_s(const float* __restrict__ alpha, float* __restrict__ s, int Ci) {
    int co = blockIdx.x;
    int lane = threadIdx.x;
    float acc[9];
#pragma unroll
    for (int k = 0; k < 9; k++) acc[k] = 0.f;
    for (int ci = lane; ci < Ci; ci += 64) {
        const float* p = alpha + ((long)co * Ci + ci) * 9;
#pragma unroll
        for (int k = 0; k < 9; k++) acc[k] += 1.f / (1.f + expf(p[k]));
    }
#pragma unroll
    for (int k = 0; k < 9; k++) {
        for (int off = 32; off > 0; off >>= 1) acc[k] += __shfl_down(acc[k], off);
    }
    if (lane == 0) {
#pragma unroll
        for (int k = 0; k < 9; k++) s[co * 9 + k] = acc[k];
    }
}

__global__ void prep_ones(const float* __restrict__ ssum, float* __restrict__ og,
                          int Co, int Hout, int Wout, int Hin, int Win, int stride, int total) {
    int idx = blockIdx.x * 256 + threadIdx.x;
    if (idx >= total) return;
    int x = idx % Wout, y = (idx / Wout) % Hout, co = idx / (Wout * Hout);
    float s = 0.f;
    for (int ky = 0; ky < 3; ky++) {
        int yi = stride * y - 1 + ky;
        if (yi < 0 || yi >= Hin) continue;
        for (int kx = 0; kx < 3; kx++) {
            int xi = stride * x - 1 + kx;
            if (xi < 0 || xi >= Win) continue;
            s += ssum[co * 9 + ky * 3 + kx];
        }
    }
    og[idx] = s;
}

// ---------------------------------------------------------------------------
// FC1 weight pack: fp32 [1024][8192] -> bf16 A-fragment order
// ---------------------------------------------------------------------------
__global__ void prep_fc1(const float* __restrict__ W, unsigned short* __restrict__ pk) {
    int idx = blockIdx.x * 256 + threadIdx.x;
    int lane = idx & 63;
    int mf = (idx >> 6) & 63;
    int kt = idx >> 12;
    int o = mf * 16 + (lane & 15);
    long k = (long)kt * 32 + (lane >> 4) * 8;
    const float* src = W + (long)o * 8192 + k;
    float4 f0 = *(const float4*)src;
    float4 f1 = *(const float4*)(src + 4);
    uint4 v;
    v.x = (unsigned)f2bf(f0.x) | ((unsigned)f2bf(f0.y) << 16);
    v.y = (unsigned)f2bf(f0.z) | ((unsigned)f2bf(f0.w) << 16);
    v.z = (unsigned)f2bf(f1.x) | ((unsigned)f2bf(f1.y) << 16);
    v.w = (unsigned)f2bf(f1.z) | ((unsigned)f2bf(f1.w) << 16);
    *(uint4*)(pk + (long)idx * 8) = v;
}

// ---------------------------------------------------------------------------
// L1: fp32 vector conv (Ci=3) -> erf -> NHWC bf16.
// ---------------------------------------------------------------------------
__global__ __launch_bounds__(256) void conv1_k(const float* __restrict__ x,
        const float* __restrict__ wa, const float* __restrict__ wb,
        const float* __restrict__ bias, unsigned short* __restrict__ out) {
    __shared__ float win[3 * 4 * 34];
    __shared__ float wl[128 * 56];
    int b = blockIdx.x >> 4;
    int y0 = (blockIdx.x & 15) * 2;
    int tid = threadIdx.x;
    for (int i = tid; i < 408; i += 256) {
        int ci = i / 136, r = (i % 136) / 34, px = i % 34;
        int yy = y0 - 1 + r, xx = px - 1;
        float v = 0.f;
        if (yy >= 0 && yy < 32 && xx >= 0 && xx < 32)
            v = x[((b * 3 + ci) * 32 + yy) * 32 + xx];
        win[i] = v;
    }
    for (int i = tid; i < 128 * 56; i += 256) {
        int co = i / 56, q = i % 56, j = q >> 1;
        float v = 0.f;
        if (j < 27) v = (q & 1) ? wb[co * 27 + j] : wa[co * 27 + j];
        wl[i] = v;
    }
    __syncthreads();
    int xo = tid & 31;
    int cog = tid >> 5;
    float iv[2][28], sq[2][28];
#pragma unroll
    for (int r = 0; r < 2; r++) {
#pragma unroll
        for (int ci = 0; ci < 3; ci++)
#pragma unroll
        for (int ky = 0; ky < 3; ky++)
#pragma unroll
        for (int kx = 0; kx < 3; kx++) {
            float v = win[(ci * 4 + r + ky) * 34 + xo + kx];
            iv[r][ci * 9 + ky * 3 + kx] = v;
            sq[r][ci * 9 + ky * 3 + kx] = v * v;
        }
        iv[r][27] = 0.f; sq[r][27] = 0.f;
    }
    unsigned int pk[2][8];
#pragma unroll
    for (int k = 0; k < 16; k++) {
        int co = cog * 16 + k;
        const float4* wp = (const float4*)&wl[co * 56];
        float bs = bias[co];
        float m0 = bs, v0 = 0.f, m1 = bs, v1 = 0.f;
#pragma unroll
        for (int q = 0; q < 14; q++) {
            float4 w4 = wp[q];
            m0 = fmaf(iv[0][2 * q], w4.x, m0);     v0 = fmaf(sq[0][2 * q], w4.y, v0);
            m0 = fmaf(iv[0][2 * q + 1], w4.z, m0); v0 = fmaf(sq[0][2 * q + 1], w4.w, v0);
            m1 = fmaf(iv[1][2 * q], w4.x, m1);     v1 = fmaf(sq[1][2 * q], w4.y, v1);
            m1 = fmaf(iv[1][2 * q + 1], w4.z, m1); v1 = fmaf(sq[1][2 * q + 1], w4.w, v1);
        }
        unsigned int h0 = f2bf(erff(m0 * rsqrtf(v0 + EPSV) * INV_SQRT2));
        unsigned int h1 = f2bf(erff(m1 * rsqrtf(v1 + EPSV) * INV_SQRT2));
        if (k & 1) { pk[0][k >> 1] |= h0 << 16; pk[1][k >> 1] |= h1 << 16; }
        else       { pk[0][k >> 1] = h0;        pk[1][k >> 1] = h1; }
    }
#pragma unroll
    for (int r = 0; r < 2; r++) {
        long oa = (((long)b * 32 + y0 + r) * 32 + xo) * 128 + cog * 16;
        uint4 u0; u0.x = pk[r][0]; u0.y = pk[r][1]; u0.z = pk[r][2]; u0.w = pk[r][3];
        uint4 u1; u1.x = pk[r][4]; u1.y = pk[r][5]; u1.z = pk[r][6]; u1.w = pk[r][7];
        *(uint4*)(out + oa) = u0;
        *(uint4*)(out + oa + 8) = u1;
    }
}

// ---------------------------------------------------------------------------
// MFMA implicit-GEMM fused LRnet conv. NHWC bf16 input. 512 thr (wm2 x wn4).
// MODE 0: lrconv  -> erf -> NHWC bf16   (v = convB)
// MODE 1: ver2    -> erf -> NHWC bf16   (v = ones - convB)
// MODE 3: ver2 + sample -> NHWC bf16    (out = m + sqrt(v+eps)*epsb)
// MODE 4: ver2 + sample -> NCHW bf16
// ---------------------------------------------------------------------------
template<int Ci, int Hin, int Win, int Co, int Hout, int Wout, int STRIDE,
         int ROWS, int IPB, int NTILE, int CHUNK, int MODE>
__global__ __launch_bounds__(512) void conv_mfma(
    const unsigned short* __restrict__ in,
    const unsigned short* __restrict__ wpk,
    const float* __restrict__ bias,
    const float* __restrict__ ones_g,
    const float* __restrict__ epsb,
    void* __restrict__ outp)
{
    constexpr int BLK = 512;
    constexpr int MTILE = 128;
    constexpr int PROWS = STRIDE * (ROWS - 1) + 3;
    constexpr int PW = Win + 2;
    constexpr int POS = IPB * PROWS * PW;
    constexpr int NCH32 = Ci / 32;
    constexpr int NCHL = Ci / CHUNK;
    constexpr int KS = CHUNK / 32;
    constexpr int MFg = Co / 16;
    constexpr int NF = NTILE / 16;
    constexpr int WMF = 4;
    constexpr int WNF = NF / 4;
    constexpr int CT = Co / MTILE;
    constexpr int RG = Hout / ROWS;
    constexpr int LINE = CHUNK * 2 + 16;
    constexpr int TSTR = MTILE + 8;
    constexpr int PASSN = (NTILE < 128) ? NTILE : 128;
    constexpr int NPASS = (MODE == 4) ? 0 : NTILE / PASSN;
    constexpr int STAGE_B = POS * LINE;
    constexpr int TR_B = (MODE == 4) ? 0 : PASSN * TSTR * 2;
    constexpr int LDS_B = STAGE_B > TR_B ? STAGE_B : TR_B;
    static_assert(8 % CT == 0, "ct swizzle");
    static_assert(WNF * 4 == NF, "wnf");
    static_assert(NCHL * CHUNK == Ci, "chunk");
    static_assert(LDS_B <= 65536, "lds");
    __shared__ char lds[LDS_B];

    const int tid = threadIdx.x;
    const int lane = tid & 63;
    const int wv = tid >> 6;
    const int wm = wv & 1, wn = wv >> 1;
    const int g = lane >> 4, ln = lane & 15;

    const int bid = blockIdx.x;
    const int xcd = bid & 7;
    constexpr int XPC = 8 / CT;
    const int ct = xcd % CT;
    const int nt = (bid >> 3) * XPC + xcd / CT;
    const int b0 = (nt / RG) * IPB;
    const int y0 = (nt % RG) * ROWS;

    int pbase[WNF];
#pragma unroll
    for (int nf = 0; nf < WNF; nf++) {
        int n = (wn * WNF + nf) * 16 + ln;
        int img = n / (ROWS * Wout);
        int rem = n % (ROWS * Wout);
        int yr = rem / Wout, xo = rem % Wout;
        pbase[nf] = (img * PROWS + STRIDE * yr) * PW + STRIDE * xo;
    }

    f32x4 accA[WMF][WNF], accB[WMF][WNF];
#pragma unroll
    for (int mf = 0; mf < WMF; mf++)
#pragma unroll
    for (int nf = 0; nf < WNF; nf++) {
        accA[mf][nf] = (f32x4){0.f, 0.f, 0.f, 0.f};
        accB[mf][nf] = (f32x4){0.f, 0.f, 0.f, 0.f};
    }

    const unsigned short* wbase = wpk + ((long)(ct * 8 + wm * WMF) * 64 + lane) * 8;

    for (int ch = 0; ch < NCHL; ch++) {
        // ---- stage CHUNK channels (bf16) into LDS ----
        for (int i = tid; i < POS * (CHUNK / 8); i += BLK) {
            int p = i / (CHUNK / 8), c = i % (CHUNK / 8);
            int img = p / (PROWS * PW);
            int r = p % (PROWS * PW);
            int prow = r / PW, px = r % PW;
            int yin = STRIDE * y0 - 1 + prow;
            int xin = px - 1;
            uint4 v; v.x = 0; v.y = 0; v.z = 0; v.w = 0;
            if (yin >= 0 && yin < Hin && xin >= 0 && xin < Win) {
                long a = (((long)(b0 + img) * Hin + yin) * Win + xin) * Ci + ch * CHUNK + c * 8;
                v = *(const uint4*)(in + a);
            }
            *(uint4*)(lds + p * LINE + c * 16) = v;
        }
        __syncthreads();
        // ---- 9 kernel positions x KS k-substeps ----
#pragma unroll 3
        for (int pos = 0; pos < 9; pos++) {
            const int ky = pos / 3, kx = pos % 3;
#pragma unroll
            for (int ks = 0; ks < KS; ks++) {
                const int ch32 = ch * KS + ks;
                short8 af[2][WMF];
#pragma unroll
                for (int cv = 0; cv < 2; cv++)
#pragma unroll
                for (int mf = 0; mf < WMF; mf++)
                    af[cv][mf] = *(const short8*)(wbase +
                        ((long)(((cv * 9 + pos) * NCH32 + ch32) * MFg + mf)) * 512);
#pragma unroll
                for (int nf = 0; nf < WNF; nf++) {
                    int po = (pbase[nf] + ky * PW + kx) * LINE + ks * 64 + g * 16;
                    short8 b1 = *(const short8*)(lds + po);
                    short8 b2 = sq8(b1);
#pragma unroll
                    for (int mf = 0; mf < WMF; mf++) {
                        accA[mf][nf] = __builtin_amdgcn_mfma_f32_16x16x32_bf16(af[0][mf], b1, accA[mf][nf], 0, 0, 0);
                        accB[mf][nf] = __builtin_amdgcn_mfma_f32_16x16x32_bf16(af[1][mf], b2, accB[mf][nf], 0, 0, 0);
                    }
                }
            }
        }
        __syncthreads();
    }

    // ---- epilogue ----
    if constexpr (MODE == 4) {
        unsigned short* out = (unsigned short*)outp;
#pragma unroll
        for (int mf = 0; mf < WMF; mf++) {
            int co = ct * MTILE + (wm * WMF + mf) * 16 + g * 4;
#pragma unroll
            for (int nf = 0; nf < WNF; nf++) {
                int n = (wn * WNF + nf) * 16 + ln;
                int img = n / (ROWS * Wout), rem = n % (ROWS * Wout);
                int y = y0 + rem / Wout, x = rem % Wout;
                int b = b0 + img;
#pragma unroll
                for (int r = 0; r < 4; r++) {
                    int c = co + r;
                    float m = accA[mf][nf][r] + bias[c];
                    float v = ones_g[(c * Hout + y) * Wout + x] - accB[mf][nf][r];
                    long oi = (((long)b * Co + c) * Hout + y) * Wout + x;
                    out[oi] = f2bf(m + sqrtf(v + EPSV) * epsb[oi]);
                }
            }
        }
    } else {
        unsigned short* out = (unsigned short*)outp;
#pragma unroll
        for (int pass = 0; pass < NPASS; pass++) {
            __syncthreads();
#pragma unroll
            for (int mf = 0; mf < WMF; mf++) {
                int cob = (wm * WMF + mf) * 16 + g * 4;
                int cg = ct * MTILE + cob;
#pragma unroll
                for (int nf = 0; nf < WNF; nf++) {
                    int nb = (wn * WNF + nf) * 16;
                    if (nb < pass * PASSN || nb >= (pass + 1) * PASSN) continue;
                    int n = nb + ln;
                    int img = n / (ROWS * Wout), rem = n % (ROWS * Wout);
                    int y = y0 + rem / Wout, x = rem % Wout;
                    int b = b0 + img;
                    unsigned int pk2[2];
#pragma unroll
                    for (int r = 0; r < 4; r++) {
                        int c = cg + r;
                        float m = accA[mf][nf][r] + bias[c];
                        float val;
                        if constexpr (MODE == 0) {
                            val = erff(m * rsqrtf(accB[mf][nf][r] + EPSV) * INV_SQRT2);
                        } else if constexpr (MODE == 1) {
                            float v = ones_g[(c * Hout + y) * Wout + x] - accB[mf][nf][r];
                            val = erff(m * rsqrtf(v + EPSV) * INV_SQRT2);
                        } else { // MODE 3
                            float v = ones_g[(c * Hout + y) * Wout + x] - accB[mf][nf][r];
                            float ev = epsb[(((long)b * Co + c) * Hout + y) * Wout + x];
                            val = m + sqrtf(v + EPSV) * ev;
                        }
                        unsigned int hv = f2bf(val);
                        if (r & 1) pk2[r >> 1] |= hv << 16; else pk2[r >> 1] = hv;
                    }
                    int nl = n - pass * PASSN;
                    *(unsigned int*)(lds + (nl * TSTR + cob) * 2) = pk2[0];
                    *(unsigned int*)(lds + (nl * TSTR + cob) * 2 + 4) = pk2[1];
                }
            }
            __syncthreads();
            for (int i = tid; i < PASSN * (MTILE / 8); i += BLK) {
                int nl = i / (MTILE / 8);
                int n = pass * PASSN + nl;
                int c8 = (i % (MTILE / 8)) * 8;
                int img = n / (ROWS * Wout), rem = n % (ROWS * Wout);
                int y = y0 + rem / Wout, x = rem % Wout;
                int b = b0 + img;
                uint4 val = *(const uint4*)(lds + (nl * TSTR + c8) * 2);
                long oa = (((long)b * Hout + y) * Wout + x) * Co + ct * MTILE + c8;
                *(uint4*)(out + oa) = val;
            }
        }
    }
}

// ---------------------------------------------------------------------------
// BatchNorm (bf16, partial-sum based, no atomics)
// ---------------------------------------------------------------------------
__global__ void bn_part_nhwc(const unsigned short* __restrict__ h, float* __restrict__ part,
                             int C, int rpc) {
    int c = threadIdx.x;
    long r0 = (long)blockIdx.x * rpc;
    float s = 0.f, s2 = 0.f;
    for (int r = 0; r < rpc; r++) {
        float v = bf2f(h[(r0 + r) * C + c]);
        s += v; s2 += v * v;
    }
    part[(long)blockIdx.x * 2 * C + c] = s;
    part[(long)blockIdx.x * 2 * C + C + c] = s2;
}

__global__ void bn_part_nchw(const unsigned short* __restrict__ h, float* __restrict__ part,
                             int ipc) {
    int c = threadIdx.x;
    int b0 = blockIdx.x * ipc;
    float s = 0.f, s2 = 0.f;
    for (int b = 0; b < ipc; b++) {
        const unsigned short* p = h + ((long)(b0 + b) * 512 + c) * 16;
        uint4 v0 = *(const uint4*)p;
        uint4 v1 = *(const uint4*)(p + 8);
        unsigned int* vp0 = (unsigned int*)&v0;
        unsigned int* vp1 = (unsigned int*)&v1;
#pragma unroll
        for (int e = 0; e < 4; e++) {
            float a = bf2f((unsigned short)(vp0[e] & 0xffffu)), bb = bf2f((unsigned short)(vp0[e] >> 16));
            float cc = bf2f((unsigned short)(vp1[e] & 0xffffu)), d = bf2f((unsigned short)(vp1[e] >> 16));
            s += a + bb + cc + d;
            s2 += a * a + bb * bb + cc * cc + d * d;
        }
    }
    part[(long)blockIdx.x * 1024 + c] = s;
    part[(long)blockIdx.x * 1024 + 512 + c] = s2;
}

__global__ void bn_fin(const float* __restrict__ part, const float* __restrict__ gamma,
                       const float* __restrict__ beta, float* __restrict__ sc,
                       float* __restrict__ sh, int C, int chunks, float invN) {
    int c = blockIdx.x * 256 + threadIdx.x;
    if (c >= C) return;
    float s = 0.f, s2 = 0.f;
    for (int j = 0; j < chunks; j++) {
        s += part[(long)j * 2 * C + c];
        s2 += part[(long)j * 2 * C + C + c];
    }
    float mean = s * invN;
    float var = s2 * invN - mean * mean;
    float k = gamma[c] * rsqrtf(var + BNEPS);
    sc[c] = k;
    sh[c] = beta[c] - mean * k;
}

__global__ void bn_app_nhwc(unsigned short* __restrict__ h, const float* __restrict__ sc,
                            const float* __restrict__ sh) {
    int i = blockIdx.x * 256 + threadIdx.x;   // 2097152 total
    int cb = (i & 31) * 8;
    uint4 v = *(uint4*)(h + (long)i * 8);
    float4 s0 = *(const float4*)(sc + cb), s1 = *(const float4*)(sc + cb + 4);
    float4 t0 = *(const float4*)(sh + cb), t1 = *(const float4*)(sh + cb + 4);
    float scl[8] = {s0.x, s0.y, s0.z, s0.w, s1.x, s1.y, s1.z, s1.w};
    float shf[8] = {t0.x, t0.y, t0.z, t0.w, t1.x, t1.y, t1.z, t1.w};
    unsigned int* vp = (unsigned int*)&v;
#pragma unroll
    for (int e = 0; e < 4; e++) {
        float lo = bf2f((unsigned short)(vp[e] & 0xffffu));
        float hi = bf2f((unsigned short)(vp[e] >> 16));
        lo = fmaf(lo, scl[2 * e], shf[2 * e]);     lo = lo > 0.f ? lo : 0.f;
        hi = fmaf(hi, scl[2 * e + 1], shf[2 * e + 1]); hi = hi > 0.f ? hi : 0.f;
        vp[e] = (unsigned int)f2bf(lo) | (((unsigned int)f2bf(hi)) << 16);
    }
    *(uint4*)(h + (long)i * 8) = v;
}

__global__ void bn_app_nchw(unsigned short* __restrict__ h, const float* __restrict__ sc,
                            const float* __restrict__ sh) {
    int i = blockIdx.x * 256 + threadIdx.x;   // 524288 total
    int c = (i >> 1) & 511;
    float k = sc[c], t = sh[c];
    uint4 v = *(uint4*)(h + (long)i * 8);
    unsigned int* vp = (unsigned int*)&v;
#pragma unroll
    for (int e = 0; e < 4; e++) {
        float lo = bf2f((unsigned short)(vp[e] & 0xffffu));
        float hi = bf2f((unsigned short)(vp[e] >> 16));
        lo = fmaf(lo, k, t); lo = lo > 0.f ? lo : 0.f;
        hi = fmaf(hi, k, t); hi = hi > 0.f ? hi : 0.f;
        vp[e] = (unsigned int)f2bf(lo) | (((unsigned int)f2bf(hi)) << 16);
    }
    *(uint4*)(h + (long)i * 8) = v;
}

// ---------------------------------------------------------------------------
// FC1 bf16 MFMA split-K + reduce
// ---------------------------------------------------------------------------
__global__ __launch_bounds__(256) void fc1_mfma(const unsigned short* __restrict__ Ab,
                                                const unsigned short* __restrict__ Wp,
                                                float* __restrict__ pbuf) {
    __shared__ char lds[2 * 64 * 80];
    const int tid = threadIdx.x;
    const int lane = tid & 63;
    const int wv = tid >> 6;
    const int g = lane >> 4, ln = lane & 15;
    const int ot = blockIdx.x, bt = blockIdx.y, s = blockIdx.z;
    const int b0 = bt * 64;
    const int k0g = s * 1024;

    f32x4 acc[2][4];
#pragma unroll
    for (int c = 0; c < 2; c++)
#pragma unroll
    for (int nf = 0; nf < 4; nf++) acc[c][nf] = (f32x4){0.f, 0.f, 0.f, 0.f};

    for (int k0 = 0; k0 < 1024; k0 += 64) {
        __syncthreads();
        for (int i = tid; i < 512; i += 256) {
            int row = i >> 3, kk = (i >> 2) & 1, seg = i & 3;
            uint4 v = *(const uint4*)(Ab + ((long)(b0 + row) * 8192 + k0g + k0 + kk * 32 + seg * 8));
            *(uint4*)(lds + (kk * 64 + row) * 80 + seg * 16) = v;
        }
        __syncthreads();
#pragma unroll
        for (int kk = 0; kk < 2; kk++) {
            int kt = (k0g + k0) / 32 + kk;
            short8 af[2];
#pragma unroll
            for (int c = 0; c < 2; c++) {
                int mf = ot * 8 + wv * 2 + c;
                af[c] = *(const short8*)(Wp + (((long)kt * 64 + mf) * 64 + lane) * 8);
            }
            short8 bf[4];
#pragma unroll
            for (int nf = 0; nf < 4; nf++)
                bf[nf] = *(const short8*)(lds + (kk * 64 + nf * 16 + ln) * 80 + g * 16);
#pragma unroll
            for (int c = 0; c < 2; c++)
#pragma unroll
            for (int nf = 0; nf < 4; nf++)
                acc[c][nf] = __builtin_amdgcn_mfma_f32_16x16x32_bf16(af[c], bf[nf], acc[c][nf], 0, 0, 0);
        }
    }
#pragma unroll
    for (int c = 0; c < 2; c++) {
        int o = ot * 128 + (wv * 2 + c) * 16 + g * 4;
#pragma unroll
        for (int nf = 0; nf < 4; nf++) {
            int b = b0 + nf * 16 + ln;
            *(f32x4*)(pbuf + ((long)s * 256 + b) * 1024 + o) = acc[c][nf];
        }
    }
}

__global__ void fc1_reduce(const float* __restrict__ pbuf, const float* __restrict__ bias,
                           float* __restrict__ out) {
    int idx = blockIdx.x * 256 + threadIdx.x;
    float s = 0.f;
#pragma unroll
    for (int j = 0; j < 8; j++) s += pbuf[(long)j * 262144 + idx];
    s += bias[idx & 1023];
    out[idx] = s > 0.f ? s : 0.f;
}

__global__ void fc2_k(const float* __restrict__ A, const float* __restrict__ W,
                      const float* __restrict__ b2, float* __restrict__ out) {
    int bb = blockIdx.x;
    int tid = threadIdx.x;
    float acc[10];
#pragma unroll
    for (int o = 0; o < 10; o++) acc[o] = 0.f;
    const float* arow = A + (long)bb * 1024;
    for (int k = tid; k < 1024; k += 256) {
        float a = arow[k];
#pragma unroll
        for (int o = 0; o < 10; o++) acc[o] = fmaf(a, W[o * 1024 + k], acc[o]);
    }
#pragma unroll
    for (int o = 0; o < 10; o++)
        for (int off = 32; off > 0; off >>= 1) acc[o] += __shfl_down(acc[o], off);
    __shared__ float red[10][4];
    int wid = tid >> 6, lane = tid & 63;
    if (lane == 0) {
#pragma unroll
        for (int o = 0; o < 10; o++) red[o][wid] = acc[o];
    }
    __syncthreads();
    if (tid < 10)
        out[bb * 10 + tid] = red[tid][0] + red[tid][1] + red[tid][2] + red[tid][3] + b2[tid];
}

// ---------------------------------------------------------------------------
extern "C" void kernel_launch(void* const* d_in, const int* in_sizes, int n_in,
                              void* d_out, int out_size, void* d_ws, size_t ws_size,
                              hipStream_t stream) {
    const float* x  = (const float*)d_in[0];
    const float* a1 = (const float*)d_in[1];  const float* b1 = (const float*)d_in[2];  const float* c1 = (const float*)d_in[3];
    const float* a2 = (const float*)d_in[4];  const float* b2 = (const float*)d_in[5];  const float* c2 = (const float*)d_in[6];
    const float* a3 = (const float*)d_in[7];  const float* b3 = (const float*)d_in[8];  const float* c3 = (const float*)d_in[9];
    const float* a4 = (const float*)d_in[10]; const float* b4 = (const float*)d_in[11]; const float* c4 = (const float*)d_in[12];
    const float* a5 = (const float*)d_in[13]; const float* b5 = (const float*)d_in[14]; const float* c5 = (const float*)d_in[15];
    const float* a6 = (const float*)d_in[16]; const float* b6 = (const float*)d_in[17]; const float* c6 = (const float*)d_in[18];
    const float* g3 = (const float*)d_in[19]; const float* be3 = (const float*)d_in[20];
    const float* g6 = (const float*)d_in[21]; const float* be6 = (const float*)d_in[22];
    const float* fc1w = (const float*)d_in[23]; const float* fc1b = (const float*)d_in[24];
    const float* fc2w = (const float*)d_in[25]; const float* fc2b = (const float*)d_in[26];
    const float* eps3 = (const float*)d_in[27]; const float* eps6 = (const float*)d_in[28];
    (void)in_sizes; (void)n_in; (void)out_size; (void)ws_size;

    float* w = (float*)d_ws;
    size_t off = 0;
    auto alloc = [&](size_t n) { float* p = w + off; off += n; return p; };
    unsigned short* pk2 = (unsigned short*)alloc(147456);
    unsigned short* pk3 = (unsigned short*)alloc(294912);
    unsigned short* pk4 = (unsigned short*)alloc(589824);
    unsigned short* pk5 = (unsigned short*)alloc(1179648);
    unsigned short* pk6 = (unsigned short*)alloc(2359296);
    float* wa1 = alloc(3456); float* wb1 = alloc(3456);
    float* ss2 = alloc(1152); float* ss3 = alloc(2304);
    float* ss5 = alloc(4608); float* ss6 = alloc(4608);
    float* og2 = alloc(32768); float* og3 = alloc(65536);
    float* og5 = alloc(32768); float* og6 = alloc(8192);
    float* part3 = alloc(131072);
    float* part6 = alloc(65536);
    float* sc3 = alloc(256); float* sh3 = alloc(256);
    float* sc6 = alloc(512); float* sh6 = alloc(512);
    float* A  = alloc(16777216);
    float* Bb = alloc(4194304);
    float* Cc = alloc(8388608);
    float* Dd = alloc(2097152);
    float* Ee = alloc(4194304);

    unsigned short* ex1 = (unsigned short*)A;
    unsigned short* pkF = (unsigned short*)A;
    float*          pbuf = A + 4194304;
    unsigned short* ex2 = (unsigned short*)Bb;
    float*          fco = Bb;
    unsigned short* h6b = (unsigned short*)(Bb + 524288);
    unsigned short* h3b = (unsigned short*)Cc;
    unsigned short* ex4 = (unsigned short*)Dd;
    unsigned short* ex5 = (unsigned short*)Ee;

    // ---- prep ----
    prep_w<<<14, 256, 0, stream>>>(a1, b1, wa1, wb1, 3456);
    prep_pack<<<72,  256, 0, stream>>>(a2, b2, pk2, 128, 128, 1, 18432);
    prep_pack<<<144, 256, 0, stream>>>(a3, b3, pk3, 128, 256, 1, 36864);
    prep_pack<<<288, 256, 0, stream>>>(a4, b4, pk4, 256, 256, 0, 73728);
    prep_pack<<<576, 256, 0, stream>>>(a5, b5, pk5, 256, 512, 1, 147456);
    prep_pack<<<1152,256, 0, stream>>>(a6, b6, pk6, 512, 512, 1, 294912);
    prep_s<<<128, 64, 0, stream>>>(a2, ss2, 128);
    prep_s<<<256, 64, 0, stream>>>(a3, ss3, 128);
    prep_s<<<512, 64, 0, stream>>>(a5, ss5, 256);
    prep_s<<<512, 64, 0, stream>>>(a6, ss6, 512);
    prep_ones<<<128, 256, 0, stream>>>(ss2, og2, 128, 16, 16, 32, 32, 2, 32768);
    prep_ones<<<256, 256, 0, stream>>>(ss3, og3, 256, 16, 16, 16, 16, 1, 65536);
    prep_ones<<<128, 256, 0, stream>>>(ss5, og5, 512, 8, 8, 8, 8, 1, 32768);
    prep_ones<<<32,  256, 0, stream>>>(ss6, og6, 512, 4, 4, 8, 8, 2, 8192);

    // ---- network ----
    conv1_k<<<4096, 256, 0, stream>>>(x, wa1, wb1, c1, ex1);
    // L2: [256,32,32,128] -> [256,16,16,128]   (r5-proven geometry)
    conv_mfma<128,32,32,128,16,16,2, 8,1,128,32,1><<<512, 512, 0, stream>>>(ex1, pk2, c2, og2, nullptr, ex2);
    // L3: -> h3b [256,16,16,256] NHWC bf16 (sampled)   (r6-proven geometry, 170us)
    conv_mfma<128,16,16,256,16,16,1, 8,2,256,64,3><<<512, 512, 0, stream>>>(ex2, pk3, c3, og3, eps3, h3b);
    // FC1 weight pack into A (ex1 dead after L2)
    prep_fc1<<<4096, 256, 0, stream>>>(fc1w, pkF);
    // BN3 (bf16 NHWC, in place)
    bn_part_nhwc<<<256, 256, 0, stream>>>(h3b, part3, 256, 256);
    bn_fin<<<1, 256, 0, stream>>>(part3, g3, be3, sc3, sh3, 256, 256, 1.f / 65536.f);
    bn_app_nhwc<<<8192, 256, 0, stream>>>(h3b, sc3, sh3);
    // L4: [256,16,16,256] -> [256,8,8,256]   (r5-proven: NTILE=64 CHUNK=32 grid 512)
    conv_mfma<256,16,16,256, 8, 8,2, 8,1,64,32,0><<<512, 512, 0, stream>>>(h3b, pk4, c4, nullptr, nullptr, ex4);
    // L5: -> [256,8,8,512]   (r5-proven: NTILE=128 CHUNK=32 grid 512)
    conv_mfma<256, 8, 8,512, 8, 8,1, 8,2,128,32,1><<<512, 512, 0, stream>>>(ex4, pk5, c5, og5, nullptr, ex5);
    // L6: -> h6b [256,512,4,4] NCHW bf16 (sampled)   (r5-proven: NTILE=64 CHUNK=32 grid 256)
    conv_mfma<512, 8, 8,512, 4, 4,2, 4,4,64,32,4><<<256, 512, 0, stream>>>(ex5, pk6, c6, og6, eps6, h6b);
    // BN6 (bf16 NCHW, in place)
    bn_part_nchw<<<64, 512, 0, stream>>>(h6b, part6, 4);
    bn_fin<<<2, 256, 0, stream>>>(part6, g6, be6, sc6, sh6, 512, 64, 1.f / 4096.f);
    bn_app_nchw<<<2048, 256, 0, stream>>>(h6b, sc6, sh6);
    // FC1 + FC2
    fc1_mfma<<<dim3(8, 4, 8), 256, 0, stream>>>(h6b, pkF, pbuf);
    fc1_reduce<<<1024, 256, 0, stream>>>(pbuf, fc1b, fco);
    fc2_k<<<256, 256, 0, stream>>>(fco, fc2w, fc2b, (float*)d_out);
}

// Round 9
// 899.223 us; speedup vs baseline: 1.2042x; 1.0855x over previous
//
#include <hip/hip_runtime.h>
#include <hip/hip_bf16.h>
#include <math.h>

#define EPSV 1e-10f
#define BNEPS 1e-5f
#define INV_SQRT2 0.70710678118654752440f

typedef __attribute__((ext_vector_type(8))) short short8;
typedef __attribute__((ext_vector_type(4))) float f32x4;
typedef _Float16 half8 __attribute__((ext_vector_type(8)));

__device__ __forceinline__ unsigned short f2h(float f) {
    _Float16 h = (_Float16)f;                      // RNE
    return __builtin_bit_cast(unsigned short, h);
}
__device__ __forceinline__ float h2f(unsigned short u) {
    _Float16 h = __builtin_bit_cast(_Float16, u);
    return (float)h;
}

// ---------------------------------------------------------------------------
// L1 weight prep (fp32)
// ---------------------------------------------------------------------------
__global__ void prep_w(const float* __restrict__ a, const float* __restrict__ b,
                       float* __restrict__ WA, float* __restrict__ WB, int n) {
    for (int i = blockIdx.x * blockDim.x + threadIdx.x; i < n; i += gridDim.x * blockDim.x) {
        float p0 = 1.f / (1.f + expf(-a[i]));
        float sb = 1.f / (1.f + expf(-b[i]));
        float p1 = (1.f - p0) * sb;
        float ew = 2.f * p1 - (1.f - p0);
        float ew2 = 1.f - p0;
        WA[i] = ew;
        WB[i] = ew2 - ew * ew;
    }
}

// ---------------------------------------------------------------------------
// Pack ternary-stat weights into MFMA A-fragment order (fp16).
// ---------------------------------------------------------------------------
__global__ void prep_pack(const float* __restrict__ a, const float* __restrict__ b,
                          unsigned short* __restrict__ pk, int Ci, int Co, int ver2, int total) {
    int idx = blockIdx.x * 256 + threadIdx.x;
    if (idx >= total) return;
    int lane = idx & 63;
    int MFg = Co >> 4, NCH = Ci >> 5;
    int mfch = idx >> 6;
    int mf = mfch % MFg;
    int chpos = mfch / MFg;
    int ch = chpos % NCH;
    int pos = chpos / NCH;
    int co = mf * 16 + (lane & 15);
    int cib = ch * 32 + (lane >> 4) * 8;
    unsigned int wa[4], wb[4];
#pragma unroll
    for (int j = 0; j < 8; j++) {
        long s = ((long)co * Ci + cib + j) * 9 + pos;
        float p0 = 1.f / (1.f + expf(-a[s]));
        float sb = 1.f / (1.f + expf(-b[s]));
        float p1 = (1.f - p0) * sb;
        float ew = 2.f * p1 - (1.f - p0);
        float ew2 = 1.f - p0;
        unsigned int ha = f2h(ew);
        unsigned int hb = f2h(ver2 ? ew * ew : ew2 - ew * ew);
        if (j & 1) { wa[j >> 1] |= ha << 16; wb[j >> 1] |= hb << 16; }
        else       { wa[j >> 1] = ha;        wb[j >> 1] = hb; }
    }
    long b0 = (((long)(0 * 9 + pos) * NCH + ch) * MFg + mf) * 64 + lane;
    long b1 = (((long)(1 * 9 + pos) * NCH + ch) * MFg + mf) * 64 + lane;
    uint4 va; va.x = wa[0]; va.y = wa[1]; va.z = wa[2]; va.w = wa[3];
    uint4 vb; vb.x = wb[0]; vb.y = wb[1]; vb.z = wb[2]; vb.w = wb[3];
    *(uint4*)(pk + b0 * 8) = va;
    *(uint4*)(pk + b1 * 8) = vb;
}

// ssum[co][k] = sum_ci sigmoid(-alpha)
__global__ void prep_s(const float* __restrict__ alpha, float* __restrict__ s, int Ci) {
    int co = blockIdx.x;
    int lane = threadIdx.x;
    float acc[9];
#pragma unroll
    for (int k = 0; k < 9; k++) acc[k] = 0.f;
    for (int ci = lane; ci < Ci; ci += 64) {
        const float* p = alpha + ((long)co * Ci + ci) * 9;
#pragma unroll
        for (int k = 0; k < 9; k++) acc[k] += 1.f / (1.f + expf(p[k]));
    }
#pragma unroll
    for (int k = 0; k < 9; k++) {
        for (int off = 32; off > 0; off >>= 1) acc[k] += __shfl_down(acc[k], off);
    }
    if (lane == 0) {
#pragma unroll
        for (int k = 0; k < 9; k++) s[co * 9 + k] = acc[k];
    }
}

__global__ void prep_ones(const float* __restrict__ ssum, float* __restrict__ og,
                          int Co, int Hout, int Wout, int Hin, int Win, int stride, int total) {
    int idx = blockIdx.x * 256 + threadIdx.x;
    if (idx >= total) return;
    int x = idx % Wout, y = (idx / Wout) % Hout, co = idx / (Wout * Hout);
    float s = 0.f;
    for (int ky = 0; ky < 3; ky++) {
        int yi = stride * y - 1 + ky;
        if (yi < 0 || yi >= Hin) continue;
        for (int kx = 0; kx < 3; kx++) {
            int xi = stride * x - 1 + kx;
            if (xi < 0 || xi >= Win) continue;
            s += ssum[co * 9 + ky * 3 + kx];
        }
    }
    og[idx] = s;
}

// ---------------------------------------------------------------------------
// FC1 weight pack: fp32 [1024][8192] -> fp16 A-fragment order
// ---------------------------------------------------------------------------
__global__ void prep_fc1(const float* __restrict__ W, unsigned short* __restrict__ pk) {
    int idx = blockIdx.x * 256 + threadIdx.x;
    int lane = idx & 63;
    int mf = (idx >> 6) & 63;
    int kt = idx >> 12;
    int o = mf * 16 + (lane & 15);
    long k = (long)kt * 32 + (lane >> 4) * 8;
    const float* src = W + (long)o * 8192 + k;
    float4 f0 = *(const float4*)src;
    float4 f1 = *(const float4*)(src + 4);
    uint4 v;
    v.x = (unsigned)f2h(f0.x) | ((unsigned)f2h(f0.y) << 16);
    v.y = (unsigned)f2h(f0.z) | ((unsigned)f2h(f0.w) << 16);
    v.z = (unsigned)f2h(f1.x) | ((unsigned)f2h(f1.y) << 16);
    v.w = (unsigned)f2h(f1.z) | ((unsigned)f2h(f1.w) << 16);
    *(uint4*)(pk + (long)idx * 8) = v;
}

// ---------------------------------------------------------------------------
// L1: fp32 vector conv (Ci=3) -> erf -> NHWC fp16.
// ---------------------------------------------------------------------------
__global__ __launch_bounds__(256) void conv1_k(const float* __restrict__ x,
        const float* __restrict__ wa, const float* __restrict__ wb,
        const float* __restrict__ bias, unsigned short* __restrict__ out) {
    __shared__ float win[3 * 4 * 34];
    __shared__ float wl[128 * 56];
    int b = blockIdx.x >> 4;
    int y0 = (blockIdx.x & 15) * 2;
    int tid = threadIdx.x;
    for (int i = tid; i < 408; i += 256) {
        int ci = i / 136, r = (i % 136) / 34, px = i % 34;
        int yy = y0 - 1 + r, xx = px - 1;
        float v = 0.f;
        if (yy >= 0 && yy < 32 && xx >= 0 && xx < 32)
            v = x[((b * 3 + ci) * 32 + yy) * 32 + xx];
        win[i] = v;
    }
    for (int i = tid; i < 128 * 56; i += 256) {
        int co = i / 56, q = i % 56, j = q >> 1;
        float v = 0.f;
        if (j < 27) v = (q & 1) ? wb[co * 27 + j] : wa[co * 27 + j];
        wl[i] = v;
    }
    __syncthreads();
    int xo = tid & 31;
    int cog = tid >> 5;
    float iv[2][28], sq[2][28];
#pragma unroll
    for (int r = 0; r < 2; r++) {
#pragma unroll
        for (int ci = 0; ci < 3; ci++)
#pragma unroll
        for (int ky = 0; ky < 3; ky++)
#pragma unroll
        for (int kx = 0; kx < 3; kx++) {
            float v = win[(ci * 4 + r + ky) * 34 + xo + kx];
            iv[r][ci * 9 + ky * 3 + kx] = v;
            sq[r][ci * 9 + ky * 3 + kx] = v * v;
        }
        iv[r][27] = 0.f; sq[r][27] = 0.f;
    }
    unsigned int pk[2][8];
#pragma unroll
    for (int k = 0; k < 16; k++) {
        int co = cog * 16 + k;
        const float4* wp = (const float4*)&wl[co * 56];
        float bs = bias[co];
        float m0 = bs, v0 = 0.f, m1 = bs, v1 = 0.f;
#pragma unroll
        for (int q = 0; q < 14; q++) {
            float4 w4 = wp[q];
            m0 = fmaf(iv[0][2 * q], w4.x, m0);     v0 = fmaf(sq[0][2 * q], w4.y, v0);
            m0 = fmaf(iv[0][2 * q + 1], w4.z, m0); v0 = fmaf(sq[0][2 * q + 1], w4.w, v0);
            m1 = fmaf(iv[1][2 * q], w4.x, m1);     v1 = fmaf(sq[1][2 * q], w4.y, v1);
            m1 = fmaf(iv[1][2 * q + 1], w4.z, m1); v1 = fmaf(sq[1][2 * q + 1], w4.w, v1);
        }
        unsigned int h0 = f2h(erff(m0 * rsqrtf(v0 + EPSV) * INV_SQRT2));
        unsigned int h1 = f2h(erff(m1 * rsqrtf(v1 + EPSV) * INV_SQRT2));
        if (k & 1) { pk[0][k >> 1] |= h0 << 16; pk[1][k >> 1] |= h1 << 16; }
        else       { pk[0][k >> 1] = h0;        pk[1][k >> 1] = h1; }
    }
#pragma unroll
    for (int r = 0; r < 2; r++) {
        long oa = (((long)b * 32 + y0 + r) * 32 + xo) * 128 + cog * 16;
        uint4 u0; u0.x = pk[r][0]; u0.y = pk[r][1]; u0.z = pk[r][2]; u0.w = pk[r][3];
        uint4 u1; u1.x = pk[r][4]; u1.y = pk[r][5]; u1.z = pk[r][6]; u1.w = pk[r][7];
        *(uint4*)(out + oa) = u0;
        *(uint4*)(out + oa + 8) = u1;
    }
}

// ---------------------------------------------------------------------------
// MFMA implicit-GEMM fused LRnet conv. NHWC fp16 input. 512 thr (wm2 x wn4).
// Square via v_pk_mul_f16 (4 insts per fragment).
// MODE 0: lrconv  -> erf -> NHWC fp16   (v = convB)
// MODE 1: ver2    -> erf -> NHWC fp16   (v = ones - convB)
// MODE 3: ver2 + sample -> NHWC fp16    (out = m + sqrt(v+eps)*epsb)
// MODE 4: ver2 + sample -> NCHW fp16
// ---------------------------------------------------------------------------
template<int Ci, int Hin, int Win, int Co, int Hout, int Wout, int STRIDE,
         int ROWS, int IPB, int NTILE, int CHUNK, int MODE>
__global__ __launch_bounds__(512) void conv_mfma(
    const unsigned short* __restrict__ in,
    const unsigned short* __restrict__ wpk,
    const float* __restrict__ bias,
    const float* __restrict__ ones_g,
    const float* __restrict__ epsb,
    void* __restrict__ outp)
{
    constexpr int BLK = 512;
    constexpr int MTILE = 128;
    constexpr int PROWS = STRIDE * (ROWS - 1) + 3;
    constexpr int PW = Win + 2;
    constexpr int POS = IPB * PROWS * PW;
    constexpr int NCH32 = Ci / 32;
    constexpr int NCHL = Ci / CHUNK;
    constexpr int KS = CHUNK / 32;
    constexpr int MFg = Co / 16;
    constexpr int NF = NTILE / 16;
    constexpr int WMF = 4;
    constexpr int WNF = NF / 4;
    constexpr int CT = Co / MTILE;
    constexpr int RG = Hout / ROWS;
    constexpr int LINE = CHUNK * 2 + 16;
    constexpr int TSTR = MTILE + 8;
    constexpr int PASSN = (NTILE < 128) ? NTILE : 128;
    constexpr int NPASS = (MODE == 4) ? 0 : NTILE / PASSN;
    constexpr int STAGE_B = POS * LINE;
    constexpr int TR_B = (MODE == 4) ? 0 : PASSN * TSTR * 2;
    constexpr int LDS_B = STAGE_B > TR_B ? STAGE_B : TR_B;
    static_assert(8 % CT == 0, "ct swizzle");
    static_assert(WNF * 4 == NF, "wnf");
    static_assert(NCHL * CHUNK == Ci, "chunk");
    static_assert(LDS_B <= 65536, "lds");
    __shared__ char lds[LDS_B];

    const int tid = threadIdx.x;
    const int lane = tid & 63;
    const int wv = tid >> 6;
    const int wm = wv & 1, wn = wv >> 1;
    const int g = lane >> 4, ln = lane & 15;

    const int bid = blockIdx.x;
    const int xcd = bid & 7;
    constexpr int XPC = 8 / CT;
    const int ct = xcd % CT;
    const int nt = (bid >> 3) * XPC + xcd / CT;
    const int b0 = (nt / RG) * IPB;
    const int y0 = (nt % RG) * ROWS;

    int pbase[WNF];
#pragma unroll
    for (int nf = 0; nf < WNF; nf++) {
        int n = (wn * WNF + nf) * 16 + ln;
        int img = n / (ROWS * Wout);
        int rem = n % (ROWS * Wout);
        int yr = rem / Wout, xo = rem % Wout;
        pbase[nf] = (img * PROWS + STRIDE * yr) * PW + STRIDE * xo;
    }

    f32x4 accA[WMF][WNF], accB[WMF][WNF];
#pragma unroll
    for (int mf = 0; mf < WMF; mf++)
#pragma unroll
    for (int nf = 0; nf < WNF; nf++) {
        accA[mf][nf] = (f32x4){0.f, 0.f, 0.f, 0.f};
        accB[mf][nf] = (f32x4){0.f, 0.f, 0.f, 0.f};
    }

    const unsigned short* wbase = wpk + ((long)(ct * 8 + wm * WMF) * 64 + lane) * 8;

    for (int ch = 0; ch < NCHL; ch++) {
        // ---- stage CHUNK channels (fp16) into LDS ----
        for (int i = tid; i < POS * (CHUNK / 8); i += BLK) {
            int p = i / (CHUNK / 8), c = i % (CHUNK / 8);
            int img = p / (PROWS * PW);
            int r = p % (PROWS * PW);
            int prow = r / PW, px = r % PW;
            int yin = STRIDE * y0 - 1 + prow;
            int xin = px - 1;
            uint4 v; v.x = 0; v.y = 0; v.z = 0; v.w = 0;
            if (yin >= 0 && yin < Hin && xin >= 0 && xin < Win) {
                long a = (((long)(b0 + img) * Hin + yin) * Win + xin) * Ci + ch * CHUNK + c * 8;
                v = *(const uint4*)(in + a);
            }
            *(uint4*)(lds + p * LINE + c * 16) = v;
        }
        __syncthreads();
        // ---- 9 kernel positions x KS k-substeps ----
#pragma unroll 3
        for (int pos = 0; pos < 9; pos++) {
            const int ky = pos / 3, kx = pos % 3;
#pragma unroll
            for (int ks = 0; ks < KS; ks++) {
                const int ch32 = ch * KS + ks;
                half8 af[2][WMF];
#pragma unroll
                for (int cv = 0; cv < 2; cv++)
#pragma unroll
                for (int mf = 0; mf < WMF; mf++)
                    af[cv][mf] = *(const half8*)(wbase +
                        ((long)(((cv * 9 + pos) * NCH32 + ch32) * MFg + mf)) * 512);
#pragma unroll
                for (int nf = 0; nf < WNF; nf++) {
                    int po = (pbase[nf] + ky * PW + kx) * LINE + ks * 64 + g * 16;
                    half8 b1 = *(const half8*)(lds + po);
                    half8 b2 = b1 * b1;               // 4x v_pk_mul_f16
#pragma unroll
                    for (int mf = 0; mf < WMF; mf++) {
                        accA[mf][nf] = __builtin_amdgcn_mfma_f32_16x16x32_f16(af[0][mf], b1, accA[mf][nf], 0, 0, 0);
                        accB[mf][nf] = __builtin_amdgcn_mfma_f32_16x16x32_f16(af[1][mf], b2, accB[mf][nf], 0, 0, 0);
                    }
                }
            }
        }
        __syncthreads();
    }

    // ---- epilogue ----
    if constexpr (MODE == 4) {
        unsigned short* out = (unsigned short*)outp;
#pragma unroll
        for (int mf = 0; mf < WMF; mf++) {
            int co = ct * MTILE + (wm * WMF + mf) * 16 + g * 4;
#pragma unroll
            for (int nf = 0; nf < WNF; nf++) {
                int n = (wn * WNF + nf) * 16 + ln;
                int img = n / (ROWS * Wout), rem = n % (ROWS * Wout);
                int y = y0 + rem / Wout, x = rem % Wout;
                int b = b0 + img;
#pragma unroll
                for (int r = 0; r < 4; r++) {
                    int c = co + r;
                    float m = accA[mf][nf][r] + bias[c];
                    float v = ones_g[(c * Hout + y) * Wout + x] - accB[mf][nf][r];
                    long oi = (((long)b * Co + c) * Hout + y) * Wout + x;
                    out[oi] = f2h(m + sqrtf(v + EPSV) * epsb[oi]);
                }
            }
        }
    } else {
        unsigned short* out = (unsigned short*)outp;
#pragma unroll
        for (int pass = 0; pass < NPASS; pass++) {
            __syncthreads();
#pragma unroll
            for (int mf = 0; mf < WMF; mf++) {
                int cob = (wm * WMF + mf) * 16 + g * 4;
                int cg = ct * MTILE + cob;
#pragma unroll
                for (int nf = 0; nf < WNF; nf++) {
                    int nb = (wn * WNF + nf) * 16;
                    if (nb < pass * PASSN || nb >= (pass + 1) * PASSN) continue;
                    int n = nb + ln;
                    int img = n / (ROWS * Wout), rem = n % (ROWS * Wout);
                    int y = y0 + rem / Wout, x = rem % Wout;
                    int b = b0 + img;
                    unsigned int pk2[2];
#pragma unroll
                    for (int r = 0; r < 4; r++) {
                        int c = cg + r;
                        float m = accA[mf][nf][r] + bias[c];
                        float val;
                        if constexpr (MODE == 0) {
                            val = erff(m * rsqrtf(accB[mf][nf][r] + EPSV) * INV_SQRT2);
                        } else if constexpr (MODE == 1) {
                            float v = ones_g[(c * Hout + y) * Wout + x] - accB[mf][nf][r];
                            val = erff(m * rsqrtf(v + EPSV) * INV_SQRT2);
                        } else { // MODE 3
                            float v = ones_g[(c * Hout + y) * Wout + x] - accB[mf][nf][r];
                            float ev = epsb[(((long)b * Co + c) * Hout + y) * Wout + x];
                            val = m + sqrtf(v + EPSV) * ev;
                        }
                        unsigned int hv = f2h(val);
                        if (r & 1) pk2[r >> 1] |= hv << 16; else pk2[r >> 1] = hv;
                    }
                    int nl = n - pass * PASSN;
                    *(unsigned int*)(lds + (nl * TSTR + cob) * 2) = pk2[0];
                    *(unsigned int*)(lds + (nl * TSTR + cob) * 2 + 4) = pk2[1];
                }
            }
            __syncthreads();
            for (int i = tid; i < PASSN * (MTILE / 8); i += BLK) {
                int nl = i / (MTILE / 8);
                int n = pass * PASSN + nl;
                int c8 = (i % (MTILE / 8)) * 8;
                int img = n / (ROWS * Wout), rem = n % (ROWS * Wout);
                int y = y0 + rem / Wout, x = rem % Wout;
                int b = b0 + img;
                uint4 val = *(const uint4*)(lds + (nl * TSTR + c8) * 2);
                long oa = (((long)b * Hout + y) * Wout + x) * Co + ct * MTILE + c8;
                *(uint4*)(out + oa) = val;
            }
        }
    }
}

// ---------------------------------------------------------------------------
// BatchNorm (fp16 activations, partial-sum based, no atomics)
// ---------------------------------------------------------------------------
__global__ void bn_part_nhwc(const unsigned short* __restrict__ h, float* __restrict__ part,
                             int C, int rpc) {
    int c = threadIdx.x;
    long r0 = (long)blockIdx.x * rpc;
    float s = 0.f, s2 = 0.f;
    for (int r = 0; r < rpc; r++) {
        float v = h2f(h[(r0 + r) * C + c]);
        s += v; s2 += v * v;
    }
    part[(long)blockIdx.x * 2 * C + c] = s;
    part[(long)blockIdx.x * 2 * C + C + c] = s2;
}

__global__ void bn_part_nchw(const unsigned short* __restrict__ h, float* __restrict__ part,
                             int ipc) {
    int c = threadIdx.x;
    int b0 = blockIdx.x * ipc;
    float s = 0.f, s2 = 0.f;
    for (int b = 0; b < ipc; b++) {
        const unsigned short* p = h + ((long)(b0 + b) * 512 + c) * 16;
        uint4 v0 = *(const uint4*)p;
        uint4 v1 = *(const uint4*)(p + 8);
        unsigned int* vp0 = (unsigned int*)&v0;
        unsigned int* vp1 = (unsigned int*)&v1;
#pragma unroll
        for (int e = 0; e < 4; e++) {
            float a = h2f((unsigned short)(vp0[e] & 0xffffu)), bb = h2f((unsigned short)(vp0[e] >> 16));
            float cc = h2f((unsigned short)(vp1[e] & 0xffffu)), d = h2f((unsigned short)(vp1[e] >> 16));
            s += a + bb + cc + d;
            s2 += a * a + bb * bb + cc * cc + d * d;
        }
    }
    part[(long)blockIdx.x * 1024 + c] = s;
    part[(long)blockIdx.x * 1024 + 512 + c] = s2;
}

__global__ void bn_fin(const float* __restrict__ part, const float* __restrict__ gamma,
                       const float* __restrict__ beta, float* __restrict__ sc,
                       float* __restrict__ sh, int C, int chunks, float invN) {
    int c = blockIdx.x * 256 + threadIdx.x;
    if (c >= C) return;
    float s = 0.f, s2 = 0.f;
    for (int j = 0; j < chunks; j++) {
        s += part[(long)j * 2 * C + c];
        s2 += part[(long)j * 2 * C + C + c];
    }
    float mean = s * invN;
    float var = s2 * invN - mean * mean;
    float k = gamma[c] * rsqrtf(var + BNEPS);
    sc[c] = k;
    sh[c] = beta[c] - mean * k;
}

__global__ void bn_app_nhwc(unsigned short* __restrict__ h, const float* __restrict__ sc,
                            const float* __restrict__ sh) {
    int i = blockIdx.x * 256 + threadIdx.x;   // 2097152 total
    int cb = (i & 31) * 8;
    uint4 v = *(uint4*)(h + (long)i * 8);
    float4 s0 = *(const float4*)(sc + cb), s1 = *(const float4*)(sc + cb + 4);
    float4 t0 = *(const float4*)(sh + cb), t1 = *(const float4*)(sh + cb + 4);
    float scl[8] = {s0.x, s0.y, s0.z, s0.w, s1.x, s1.y, s1.z, s1.w};
    float shf[8] = {t0.x, t0.y, t0.z, t0.w, t1.x, t1.y, t1.z, t1.w};
    unsigned int* vp = (unsigned int*)&v;
#pragma unroll
    for (int e = 0; e < 4; e++) {
        float lo = h2f((unsigned short)(vp[e] & 0xffffu));
        float hi = h2f((unsigned short)(vp[e] >> 16));
        lo = fmaf(lo, scl[2 * e], shf[2 * e]);     lo = lo > 0.f ? lo : 0.f;
        hi = fmaf(hi, scl[2 * e + 1], shf[2 * e + 1]); hi = hi > 0.f ? hi : 0.f;
        vp[e] = (unsigned int)f2h(lo) | (((unsigned int)f2h(hi)) << 16);
    }
    *(uint4*)(h + (long)i * 8) = v;
}

__global__ void bn_app_nchw(unsigned short* __restrict__ h, const float* __restrict__ sc,
                            const float* __restrict__ sh) {
    int i = blockIdx.x * 256 + threadIdx.x;   // 524288 total
    int c = (i >> 1) & 511;
    float k = sc[c], t = sh[c];
    uint4 v = *(uint4*)(h + (long)i * 8);
    unsigned int* vp = (unsigned int*)&v;
#pragma unroll
    for (int e = 0; e < 4; e++) {
        float lo = h2f((unsigned short)(vp[e] & 0xffffu));
        float hi = h2f((unsigned short)(vp[e] >> 16));
        lo = fmaf(lo, k, t); lo = lo > 0.f ? lo : 0.f;
        hi = fmaf(hi, k, t); hi = hi > 0.f ? hi : 0.f;
        vp[e] = (unsigned int)f2h(lo) | (((unsigned int)f2h(hi)) << 16);
    }
    *(uint4*)(h + (long)i * 8) = v;
}

// ---------------------------------------------------------------------------
// FC1 fp16 MFMA split-K + reduce
// ---------------------------------------------------------------------------
__global__ __launch_bounds__(256) void fc1_mfma(const unsigned short* __restrict__ Ab,
                                                const unsigned short* __restrict__ Wp,
                                                float* __restrict__ pbuf) {
    __shared__ char lds[2 * 64 * 80];
    const int tid = threadIdx.x;
    const int lane = tid & 63;
    const int wv = tid >> 6;
    const int g = lane >> 4, ln = lane & 15;
    const int ot = blockIdx.x, bt = blockIdx.y, s = blockIdx.z;
    const int b0 = bt * 64;
    const int k0g = s * 1024;

    f32x4 acc[2][4];
#pragma unroll
    for (int c = 0; c < 2; c++)
#pragma unroll
    for (int nf = 0; nf < 4; nf++) acc[c][nf] = (f32x4){0.f, 0.f, 0.f, 0.f};

    for (int k0 = 0; k0 < 1024; k0 += 64) {
        __syncthreads();
        for (int i = tid; i < 512; i += 256) {
            int row = i >> 3, kk = (i >> 2) & 1, seg = i & 3;
            uint4 v = *(const uint4*)(Ab + ((long)(b0 + row) * 8192 + k0g + k0 + kk * 32 + seg * 8));
            *(uint4*)(lds + (kk * 64 + row) * 80 + seg * 16) = v;
        }
        __syncthreads();
#pragma unroll
        for (int kk = 0; kk < 2; kk++) {
            int kt = (k0g + k0) / 32 + kk;
            half8 af[2];
#pragma unroll
            for (int c = 0; c < 2; c++) {
                int mf = ot * 8 + wv * 2 + c;
                af[c] = *(const half8*)(Wp + (((long)kt * 64 + mf) * 64 + lane) * 8);
            }
            half8 bf[4];
#pragma unroll
            for (int nf = 0; nf < 4; nf++)
                bf[nf] = *(const half8*)(lds + (kk * 64 + nf * 16 + ln) * 80 + g * 16);
#pragma unroll
            for (int c = 0; c < 2; c++)
#pragma unroll
            for (int nf = 0; nf < 4; nf++)
                acc[c][nf] = __builtin_amdgcn_mfma_f32_16x16x32_f16(af[c], bf[nf], acc[c][nf], 0, 0, 0);
        }
    }
#pragma unroll
    for (int c = 0; c < 2; c++) {
        int o = ot * 128 + (wv * 2 + c) * 16 + g * 4;
#pragma unroll
        for (int nf = 0; nf < 4; nf++) {
            int b = b0 + nf * 16 + ln;
            *(f32x4*)(pbuf + ((long)s * 256 + b) * 1024 + o) = acc[c][nf];
        }
    }
}

__global__ void fc1_reduce(const float* __restrict__ pbuf, const float* __restrict__ bias,
                           float* __restrict__ out) {
    int idx = blockIdx.x * 256 + threadIdx.x;
    float s = 0.f;
#pragma unroll
    for (int j = 0; j < 8; j++) s += pbuf[(long)j * 262144 + idx];
    s += bias[idx & 1023];
    out[idx] = s > 0.f ? s : 0.f;
}

__global__ void fc2_k(const float* __restrict__ A, const float* __restrict__ W,
                      const float* __restrict__ b2, float* __restrict__ out) {
    int bb = blockIdx.x;
    int tid = threadIdx.x;
    float acc[10];
#pragma unroll
    for (int o = 0; o < 10; o++) acc[o] = 0.f;
    const float* arow = A + (long)bb * 1024;
    for (int k = tid; k < 1024; k += 256) {
        float a = arow[k];
#pragma unroll
        for (int o = 0; o < 10; o++) acc[o] = fmaf(a, W[o * 1024 + k], acc[o]);
    }
#pragma unroll
    for (int o = 0; o < 10; o++)
        for (int off = 32; off > 0; off >>= 1) acc[o] += __shfl_down(acc[o], off);
    __shared__ float red[10][4];
    int wid = tid >> 6, lane = tid & 63;
    if (lane == 0) {
#pragma unroll
        for (int o = 0; o < 10; o++) red[o][wid] = acc[o];
    }
    __syncthreads();
    if (tid < 10)
        out[bb * 10 + tid] = red[tid][0] + red[tid][1] + red[tid][2] + red[tid][3] + b2[tid];
}

// ---------------------------------------------------------------------------
extern "C" void kernel_launch(void* const* d_in, const int* in_sizes, int n_in,
                              void* d_out, int out_size, void* d_ws, size_t ws_size,
                              hipStream_t stream) {
    const float* x  = (const float*)d_in[0];
    const float* a1 = (const float*)d_in[1];  const float* b1 = (const float*)d_in[2];  const float* c1 = (const float*)d_in[3];
    const float* a2 = (const float*)d_in[4];  const float* b2 = (const float*)d_in[5];  const float* c2 = (const float*)d_in[6];
    const float* a3 = (const float*)d_in[7];  const float* b3 = (const float*)d_in[8];  const float* c3 = (const float*)d_in[9];
    const float* a4 = (const float*)d_in[10]; const float* b4 = (const float*)d_in[11]; const float* c4 = (const float*)d_in[12];
    const float* a5 = (const float*)d_in[13]; const float* b5 = (const float*)d_in[14]; const float* c5 = (const float*)d_in[15];
    const float* a6 = (const float*)d_in[16]; const float* b6 = (const float*)d_in[17]; const float* c6 = (const float*)d_in[18];
    const float* g3 = (const float*)d_in[19]; const float* be3 = (const float*)d_in[20];
    const float* g6 = (const float*)d_in[21]; const float* be6 = (const float*)d_in[22];
    const float* fc1w = (const float*)d_in[23]; const float* fc1b = (const float*)d_in[24];
    const float* fc2w = (const float*)d_in[25]; const float* fc2b = (const float*)d_in[26];
    const float* eps3 = (const float*)d_in[27]; const float* eps6 = (const float*)d_in[28];
    (void)in_sizes; (void)n_in; (void)out_size; (void)ws_size;

    float* w = (float*)d_ws;
    size_t off = 0;
    auto alloc = [&](size_t n) { float* p = w + off; off += n; return p; };
    unsigned short* pk2 = (unsigned short*)alloc(147456);
    unsigned short* pk3 = (unsigned short*)alloc(294912);
    unsigned short* pk4 = (unsigned short*)alloc(589824);
    unsigned short* pk5 = (unsigned short*)alloc(1179648);
    unsigned short* pk6 = (unsigned short*)alloc(2359296);
    float* wa1 = alloc(3456); float* wb1 = alloc(3456);
    float* ss2 = alloc(1152); float* ss3 = alloc(2304);
    float* ss5 = alloc(4608); float* ss6 = alloc(4608);
    float* og2 = alloc(32768); float* og3 = alloc(65536);
    float* og5 = alloc(32768); float* og6 = alloc(8192);
    float* part3 = alloc(131072);
    float* part6 = alloc(65536);
    float* sc3 = alloc(256); float* sh3 = alloc(256);
    float* sc6 = alloc(512); float* sh6 = alloc(512);
    float* A  = alloc(16777216);
    float* Bb = alloc(4194304);
    float* Cc = alloc(8388608);
    float* Dd = alloc(2097152);
    float* Ee = alloc(4194304);

    unsigned short* ex1 = (unsigned short*)A;
    unsigned short* pkF = (unsigned short*)A;
    float*          pbuf = A + 4194304;
    unsigned short* ex2 = (unsigned short*)Bb;
    float*          fco = Bb;
    unsigned short* h6b = (unsigned short*)(Bb + 524288);
    unsigned short* h3b = (unsigned short*)Cc;
    unsigned short* ex4 = (unsigned short*)Dd;
    unsigned short* ex5 = (unsigned short*)Ee;

    // ---- prep ----
    prep_w<<<14, 256, 0, stream>>>(a1, b1, wa1, wb1, 3456);
    prep_pack<<<72,  256, 0, stream>>>(a2, b2, pk2, 128, 128, 1, 18432);
    prep_pack<<<144, 256, 0, stream>>>(a3, b3, pk3, 128, 256, 1, 36864);
    prep_pack<<<288, 256, 0, stream>>>(a4, b4, pk4, 256, 256, 0, 73728);
    prep_pack<<<576, 256, 0, stream>>>(a5, b5, pk5, 256, 512, 1, 147456);
    prep_pack<<<1152,256, 0, stream>>>(a6, b6, pk6, 512, 512, 1, 294912);
    prep_s<<<128, 64, 0, stream>>>(a2, ss2, 128);
    prep_s<<<256, 64, 0, stream>>>(a3, ss3, 128);
    prep_s<<<512, 64, 0, stream>>>(a5, ss5, 256);
    prep_s<<<512, 64, 0, stream>>>(a6, ss6, 512);
    prep_ones<<<128, 256, 0, stream>>>(ss2, og2, 128, 16, 16, 32, 32, 2, 32768);
    prep_ones<<<256, 256, 0, stream>>>(ss3, og3, 256, 16, 16, 16, 16, 1, 65536);
    prep_ones<<<128, 256, 0, stream>>>(ss5, og5, 512, 8, 8, 8, 8, 1, 32768);
    prep_ones<<<32,  256, 0, stream>>>(ss6, og6, 512, 4, 4, 8, 8, 2, 8192);

    // ---- network ----
    conv1_k<<<4096, 256, 0, stream>>>(x, wa1, wb1, c1, ex1);
    // L2: [256,32,32,128] -> [256,16,16,128]
    conv_mfma<128,32,32,128,16,16,2, 8,1,128,32,1><<<512, 512, 0, stream>>>(ex1, pk2, c2, og2, nullptr, ex2);
    // L3: -> h3b [256,16,16,256] NHWC fp16 (sampled)
    conv_mfma<128,16,16,256,16,16,1, 8,2,256,64,3><<<512, 512, 0, stream>>>(ex2, pk3, c3, og3, eps3, h3b);
    // FC1 weight pack into A (ex1 dead after L2)
    prep_fc1<<<4096, 256, 0, stream>>>(fc1w, pkF);
    // BN3 (fp16 NHWC, in place)
    bn_part_nhwc<<<256, 256, 0, stream>>>(h3b, part3, 256, 256);
    bn_fin<<<1, 256, 0, stream>>>(part3, g3, be3, sc3, sh3, 256, 256, 1.f / 65536.f);
    bn_app_nhwc<<<8192, 256, 0, stream>>>(h3b, sc3, sh3);
    // L4: [256,16,16,256] -> [256,8,8,256]
    conv_mfma<256,16,16,256, 8, 8,2, 8,1,64,32,0><<<512, 512, 0, stream>>>(h3b, pk4, c4, nullptr, nullptr, ex4);
    // L5: -> [256,8,8,512]
    conv_mfma<256, 8, 8,512, 8, 8,1, 8,2,128,32,1><<<512, 512, 0, stream>>>(ex4, pk5, c5, og5, nullptr, ex5);
    // L6: -> h6b [256,512,4,4] NCHW fp16 (sampled)
    conv_mfma<512, 8, 8,512, 4, 4,2, 4,4,64,32,4><<<256, 512, 0, stream>>>(ex5, pk6, c6, og6, eps6, h6b);
    // BN6 (fp16 NCHW, in place)
    bn_part_nchw<<<64, 512, 0, stream>>>(h6b, part6, 4);
    bn_fin<<<2, 256, 0, stream>>>(part6, g6, be6, sc6, sh6, 512, 64, 1.f / 4096.f);
    bn_app_nchw<<<2048, 256, 0, stream>>>(h6b, sc6, sh6);
    // FC1 + FC2
    fc1_mfma<<<dim3(8, 4, 8), 256, 0, stream>>>(h6b, pkF, pbuf);
    fc1_reduce<<<1024, 256, 0, stream>>>(pbuf, fc1b, fco);
    fc2_k<<<256, 256, 0, stream>>>(fco, fc2w, fc2b, (float*)d_out);
}

// Round 10
// 829.759 us; speedup vs baseline: 1.3050x; 1.0837x over previous
//
#include <hip/hip_runtime.h>
#include <hip/hip_bf16.h>
#include <math.h>

#define EPSV 1e-10f
#define BNEPS 1e-5f
#define INV_SQRT2 0.70710678118654752440f

typedef __attribute__((ext_vector_type(8))) short short8;
typedef __attribute__((ext_vector_type(4))) float f32x4;
typedef _Float16 half8 __attribute__((ext_vector_type(8)));

__device__ __forceinline__ unsigned short f2h(float f) {
    _Float16 h = (_Float16)f;                      // RNE
    return __builtin_bit_cast(unsigned short, h);
}
__device__ __forceinline__ float h2f(unsigned short u) {
    _Float16 h = __builtin_bit_cast(_Float16, u);
    return (float)h;
}

// ---------------------------------------------------------------------------
// L1 weight prep (fp32)
// ---------------------------------------------------------------------------
__global__ void prep_w(const float* __restrict__ a, const float* __restrict__ b,
                       float* __restrict__ WA, float* __restrict__ WB, int n) {
    for (int i = blockIdx.x * blockDim.x + threadIdx.x; i < n; i += gridDim.x * blockDim.x) {
        float p0 = 1.f / (1.f + expf(-a[i]));
        float sb = 1.f / (1.f + expf(-b[i]));
        float p1 = (1.f - p0) * sb;
        float ew = 2.f * p1 - (1.f - p0);
        float ew2 = 1.f - p0;
        WA[i] = ew;
        WB[i] = ew2 - ew * ew;
    }
}

// L1 weights -> MFMA A-fragment order (fp16), K=32 (27 used), 2cv x 8mf
__global__ void prep_packL1(const float* __restrict__ wa, const float* __restrict__ wb,
                            unsigned short* __restrict__ pk) {
    int idx = blockIdx.x * 256 + threadIdx.x;   // 1024 total
    if (idx >= 1024) return;
    int lane = idx & 63;
    int mf = (idx >> 6) & 7;
    int cv = idx >> 9;
    int co = mf * 16 + (lane & 15);
    int k0 = (lane >> 4) * 8;
    const float* src = (cv ? wb : wa) + co * 27;
    unsigned int o[4] = {0, 0, 0, 0};
#pragma unroll
    for (int j = 0; j < 8; j++) {
        int k = k0 + j;
        if (k < 27) {
            unsigned int h = f2h(src[k]);
            o[j >> 1] |= h << ((j & 1) * 16);
        }
    }
    uint4 v; v.x = o[0]; v.y = o[1]; v.z = o[2]; v.w = o[3];
    *(uint4*)(pk + (long)idx * 8) = v;
}

// ---------------------------------------------------------------------------
// Pack ternary-stat weights into MFMA A-fragment order (fp16).
// ---------------------------------------------------------------------------
__global__ void prep_pack(const float* __restrict__ a, const float* __restrict__ b,
                          unsigned short* __restrict__ pk, int Ci, int Co, int ver2, int total) {
    int idx = blockIdx.x * 256 + threadIdx.x;
    if (idx >= total) return;
    int lane = idx & 63;
    int MFg = Co >> 4, NCH = Ci >> 5;
    int mfch = idx >> 6;
    int mf = mfch % MFg;
    int chpos = mfch / MFg;
    int ch = chpos % NCH;
    int pos = chpos / NCH;
    int co = mf * 16 + (lane & 15);
    int cib = ch * 32 + (lane >> 4) * 8;
    unsigned int wa[4], wb[4];
#pragma unroll
    for (int j = 0; j < 8; j++) {
        long s = ((long)co * Ci + cib + j) * 9 + pos;
        float p0 = 1.f / (1.f + expf(-a[s]));
        float sb = 1.f / (1.f + expf(-b[s]));
        float p1 = (1.f - p0) * sb;
        float ew = 2.f * p1 - (1.f - p0);
        float ew2 = 1.f - p0;
        unsigned int ha = f2h(ew);
        unsigned int hb = f2h(ver2 ? ew * ew : ew2 - ew * ew);
        if (j & 1) { wa[j >> 1] |= ha << 16; wb[j >> 1] |= hb << 16; }
        else       { wa[j >> 1] = ha;        wb[j >> 1] = hb; }
    }
    long b0 = (((long)(0 * 9 + pos) * NCH + ch) * MFg + mf) * 64 + lane;
    long b1 = (((long)(1 * 9 + pos) * NCH + ch) * MFg + mf) * 64 + lane;
    uint4 va; va.x = wa[0]; va.y = wa[1]; va.z = wa[2]; va.w = wa[3];
    uint4 vb; vb.x = wb[0]; vb.y = wb[1]; vb.z = wb[2]; vb.w = wb[3];
    *(uint4*)(pk + b0 * 8) = va;
    *(uint4*)(pk + b1 * 8) = vb;
}

// ssum[co][k] = sum_ci sigmoid(-alpha)
__global__ void prep_s(const float* __restrict__ alpha, float* __restrict__ s, int Ci) {
    int co = blockIdx.x;
    int lane = threadIdx.x;
    float acc[9];
#pragma unroll
    for (int k = 0; k < 9; k++) acc[k] = 0.f;
    for (int ci = lane; ci < Ci; ci += 64) {
        const float* p = alpha + ((long)co * Ci + ci) * 9;
#pragma unroll
        for (int k = 0; k < 9; k++) acc[k] += 1.f / (1.f + expf(p[k]));
    }
#pragma unroll
    for (int k = 0; k < 9; k++) {
        for (int off = 32; off > 0; off >>= 1) acc[k] += __shfl_down(acc[k], off);
    }
    if (lane == 0) {
#pragma unroll
        for (int k = 0; k < 9; k++) s[co * 9 + k] = acc[k];
    }
}

__global__ void prep_ones(const float* __restrict__ ssum, float* __restrict__ og,
                          int Co, int Hout, int Wout, int Hin, int Win, int stride, int total) {
    int idx = blockIdx.x * 256 + threadIdx.x;
    if (idx >= total) return;
    int x = idx % Wout, y = (idx / Wout) % Hout, co = idx / (Wout * Hout);
    float s = 0.f;
    for (int ky = 0; ky < 3; ky++) {
        int yi = stride * y - 1 + ky;
        if (yi < 0 || yi >= Hin) continue;
        for (int kx = 0; kx < 3; kx++) {
            int xi = stride * x - 1 + kx;
            if (xi < 0 || xi >= Win) continue;
            s += ssum[co * 9 + ky * 3 + kx];
        }
    }
    og[idx] = s;
}

// ---------------------------------------------------------------------------
// FC1 weight pack: fp32 [1024][8192] -> fp16 A-fragment order
// ---------------------------------------------------------------------------
__global__ void prep_fc1(const float* __restrict__ W, unsigned short* __restrict__ pk) {
    int idx = blockIdx.x * 256 + threadIdx.x;
    int lane = idx & 63;
    int mf = (idx >> 6) & 63;
    int kt = idx >> 12;
    int o = mf * 16 + (lane & 15);
    long k = (long)kt * 32 + (lane >> 4) * 8;
    const float* src = W + (long)o * 8192 + k;
    float4 f0 = *(const float4*)src;
    float4 f1 = *(const float4*)(src + 4);
    uint4 v;
    v.x = (unsigned)f2h(f0.x) | ((unsigned)f2h(f0.y) << 16);
    v.y = (unsigned)f2h(f0.z) | ((unsigned)f2h(f0.w) << 16);
    v.z = (unsigned)f2h(f1.x) | ((unsigned)f2h(f1.y) << 16);
    v.w = (unsigned)f2h(f1.z) | ((unsigned)f2h(f1.w) << 16);
    *(uint4*)(pk + (long)idx * 8) = v;
}

// ---------------------------------------------------------------------------
// L1 im2col: x [256,3,32,32] fp32 -> cols[n][32] fp16, n = b*1024+y*32+x
// k = ci*9 + ky*3 + kx (27 used, 5 zero)
// ---------------------------------------------------------------------------
__global__ void l1_im2col(const float* __restrict__ x, unsigned short* __restrict__ cols) {
    int n = blockIdx.x * 256 + threadIdx.x;   // 262144
    int b = n >> 10, y = (n >> 5) & 31, xx = n & 31;
    unsigned int o[16];
#pragma unroll
    for (int i = 0; i < 16; i++) o[i] = 0;
#pragma unroll
    for (int ci = 0; ci < 3; ci++)
#pragma unroll
    for (int ky = 0; ky < 3; ky++) {
        int yy = y - 1 + ky;
        if (yy < 0 || yy > 31) continue;
#pragma unroll
        for (int kx = 0; kx < 3; kx++) {
            int xc = xx - 1 + kx;
            if (xc < 0 || xc > 31) continue;
            float v = x[((b * 3 + ci) * 32 + yy) * 32 + xc];
            int k = ci * 9 + ky * 3 + kx;
            o[k >> 1] |= ((unsigned int)f2h(v)) << ((k & 1) * 16);
        }
    }
    uint4* dst = (uint4*)(cols + (long)n * 32);
    uint4 v0; v0.x = o[0];  v0.y = o[1];  v0.z = o[2];  v0.w = o[3];
    uint4 v1; v1.x = o[4];  v1.y = o[5];  v1.z = o[6];  v1.w = o[7];
    uint4 v2; v2.x = o[8];  v2.y = o[9];  v2.z = o[10]; v2.w = o[11];
    uint4 v3; v3.x = o[12]; v3.y = o[13]; v3.z = o[14]; v3.w = o[15];
    dst[0] = v0; dst[1] = v1; dst[2] = v2; dst[3] = v3;
}

// ---------------------------------------------------------------------------
// L1 MFMA GEMM: out[n][128] = erf((cols@wa + bias) / sqrt(cols^2@wb + eps) /sqrt2)
// block 512 thr (wm2 x wn4), NTILE=128, K=32 single step.
// ---------------------------------------------------------------------------
__global__ __launch_bounds__(512) void conv1_mfma(const unsigned short* __restrict__ cols,
        const unsigned short* __restrict__ Wp, const float* __restrict__ bias,
        unsigned short* __restrict__ out) {
    constexpr int LINE = 80;     // 32 halfs + pad
    constexpr int TSTR = 136;
    __shared__ char lds[128 * TSTR * 2];   // 34816 (>= stage 128*80)
    const int tid = threadIdx.x, lane = tid & 63, wv = tid >> 6;
    const int wm = wv & 1, wn = wv >> 1;
    const int g = lane >> 4, ln = lane & 15;
    const long n0 = (long)blockIdx.x * 128;

    // stage cols rows
    for (int i = tid; i < 128 * 4; i += 512) {
        int r = i >> 2, c = i & 3;
        uint4 v = *(const uint4*)(cols + (n0 + r) * 32 + c * 8);
        *(uint4*)(lds + r * LINE + c * 16) = v;
    }
    __syncthreads();

    half8 af[2][4];
#pragma unroll
    for (int cv = 0; cv < 2; cv++)
#pragma unroll
    for (int m = 0; m < 4; m++)
        af[cv][m] = *(const half8*)(Wp + ((long)((cv * 8 + wm * 4 + m) * 64 + lane)) * 8);

    f32x4 accA[4][2], accB[4][2];
#pragma unroll
    for (int m = 0; m < 4; m++)
#pragma unroll
    for (int nf = 0; nf < 2; nf++) {
        accA[m][nf] = (f32x4){0.f, 0.f, 0.f, 0.f};
        accB[m][nf] = (f32x4){0.f, 0.f, 0.f, 0.f};
    }
#pragma unroll
    for (int nf = 0; nf < 2; nf++) {
        int r = wn * 32 + nf * 16 + ln;
        half8 b1 = *(const half8*)(lds + r * LINE + g * 16);
        half8 b2 = b1 * b1;
#pragma unroll
        for (int m = 0; m < 4; m++) {
            accA[m][nf] = __builtin_amdgcn_mfma_f32_16x16x32_f16(af[0][m], b1, accA[m][nf], 0, 0, 0);
            accB[m][nf] = __builtin_amdgcn_mfma_f32_16x16x32_f16(af[1][m], b2, accB[m][nf], 0, 0, 0);
        }
    }
    __syncthreads();
    // erf epilogue -> LDS transpose
#pragma unroll
    for (int m = 0; m < 4; m++) {
        int cob = (wm * 4 + m) * 16 + g * 4;
#pragma unroll
        for (int nf = 0; nf < 2; nf++) {
            int nl = wn * 32 + nf * 16 + ln;
            unsigned int pk2[2];
#pragma unroll
            for (int r = 0; r < 4; r++) {
                float mm = accA[m][nf][r] + bias[cob + r];
                float vv = accB[m][nf][r];
                unsigned int hv = f2h(erff(mm * rsqrtf(vv + EPSV) * INV_SQRT2));
                if (r & 1) pk2[r >> 1] |= hv << 16; else pk2[r >> 1] = hv;
            }
            *(unsigned int*)(lds + (nl * TSTR + cob) * 2) = pk2[0];
            *(unsigned int*)(lds + (nl * TSTR + cob) * 2 + 4) = pk2[1];
        }
    }
    __syncthreads();
    for (int i = tid; i < 128 * 16; i += 512) {
        int nl = i >> 4, c8 = (i & 15) * 8;
        uint4 v = *(const uint4*)(lds + (nl * TSTR + c8) * 2);
        *(uint4*)(out + (n0 + nl) * 128 + c8) = v;
    }
}

// ---------------------------------------------------------------------------
// MFMA implicit-GEMM fused LRnet conv. NHWC fp16 input. 512 thr (wm2 x wn4).
// MODE 0: lrconv  -> erf -> NHWC fp16   (v = convB)
// MODE 1: ver2    -> erf -> NHWC fp16   (v = ones - convB)
// MODE 3: ver2 + sample -> NHWC fp16    (out = m + sqrt(v+eps)*epsb)
// MODE 4: ver2 + sample -> NCHW fp16
// ---------------------------------------------------------------------------
template<int Ci, int Hin, int Win, int Co, int Hout, int Wout, int STRIDE,
         int ROWS, int IPB, int NTILE, int CHUNK, int MODE>
__global__ __launch_bounds__(512) void conv_mfma(
    const unsigned short* __restrict__ in,
    const unsigned short* __restrict__ wpk,
    const float* __restrict__ bias,
    const float* __restrict__ ones_g,
    const float* __restrict__ epsb,
    void* __restrict__ outp)
{
    constexpr int BLK = 512;
    constexpr int MTILE = 128;
    constexpr int PROWS = STRIDE * (ROWS - 1) + 3;
    constexpr int PW = Win + 2;
    constexpr int POS = IPB * PROWS * PW;
    constexpr int NCH32 = Ci / 32;
    constexpr int NCHL = Ci / CHUNK;
    constexpr int KS = CHUNK / 32;
    constexpr int MFg = Co / 16;
    constexpr int NF = NTILE / 16;
    constexpr int WMF = 4;
    constexpr int WNF = NF / 4;
    constexpr int CT = Co / MTILE;
    constexpr int RG = Hout / ROWS;
    constexpr int LINE = CHUNK * 2 + 16;
    constexpr int TSTR = MTILE + 8;
    constexpr int PASSN = (NTILE < 128) ? NTILE : 128;
    constexpr int NPASS = (MODE == 4) ? 0 : NTILE / PASSN;
    constexpr int STAGE_B = POS * LINE;
    constexpr int TR_B = (MODE == 4) ? 0 : PASSN * TSTR * 2;
    constexpr int LDS_B = STAGE_B > TR_B ? STAGE_B : TR_B;
    static_assert(8 % CT == 0, "ct swizzle");
    static_assert(WNF * 4 == NF, "wnf");
    static_assert(NCHL * CHUNK == Ci, "chunk");
    static_assert(LDS_B <= 65536, "lds");
    __shared__ char lds[LDS_B];

    const int tid = threadIdx.x;
    const int lane = tid & 63;
    const int wv = tid >> 6;
    const int wm = wv & 1, wn = wv >> 1;
    const int g = lane >> 4, ln = lane & 15;

    const int bid = blockIdx.x;
    const int xcd = bid & 7;
    constexpr int XPC = 8 / CT;
    const int ct = xcd % CT;
    const int nt = (bid >> 3) * XPC + xcd / CT;
    const int b0 = (nt / RG) * IPB;
    const int y0 = (nt % RG) * ROWS;

    int pbase[WNF];
#pragma unroll
    for (int nf = 0; nf < WNF; nf++) {
        int n = (wn * WNF + nf) * 16 + ln;
        int img = n / (ROWS * Wout);
        int rem = n % (ROWS * Wout);
        int yr = rem / Wout, xo = rem % Wout;
        pbase[nf] = (img * PROWS + STRIDE * yr) * PW + STRIDE * xo;
    }

    f32x4 accA[WMF][WNF], accB[WMF][WNF];
#pragma unroll
    for (int mf = 0; mf < WMF; mf++)
#pragma unroll
    for (int nf = 0; nf < WNF; nf++) {
        accA[mf][nf] = (f32x4){0.f, 0.f, 0.f, 0.f};
        accB[mf][nf] = (f32x4){0.f, 0.f, 0.f, 0.f};
    }

    const unsigned short* wbase = wpk + ((long)(ct * 8 + wm * WMF) * 64 + lane) * 8;

    for (int ch = 0; ch < NCHL; ch++) {
        // ---- stage CHUNK channels (fp16) into LDS ----
        for (int i = tid; i < POS * (CHUNK / 8); i += BLK) {
            int p = i / (CHUNK / 8), c = i % (CHUNK / 8);
            int img = p / (PROWS * PW);
            int r = p % (PROWS * PW);
            int prow = r / PW, px = r % PW;
            int yin = STRIDE * y0 - 1 + prow;
            int xin = px - 1;
            uint4 v; v.x = 0; v.y = 0; v.z = 0; v.w = 0;
            if (yin >= 0 && yin < Hin && xin >= 0 && xin < Win) {
                long a = (((long)(b0 + img) * Hin + yin) * Win + xin) * Ci + ch * CHUNK + c * 8;
                v = *(const uint4*)(in + a);
            }
            *(uint4*)(lds + p * LINE + c * 16) = v;
        }
        __syncthreads();
        // ---- 9 kernel positions x KS k-substeps ----
#pragma unroll 3
        for (int pos = 0; pos < 9; pos++) {
            const int ky = pos / 3, kx = pos % 3;
#pragma unroll
            for (int ks = 0; ks < KS; ks++) {
                const int ch32 = ch * KS + ks;
                half8 af[2][WMF];
#pragma unroll
                for (int cv = 0; cv < 2; cv++)
#pragma unroll
                for (int mf = 0; mf < WMF; mf++)
                    af[cv][mf] = *(const half8*)(wbase +
                        ((long)(((cv * 9 + pos) * NCH32 + ch32) * MFg + mf)) * 512);
#pragma unroll
                for (int nf = 0; nf < WNF; nf++) {
                    int po = (pbase[nf] + ky * PW + kx) * LINE + ks * 64 + g * 16;
                    half8 b1 = *(const half8*)(lds + po);
                    half8 b2 = b1 * b1;               // 4x v_pk_mul_f16
#pragma unroll
                    for (int mf = 0; mf < WMF; mf++) {
                        accA[mf][nf] = __builtin_amdgcn_mfma_f32_16x16x32_f16(af[0][mf], b1, accA[mf][nf], 0, 0, 0);
                        accB[mf][nf] = __builtin_amdgcn_mfma_f32_16x16x32_f16(af[1][mf], b2, accB[mf][nf], 0, 0, 0);
                    }
                }
            }
        }
        __syncthreads();
    }

    // ---- epilogue ----
    if constexpr (MODE == 4) {
        unsigned short* out = (unsigned short*)outp;
#pragma unroll
        for (int mf = 0; mf < WMF; mf++) {
            int co = ct * MTILE + (wm * WMF + mf) * 16 + g * 4;
#pragma unroll
            for (int nf = 0; nf < WNF; nf++) {
                int n = (wn * WNF + nf) * 16 + ln;
                int img = n / (ROWS * Wout), rem = n % (ROWS * Wout);
                int y = y0 + rem / Wout, x = rem % Wout;
                int b = b0 + img;
#pragma unroll
                for (int r = 0; r < 4; r++) {
                    int c = co + r;
                    float m = accA[mf][nf][r] + bias[c];
                    float v = ones_g[(c * Hout + y) * Wout + x] - accB[mf][nf][r];
                    long oi = (((long)b * Co + c) * Hout + y) * Wout + x;
                    out[oi] = f2h(m + sqrtf(v + EPSV) * epsb[oi]);
                }
            }
        }
    } else {
        unsigned short* out = (unsigned short*)outp;
#pragma unroll
        for (int pass = 0; pass < NPASS; pass++) {
            __syncthreads();
#pragma unroll
            for (int mf = 0; mf < WMF; mf++) {
                int cob = (wm * WMF + mf) * 16 + g * 4;
                int cg = ct * MTILE + cob;
#pragma unroll
                for (int nf = 0; nf < WNF; nf++) {
                    int nb = (wn * WNF + nf) * 16;
                    if (nb < pass * PASSN || nb >= (pass + 1) * PASSN) continue;
                    int n = nb + ln;
                    int img = n / (ROWS * Wout), rem = n % (ROWS * Wout);
                    int y = y0 + rem / Wout, x = rem % Wout;
                    int b = b0 + img;
                    unsigned int pk2[2];
#pragma unroll
                    for (int r = 0; r < 4; r++) {
                        int c = cg + r;
                        float m = accA[mf][nf][r] + bias[c];
                        float val;
                        if constexpr (MODE == 0) {
                            val = erff(m * rsqrtf(accB[mf][nf][r] + EPSV) * INV_SQRT2);
                        } else if constexpr (MODE == 1) {
                            float v = ones_g[(c * Hout + y) * Wout + x] - accB[mf][nf][r];
                            val = erff(m * rsqrtf(v + EPSV) * INV_SQRT2);
                        } else { // MODE 3
                            float v = ones_g[(c * Hout + y) * Wout + x] - accB[mf][nf][r];
                            float ev = epsb[(((long)b * Co + c) * Hout + y) * Wout + x];
                            val = m + sqrtf(v + EPSV) * ev;
                        }
                        unsigned int hv = f2h(val);
                        if (r & 1) pk2[r >> 1] |= hv << 16; else pk2[r >> 1] = hv;
                    }
                    int nl = n - pass * PASSN;
                    *(unsigned int*)(lds + (nl * TSTR + cob) * 2) = pk2[0];
                    *(unsigned int*)(lds + (nl * TSTR + cob) * 2 + 4) = pk2[1];
                }
            }
            __syncthreads();
            for (int i = tid; i < PASSN * (MTILE / 8); i += BLK) {
                int nl = i / (MTILE / 8);
                int n = pass * PASSN + nl;
                int c8 = (i % (MTILE / 8)) * 8;
                int img = n / (ROWS * Wout), rem = n % (ROWS * Wout);
                int y = y0 + rem / Wout, x = rem % Wout;
                int b = b0 + img;
                uint4 val = *(const uint4*)(lds + (nl * TSTR + c8) * 2);
                long oa = (((long)b * Hout + y) * Wout + x) * Co + ct * MTILE + c8;
                *(uint4*)(out + oa) = val;
            }
        }
    }
}

// ---------------------------------------------------------------------------
// BatchNorm (fp16 activations, partial-sum based, no atomics)
// ---------------------------------------------------------------------------
__global__ void bn_part_nhwc(const unsigned short* __restrict__ h, float* __restrict__ part,
                             int C, int rpc) {
    int c = threadIdx.x;
    long r0 = (long)blockIdx.x * rpc;
    float s = 0.f, s2 = 0.f;
    for (int r = 0; r < rpc; r++) {
        float v = h2f(h[(r0 + r) * C + c]);
        s += v; s2 += v * v;
    }
    part[(long)blockIdx.x * 2 * C + c] = s;
    part[(long)blockIdx.x * 2 * C + C + c] = s2;
}

__global__ void bn_part_nchw(const unsigned short* __restrict__ h, float* __restrict__ part,
                             int ipc) {
    int c = threadIdx.x;
    int b0 = blockIdx.x * ipc;
    float s = 0.f, s2 = 0.f;
    for (int b = 0; b < ipc; b++) {
        const unsigned short* p = h + ((long)(b0 + b) * 512 + c) * 16;
        uint4 v0 = *(const uint4*)p;
        uint4 v1 = *(const uint4*)(p + 8);
        unsigned int* vp0 = (unsigned int*)&v0;
        unsigned int* vp1 = (unsigned int*)&v1;
#pragma unroll
        for (int e = 0; e < 4; e++) {
            float a = h2f((unsigned short)(vp0[e] & 0xffffu)), bb = h2f((unsigned short)(vp0[e] >> 16));
            float cc = h2f((unsigned short)(vp1[e] & 0xffffu)), d = h2f((unsigned short)(vp1[e] >> 16));
            s += a + bb + cc + d;
            s2 += a * a + bb * bb + cc * cc + d * d;
        }
    }
    part[(long)blockIdx.x * 1024 + c] = s;
    part[(long)blockIdx.x * 1024 + 512 + c] = s2;
}

__global__ void bn_fin(const float* __restrict__ part, const float* __restrict__ gamma,
                       const float* __restrict__ beta, float* __restrict__ sc,
                       float* __restrict__ sh, int C, int chunks, float invN) {
    int c = blockIdx.x * 256 + threadIdx.x;
    if (c >= C) return;
    float s = 0.f, s2 = 0.f;
    for (int j = 0; j < chunks; j++) {
        s += part[(long)j * 2 * C + c];
        s2 += part[(long)j * 2 * C + C + c];
    }
    float mean = s * invN;
    float var = s2 * invN - mean * mean;
    float k = gamma[c] * rsqrtf(var + BNEPS);
    sc[c] = k;
    sh[c] = beta[c] - mean * k;
}

__global__ void bn_app_nhwc(unsigned short* __restrict__ h, const float* __restrict__ sc,
                            const float* __restrict__ sh) {
    int i = blockIdx.x * 256 + threadIdx.x;   // 2097152 total
    int cb = (i & 31) * 8;
    uint4 v = *(uint4*)(h + (long)i * 8);
    float4 s0 = *(const float4*)(sc + cb), s1 = *(const float4*)(sc + cb + 4);
    float4 t0 = *(const float4*)(sh + cb), t1 = *(const float4*)(sh + cb + 4);
    float scl[8] = {s0.x, s0.y, s0.z, s0.w, s1.x, s1.y, s1.z, s1.w};
    float shf[8] = {t0.x, t0.y, t0.z, t0.w, t1.x, t1.y, t1.z, t1.w};
    unsigned int* vp = (unsigned int*)&v;
#pragma unroll
    for (int e = 0; e < 4; e++) {
        float lo = h2f((unsigned short)(vp[e] & 0xffffu));
        float hi = h2f((unsigned short)(vp[e] >> 16));
        lo = fmaf(lo, scl[2 * e], shf[2 * e]);     lo = lo > 0.f ? lo : 0.f;
        hi = fmaf(hi, scl[2 * e + 1], shf[2 * e + 1]); hi = hi > 0.f ? hi : 0.f;
        vp[e] = (unsigned int)f2h(lo) | (((unsigned int)f2h(hi)) << 16);
    }
    *(uint4*)(h + (long)i * 8) = v;
}

__global__ void bn_app_nchw(unsigned short* __restrict__ h, const float* __restrict__ sc,
                            const float* __restrict__ sh) {
    int i = blockIdx.x * 256 + threadIdx.x;   // 524288 total
    int c = (i >> 1) & 511;
    float k = sc[c], t = sh[c];
    uint4 v = *(uint4*)(h + (long)i * 8);
    unsigned int* vp = (unsigned int*)&v;
#pragma unroll
    for (int e = 0; e < 4; e++) {
        float lo = h2f((unsigned short)(vp[e] & 0xffffu));
        float hi = h2f((unsigned short)(vp[e] >> 16));
        lo = fmaf(lo, k, t); lo = lo > 0.f ? lo : 0.f;
        hi = fmaf(hi, k, t); hi = hi > 0.f ? hi : 0.f;
        vp[e] = (unsigned int)f2h(lo) | (((unsigned int)f2h(hi)) << 16);
    }
    *(uint4*)(h + (long)i * 8) = v;
}

// ---------------------------------------------------------------------------
// FC1 fp16 MFMA split-K + reduce
// ---------------------------------------------------------------------------
__global__ __launch_bounds__(256) void fc1_mfma(const unsigned short* __restrict__ Ab,
                                                const unsigned short* __restrict__ Wp,
                                                float* __restrict__ pbuf) {
    __shared__ char lds[2 * 64 * 80];
    const int tid = threadIdx.x;
    const int lane = tid & 63;
    const int wv = tid >> 6;
    const int g = lane >> 4, ln = lane & 15;
    const int ot = blockIdx.x, bt = blockIdx.y, s = blockIdx.z;
    const int b0 = bt * 64;
    const int k0g = s * 1024;

    f32x4 acc[2][4];
#pragma unroll
    for (int c = 0; c < 2; c++)
#pragma unroll
    for (int nf = 0; nf < 4; nf++) acc[c][nf] = (f32x4){0.f, 0.f, 0.f, 0.f};

    for (int k0 = 0; k0 < 1024; k0 += 64) {
        __syncthreads();
        for (int i = tid; i < 512; i += 256) {
            int row = i >> 3, kk = (i >> 2) & 1, seg = i & 3;
            uint4 v = *(const uint4*)(Ab + ((long)(b0 + row) * 8192 + k0g + k0 + kk * 32 + seg * 8));
            *(uint4*)(lds + (kk * 64 + row) * 80 + seg * 16) = v;
        }
        __syncthreads();
#pragma unroll
        for (int kk = 0; kk < 2; kk++) {
            int kt = (k0g + k0) / 32 + kk;
            half8 af[2];
#pragma unroll
            for (int c = 0; c < 2; c++) {
                int mf = ot * 8 + wv * 2 + c;
                af[c] = *(const half8*)(Wp + (((long)kt * 64 + mf) * 64 + lane) * 8);
            }
            half8 bf[4];
#pragma unroll
            for (int nf = 0; nf < 4; nf++)
                bf[nf] = *(const half8*)(lds + (kk * 64 + nf * 16 + ln) * 80 + g * 16);
#pragma unroll
            for (int c = 0; c < 2; c++)
#pragma unroll
            for (int nf = 0; nf < 4; nf++)
                acc[c][nf] = __builtin_amdgcn_mfma_f32_16x16x32_f16(af[c], bf[nf], acc[c][nf], 0, 0, 0);
        }
    }
#pragma unroll
    for (int c = 0; c < 2; c++) {
        int o = ot * 128 + (wv * 2 + c) * 16 + g * 4;
#pragma unroll
        for (int nf = 0; nf < 4; nf++) {
            int b = b0 + nf * 16 + ln;
            *(f32x4*)(pbuf + ((long)s * 256 + b) * 1024 + o) = acc[c][nf];
        }
    }
}

__global__ void fc1_reduce(const float* __restrict__ pbuf, const float* __restrict__ bias,
                           float* __restrict__ out) {
    int idx = blockIdx.x * 256 + threadIdx.x;
    float s = 0.f;
#pragma unroll
    for (int j = 0; j < 8; j++) s += pbuf[(long)j * 262144 + idx];
    s += bias[idx & 1023];
    out[idx] = s > 0.f ? s : 0.f;
}

__global__ void fc2_k(const float* __restrict__ A, const float* __restrict__ W,
                      const float* __restrict__ b2, float* __restrict__ out) {
    int bb = blockIdx.x;
    int tid = threadIdx.x;
    float acc[10];
#pragma unroll
    for (int o = 0; o < 10; o++) acc[o] = 0.f;
    const float* arow = A + (long)bb * 1024;
    for (int k = tid; k < 1024; k += 256) {
        float a = arow[k];
#pragma unroll
        for (int o = 0; o < 10; o++) acc[o] = fmaf(a, W[o * 1024 + k], acc[o]);
    }
#pragma unroll
    for (int o = 0; o < 10; o++)
        for (int off = 32; off > 0; off >>= 1) acc[o] += __shfl_down(acc[o], off);
    __shared__ float red[10][4];
    int wid = tid >> 6, lane = tid & 63;
    if (lane == 0) {
#pragma unroll
        for (int o = 0; o < 10; o++) red[o][wid] = acc[o];
    }
    __syncthreads();
    if (tid < 10)
        out[bb * 10 + tid] = red[tid][0] + red[tid][1] + red[tid][2] + red[tid][3] + b2[tid];
}

// ---------------------------------------------------------------------------
extern "C" void kernel_launch(void* const* d_in, const int* in_sizes, int n_in,
                              void* d_out, int out_size, void* d_ws, size_t ws_size,
                              hipStream_t stream) {
    const float* x  = (const float*)d_in[0];
    const float* a1 = (const float*)d_in[1];  const float* b1 = (const float*)d_in[2];  const float* c1 = (const float*)d_in[3];
    const float* a2 = (const float*)d_in[4];  const float* b2 = (const float*)d_in[5];  const float* c2 = (const float*)d_in[6];
    const float* a3 = (const float*)d_in[7];  const float* b3 = (const float*)d_in[8];  const float* c3 = (const float*)d_in[9];
    const float* a4 = (const float*)d_in[10]; const float* b4 = (const float*)d_in[11]; const float* c4 = (const float*)d_in[12];
    const float* a5 = (const float*)d_in[13]; const float* b5 = (const float*)d_in[14]; const float* c5 = (const float*)d_in[15];
    const float* a6 = (const float*)d_in[16]; const float* b6 = (const float*)d_in[17]; const float* c6 = (const float*)d_in[18];
    const float* g3 = (const float*)d_in[19]; const float* be3 = (const float*)d_in[20];
    const float* g6 = (const float*)d_in[21]; const float* be6 = (const float*)d_in[22];
    const float* fc1w = (const float*)d_in[23]; const float* fc1b = (const float*)d_in[24];
    const float* fc2w = (const float*)d_in[25]; const float* fc2b = (const float*)d_in[26];
    const float* eps3 = (const float*)d_in[27]; const float* eps6 = (const float*)d_in[28];
    (void)in_sizes; (void)n_in; (void)out_size; (void)ws_size;

    float* w = (float*)d_ws;
    size_t off = 0;
    auto alloc = [&](size_t n) { float* p = w + off; off += n; return p; };
    unsigned short* pk2 = (unsigned short*)alloc(147456);
    unsigned short* pk3 = (unsigned short*)alloc(294912);
    unsigned short* pk4 = (unsigned short*)alloc(589824);
    unsigned short* pk5 = (unsigned short*)alloc(1179648);
    unsigned short* pk6 = (unsigned short*)alloc(2359296);
    unsigned short* pkL1 = (unsigned short*)alloc(4096);
    float* wa1 = alloc(3456); float* wb1 = alloc(3456);
    float* ss2 = alloc(1152); float* ss3 = alloc(2304);
    float* ss5 = alloc(4608); float* ss6 = alloc(4608);
    float* og2 = alloc(32768); float* og3 = alloc(65536);
    float* og5 = alloc(32768); float* og6 = alloc(8192);
    float* part3 = alloc(131072);
    float* part6 = alloc(65536);
    float* sc3 = alloc(256); float* sh3 = alloc(256);
    float* sc6 = alloc(512); float* sh6 = alloc(512);
    float* A  = alloc(16777216);
    float* Bb = alloc(4194304);
    float* Cc = alloc(8388608);
    float* Dd = alloc(2097152);
    float* Ee = alloc(4194304);

    unsigned short* ex1 = (unsigned short*)A;
    unsigned short* pkF = (unsigned short*)A;
    float*          pbuf = A + 4194304;
    unsigned short* ex2 = (unsigned short*)Bb;
    float*          fco = Bb;
    unsigned short* h6b = (unsigned short*)(Bb + 524288);
    unsigned short* colsL1 = (unsigned short*)Cc;   // dead before h3b written
    unsigned short* h3b = (unsigned short*)Cc;
    unsigned short* ex4 = (unsigned short*)Dd;
    unsigned short* ex5 = (unsigned short*)Ee;

    // ---- prep ----
    prep_w<<<14, 256, 0, stream>>>(a1, b1, wa1, wb1, 3456);
    prep_packL1<<<4, 256, 0, stream>>>(wa1, wb1, pkL1);
    prep_pack<<<72,  256, 0, stream>>>(a2, b2, pk2, 128, 128, 1, 18432);
    prep_pack<<<144, 256, 0, stream>>>(a3, b3, pk3, 128, 256, 1, 36864);
    prep_pack<<<288, 256, 0, stream>>>(a4, b4, pk4, 256, 256, 0, 73728);
    prep_pack<<<576, 256, 0, stream>>>(a5, b5, pk5, 256, 512, 1, 147456);
    prep_pack<<<1152,256, 0, stream>>>(a6, b6, pk6, 512, 512, 1, 294912);
    prep_s<<<128, 64, 0, stream>>>(a2, ss2, 128);
    prep_s<<<256, 64, 0, stream>>>(a3, ss3, 128);
    prep_s<<<512, 64, 0, stream>>>(a5, ss5, 256);
    prep_s<<<512, 64, 0, stream>>>(a6, ss6, 512);
    prep_ones<<<128, 256, 0, stream>>>(ss2, og2, 128, 16, 16, 32, 32, 2, 32768);
    prep_ones<<<256, 256, 0, stream>>>(ss3, og3, 256, 16, 16, 16, 16, 1, 65536);
    prep_ones<<<128, 256, 0, stream>>>(ss5, og5, 512, 8, 8, 8, 8, 1, 32768);
    prep_ones<<<32,  256, 0, stream>>>(ss6, og6, 512, 4, 4, 8, 8, 2, 8192);

    // ---- network ----
    // L1: im2col + MFMA GEMM -> ex1 [256,32,32,128] NHWC fp16
    l1_im2col<<<1024, 256, 0, stream>>>(x, colsL1);
    conv1_mfma<<<2048, 512, 0, stream>>>(colsL1, pkL1, c1, ex1);
    // L2: [256,32,32,128] -> [256,16,16,128]
    conv_mfma<128,32,32,128,16,16,2, 8,1,128,32,1><<<512, 512, 0, stream>>>(ex1, pk2, c2, og2, nullptr, ex2);
    // L3: -> h3b [256,16,16,256] NHWC fp16 (sampled)
    conv_mfma<128,16,16,256,16,16,1, 8,2,256,64,3><<<512, 512, 0, stream>>>(ex2, pk3, c3, og3, eps3, h3b);
    // FC1 weight pack into A (ex1 dead after L2)
    prep_fc1<<<4096, 256, 0, stream>>>(fc1w, pkF);
    // BN3 (fp16 NHWC, in place)
    bn_part_nhwc<<<256, 256, 0, stream>>>(h3b, part3, 256, 256);
    bn_fin<<<1, 256, 0, stream>>>(part3, g3, be3, sc3, sh3, 256, 256, 1.f / 65536.f);
    bn_app_nhwc<<<8192, 256, 0, stream>>>(h3b, sc3, sh3);
    // L4: [256,16,16,256] -> [256,8,8,256]
    conv_mfma<256,16,16,256, 8, 8,2, 8,1,64,32,0><<<512, 512, 0, stream>>>(h3b, pk4, c4, nullptr, nullptr, ex4);
    // L5: -> [256,8,8,512]
    conv_mfma<256, 8, 8,512, 8, 8,1, 8,2,128,32,1><<<512, 512, 0, stream>>>(ex4, pk5, c5, og5, nullptr, ex5);
    // L6: -> h6b [256,512,4,4] NCHW fp16 (sampled)
    conv_mfma<512, 8, 8,512, 4, 4,2, 4,4,64,32,4><<<256, 512, 0, stream>>>(ex5, pk6, c6, og6, eps6, h6b);
    // BN6 (fp16 NCHW, in place)
    bn_part_nchw<<<64, 512, 0, stream>>>(h6b, part6, 4);
    bn_fin<<<2, 256, 0, stream>>>(part6, g6, be6, sc6, sh6, 512, 64, 1.f / 4096.f);
    bn_app_nchw<<<2048, 256, 0, stream>>>(h6b, sc6, sh6);
    // FC1 + FC2
    fc1_mfma<<<dim3(8, 4, 8), 256, 0, stream>>>(h6b, pkF, pbuf);
    fc1_reduce<<<1024, 256, 0, stream>>>(pbuf, fc1b, fco);
    fc2_k<<<256, 256, 0, stream>>>(fco, fc2w, fc2b, (float*)d_out);
}

// Round 11
// 793.432 us; speedup vs baseline: 1.3648x; 1.0458x over previous
//
#include <hip/hip_runtime.h>
#include <hip/hip_bf16.h>
#include <math.h>

#define EPSV 1e-10f
#define BNEPS 1e-5f
#define INV_SQRT2 0.70710678118654752440f

typedef __attribute__((ext_vector_type(8))) short short8;
typedef __attribute__((ext_vector_type(4))) float f32x4;
typedef _Float16 half8 __attribute__((ext_vector_type(8)));

__device__ __forceinline__ unsigned short f2h(float f) {
    _Float16 h = (_Float16)f;                      // RNE
    return __builtin_bit_cast(unsigned short, h);
}
__device__ __forceinline__ float h2f(unsigned short u) {
    _Float16 h = __builtin_bit_cast(_Float16, u);
    return (float)h;
}

// ---------------------------------------------------------------------------
// L1 weight prep (fp32)
// ---------------------------------------------------------------------------
__global__ void prep_w(const float* __restrict__ a, const float* __restrict__ b,
                       float* __restrict__ WA, float* __restrict__ WB, int n) {
    for (int i = blockIdx.x * blockDim.x + threadIdx.x; i < n; i += gridDim.x * blockDim.x) {
        float p0 = 1.f / (1.f + expf(-a[i]));
        float sb = 1.f / (1.f + expf(-b[i]));
        float p1 = (1.f - p0) * sb;
        float ew = 2.f * p1 - (1.f - p0);
        float ew2 = 1.f - p0;
        WA[i] = ew;
        WB[i] = ew2 - ew * ew;
    }
}

// L1 weights -> MFMA A-fragment order (fp16), K=32 (27 used), 2cv x 8mf
__global__ void prep_packL1(const float* __restrict__ wa, const float* __restrict__ wb,
                            unsigned short* __restrict__ pk) {
    int idx = blockIdx.x * 256 + threadIdx.x;   // 1024 total
    if (idx >= 1024) return;
    int lane = idx & 63;
    int mf = (idx >> 6) & 7;
    int cv = idx >> 9;
    int co = mf * 16 + (lane & 15);
    int k0 = (lane >> 4) * 8;
    const float* src = (cv ? wb : wa) + co * 27;
    unsigned int o[4] = {0, 0, 0, 0};
#pragma unroll
    for (int j = 0; j < 8; j++) {
        int k = k0 + j;
        if (k < 27) {
            unsigned int h = f2h(src[k]);
            o[j >> 1] |= h << ((j & 1) * 16);
        }
    }
    uint4 v; v.x = o[0]; v.y = o[1]; v.z = o[2]; v.w = o[3];
    *(uint4*)(pk + (long)idx * 8) = v;
}

// ---------------------------------------------------------------------------
// Pack ternary-stat weights into MFMA A-fragment order (fp16).
// ---------------------------------------------------------------------------
__global__ void prep_pack(const float* __restrict__ a, const float* __restrict__ b,
                          unsigned short* __restrict__ pk, int Ci, int Co, int ver2, int total) {
    int idx = blockIdx.x * 256 + threadIdx.x;
    if (idx >= total) return;
    int lane = idx & 63;
    int MFg = Co >> 4, NCH = Ci >> 5;
    int mfch = idx >> 6;
    int mf = mfch % MFg;
    int chpos = mfch / MFg;
    int ch = chpos % NCH;
    int pos = chpos / NCH;
    int co = mf * 16 + (lane & 15);
    int cib = ch * 32 + (lane >> 4) * 8;
    unsigned int wa[4], wb[4];
#pragma unroll
    for (int j = 0; j < 8; j++) {
        long s = ((long)co * Ci + cib + j) * 9 + pos;
        float p0 = 1.f / (1.f + expf(-a[s]));
        float sb = 1.f / (1.f + expf(-b[s]));
        float p1 = (1.f - p0) * sb;
        float ew = 2.f * p1 - (1.f - p0);
        float ew2 = 1.f - p0;
        unsigned int ha = f2h(ew);
        unsigned int hb = f2h(ver2 ? ew * ew : ew2 - ew * ew);
        if (j & 1) { wa[j >> 1] |= ha << 16; wb[j >> 1] |= hb << 16; }
        else       { wa[j >> 1] = ha;        wb[j >> 1] = hb; }
    }
    long b0 = (((long)(0 * 9 + pos) * NCH + ch) * MFg + mf) * 64 + lane;
    long b1 = (((long)(1 * 9 + pos) * NCH + ch) * MFg + mf) * 64 + lane;
    uint4 va; va.x = wa[0]; va.y = wa[1]; va.z = wa[2]; va.w = wa[3];
    uint4 vb; vb.x = wb[0]; vb.y = wb[1]; vb.z = wb[2]; vb.w = wb[3];
    *(uint4*)(pk + b0 * 8) = va;
    *(uint4*)(pk + b1 * 8) = vb;
}

// ssum[co][k] = sum_ci sigmoid(-alpha)
__global__ void prep_s(const float* __restrict__ alpha, float* __restrict__ s, int Ci) {
    int co = blockIdx.x;
    int lane = threadIdx.x;
    float acc[9];
#pragma unroll
    for (int k = 0; k < 9; k++) acc[k] = 0.f;
    for (int ci = lane; ci < Ci; ci += 64) {
        const float* p = alpha + ((long)co * Ci + ci) * 9;
#pragma unroll
        for (int k = 0; k < 9; k++) acc[k] += 1.f / (1.f + expf(p[k]));
    }
#pragma unroll
    for (int k = 0; k < 9; k++) {
        for (int off = 32; off > 0; off >>= 1) acc[k] += __shfl_down(acc[k], off);
    }
    if (lane == 0) {
#pragma unroll
        for (int k = 0; k < 9; k++) s[co * 9 + k] = acc[k];
    }
}

__global__ void prep_ones(const float* __restrict__ ssum, float* __restrict__ og,
                          int Co, int Hout, int Wout, int Hin, int Win, int stride, int total) {
    int idx = blockIdx.x * 256 + threadIdx.x;
    if (idx >= total) return;
    int x = idx % Wout, y = (idx / Wout) % Hout, co = idx / (Wout * Hout);
    float s = 0.f;
    for (int ky = 0; ky < 3; ky++) {
        int yi = stride * y - 1 + ky;
        if (yi < 0 || yi >= Hin) continue;
        for (int kx = 0; kx < 3; kx++) {
            int xi = stride * x - 1 + kx;
            if (xi < 0 || xi >= Win) continue;
            s += ssum[co * 9 + ky * 3 + kx];
        }
    }
    og[idx] = s;
}

// ---------------------------------------------------------------------------
// FC1 weight pack: fp32 [1024][8192] -> fp16 A-fragment order
// ---------------------------------------------------------------------------
__global__ void prep_fc1(const float* __restrict__ W, unsigned short* __restrict__ pk) {
    int idx = blockIdx.x * 256 + threadIdx.x;
    int lane = idx & 63;
    int mf = (idx >> 6) & 63;
    int kt = idx >> 12;
    int o = mf * 16 + (lane & 15);
    long k = (long)kt * 32 + (lane >> 4) * 8;
    const float* src = W + (long)o * 8192 + k;
    float4 f0 = *(const float4*)src;
    float4 f1 = *(const float4*)(src + 4);
    uint4 v;
    v.x = (unsigned)f2h(f0.x) | ((unsigned)f2h(f0.y) << 16);
    v.y = (unsigned)f2h(f0.z) | ((unsigned)f2h(f0.w) << 16);
    v.z = (unsigned)f2h(f1.x) | ((unsigned)f2h(f1.y) << 16);
    v.w = (unsigned)f2h(f1.z) | ((unsigned)f2h(f1.w) << 16);
    *(uint4*)(pk + (long)idx * 8) = v;
}

// ---------------------------------------------------------------------------
// L1 im2col: x [256,3,32,32] fp32 -> cols[n][32] fp16, n = b*1024+y*32+x
// ---------------------------------------------------------------------------
__global__ void l1_im2col(const float* __restrict__ x, unsigned short* __restrict__ cols) {
    int n = blockIdx.x * 256 + threadIdx.x;   // 262144
    int b = n >> 10, y = (n >> 5) & 31, xx = n & 31;
    unsigned int o[16];
#pragma unroll
    for (int i = 0; i < 16; i++) o[i] = 0;
#pragma unroll
    for (int ci = 0; ci < 3; ci++)
#pragma unroll
    for (int ky = 0; ky < 3; ky++) {
        int yy = y - 1 + ky;
        if (yy < 0 || yy > 31) continue;
#pragma unroll
        for (int kx = 0; kx < 3; kx++) {
            int xc = xx - 1 + kx;
            if (xc < 0 || xc > 31) continue;
            float v = x[((b * 3 + ci) * 32 + yy) * 32 + xc];
            int k = ci * 9 + ky * 3 + kx;
            o[k >> 1] |= ((unsigned int)f2h(v)) << ((k & 1) * 16);
        }
    }
    uint4* dst = (uint4*)(cols + (long)n * 32);
    uint4 v0; v0.x = o[0];  v0.y = o[1];  v0.z = o[2];  v0.w = o[3];
    uint4 v1; v1.x = o[4];  v1.y = o[5];  v1.z = o[6];  v1.w = o[7];
    uint4 v2; v2.x = o[8];  v2.y = o[9];  v2.z = o[10]; v2.w = o[11];
    uint4 v3; v3.x = o[12]; v3.y = o[13]; v3.z = o[14]; v3.w = o[15];
    dst[0] = v0; dst[1] = v1; dst[2] = v2; dst[3] = v3;
}

// ---------------------------------------------------------------------------
// L1 MFMA GEMM: out[n][128] = erf((cols@wa + bias) / sqrt(cols^2@wb + eps) /sqrt2)
// ---------------------------------------------------------------------------
__global__ __launch_bounds__(512) void conv1_mfma(const unsigned short* __restrict__ cols,
        const unsigned short* __restrict__ Wp, const float* __restrict__ bias,
        unsigned short* __restrict__ out) {
    constexpr int LINE = 80;     // 32 halfs + pad
    constexpr int TSTR = 136;
    __shared__ char lds[128 * TSTR * 2];
    const int tid = threadIdx.x, lane = tid & 63, wv = tid >> 6;
    const int wm = wv & 1, wn = wv >> 1;
    const int g = lane >> 4, ln = lane & 15;
    const long n0 = (long)blockIdx.x * 128;

    for (int i = tid; i < 128 * 4; i += 512) {
        int r = i >> 2, c = i & 3;
        uint4 v = *(const uint4*)(cols + (n0 + r) * 32 + c * 8);
        *(uint4*)(lds + r * LINE + c * 16) = v;
    }
    __syncthreads();

    half8 af[2][4];
#pragma unroll
    for (int cv = 0; cv < 2; cv++)
#pragma unroll
    for (int m = 0; m < 4; m++)
        af[cv][m] = *(const half8*)(Wp + ((long)((cv * 8 + wm * 4 + m) * 64 + lane)) * 8);

    f32x4 accA[4][2], accB[4][2];
#pragma unroll
    for (int m = 0; m < 4; m++)
#pragma unroll
    for (int nf = 0; nf < 2; nf++) {
        accA[m][nf] = (f32x4){0.f, 0.f, 0.f, 0.f};
        accB[m][nf] = (f32x4){0.f, 0.f, 0.f, 0.f};
    }
#pragma unroll
    for (int nf = 0; nf < 2; nf++) {
        int r = wn * 32 + nf * 16 + ln;
        half8 b1 = *(const half8*)(lds + r * LINE + g * 16);
        half8 b2 = b1 * b1;
#pragma unroll
        for (int m = 0; m < 4; m++) {
            accA[m][nf] = __builtin_amdgcn_mfma_f32_16x16x32_f16(af[0][m], b1, accA[m][nf], 0, 0, 0);
            accB[m][nf] = __builtin_amdgcn_mfma_f32_16x16x32_f16(af[1][m], b2, accB[m][nf], 0, 0, 0);
        }
    }
    __syncthreads();
#pragma unroll
    for (int m = 0; m < 4; m++) {
        int cob = (wm * 4 + m) * 16 + g * 4;
#pragma unroll
        for (int nf = 0; nf < 2; nf++) {
            int nl = wn * 32 + nf * 16 + ln;
            unsigned int pk2[2];
#pragma unroll
            for (int r = 0; r < 4; r++) {
                float mm = accA[m][nf][r] + bias[cob + r];
                float vv = accB[m][nf][r];
                unsigned int hv = f2h(erff(mm * rsqrtf(vv + EPSV) * INV_SQRT2));
                if (r & 1) pk2[r >> 1] |= hv << 16; else pk2[r >> 1] = hv;
            }
            *(unsigned int*)(lds + (nl * TSTR + cob) * 2) = pk2[0];
            *(unsigned int*)(lds + (nl * TSTR + cob) * 2 + 4) = pk2[1];
        }
    }
    __syncthreads();
    for (int i = tid; i < 128 * 16; i += 512) {
        int nl = i >> 4, c8 = (i & 15) * 8;
        uint4 v = *(const uint4*)(lds + (nl * TSTR + c8) * 2);
        *(uint4*)(out + (n0 + nl) * 128 + c8) = v;
    }
}

// ---------------------------------------------------------------------------
// MFMA implicit-GEMM fused LRnet conv. NHWC fp16 input. 512 thr.
// MTILE now a template param: wave split wm2 x wn4, WMF = MTILE/32.
// MODE 0: lrconv  -> erf -> NHWC fp16   (v = convB)
// MODE 1: ver2    -> erf -> NHWC fp16   (v = ones - convB)
// MODE 3: ver2 + sample -> NHWC fp16    (out = m + sqrt(v+eps)*epsb)
// MODE 4: ver2 + sample -> NCHW fp16
// ---------------------------------------------------------------------------
template<int Ci, int Hin, int Win, int Co, int Hout, int Wout, int STRIDE,
         int ROWS, int IPB, int NTILE, int CHUNK, int MTILE, int MODE>
__global__ __launch_bounds__(512) void conv_mfma(
    const unsigned short* __restrict__ in,
    const unsigned short* __restrict__ wpk,
    const float* __restrict__ bias,
    const float* __restrict__ ones_g,
    const float* __restrict__ epsb,
    void* __restrict__ outp)
{
    constexpr int BLK = 512;
    constexpr int PROWS = STRIDE * (ROWS - 1) + 3;
    constexpr int PW = Win + 2;
    constexpr int POS = IPB * PROWS * PW;
    constexpr int NCH32 = Ci / 32;
    constexpr int NCHL = Ci / CHUNK;
    constexpr int KS = CHUNK / 32;
    constexpr int MFg = Co / 16;
    constexpr int NF = NTILE / 16;
    constexpr int WMF = MTILE / 32;          // per-wave mf count (wm covers 2*WMF = MTILE/16)
    constexpr int WNF = NF / 4;
    constexpr int CT = Co / MTILE;
    constexpr int RG = Hout / ROWS;
    constexpr int LINE = CHUNK * 2 + 16;
    constexpr int TSTR = MTILE + 8;
    constexpr int PASSN = (NTILE < 128) ? NTILE : 128;
    constexpr int NPASS = (MODE == 4) ? 0 : NTILE / PASSN;
    constexpr int STAGE_B = POS * LINE;
    constexpr int TR_B = (MODE == 4) ? 0 : PASSN * TSTR * 2;
    constexpr int LDS_B = STAGE_B > TR_B ? STAGE_B : TR_B;
    static_assert(8 % CT == 0, "ct swizzle");
    static_assert(WNF * 4 == NF, "wnf");
    static_assert(WMF * 32 == MTILE, "wmf");
    static_assert(NCHL * CHUNK == Ci, "chunk");
    static_assert(LDS_B <= 65536, "lds");
    __shared__ char lds[LDS_B];

    const int tid = threadIdx.x;
    const int lane = tid & 63;
    const int wv = tid >> 6;
    const int wm = wv & 1, wn = wv >> 1;
    const int g = lane >> 4, ln = lane & 15;

    const int bid = blockIdx.x;
    const int xcd = bid & 7;
    constexpr int XPC = 8 / CT;
    const int ct = xcd % CT;
    const int nt = (bid >> 3) * XPC + xcd / CT;
    const int b0 = (nt / RG) * IPB;
    const int y0 = (nt % RG) * ROWS;

    int pbase[WNF];
#pragma unroll
    for (int nf = 0; nf < WNF; nf++) {
        int n = (wn * WNF + nf) * 16 + ln;
        int img = n / (ROWS * Wout);
        int rem = n % (ROWS * Wout);
        int yr = rem / Wout, xo = rem % Wout;
        pbase[nf] = (img * PROWS + STRIDE * yr) * PW + STRIDE * xo;
    }

    f32x4 accA[WMF][WNF], accB[WMF][WNF];
#pragma unroll
    for (int mf = 0; mf < WMF; mf++)
#pragma unroll
    for (int nf = 0; nf < WNF; nf++) {
        accA[mf][nf] = (f32x4){0.f, 0.f, 0.f, 0.f};
        accB[mf][nf] = (f32x4){0.f, 0.f, 0.f, 0.f};
    }

    const unsigned short* wbase = wpk + ((long)(ct * (MTILE / 16) + wm * WMF) * 64 + lane) * 8;

    for (int ch = 0; ch < NCHL; ch++) {
        // ---- stage CHUNK channels (fp16) into LDS ----
        for (int i = tid; i < POS * (CHUNK / 8); i += BLK) {
            int p = i / (CHUNK / 8), c = i % (CHUNK / 8);
            int img = p / (PROWS * PW);
            int r = p % (PROWS * PW);
            int prow = r / PW, px = r % PW;
            int yin = STRIDE * y0 - 1 + prow;
            int xin = px - 1;
            uint4 v; v.x = 0; v.y = 0; v.z = 0; v.w = 0;
            if (yin >= 0 && yin < Hin && xin >= 0 && xin < Win) {
                long a = (((long)(b0 + img) * Hin + yin) * Win + xin) * Ci + ch * CHUNK + c * 8;
                v = *(const uint4*)(in + a);
            }
            *(uint4*)(lds + p * LINE + c * 16) = v;
        }
        __syncthreads();
        // ---- 9 kernel positions x KS k-substeps ----
#pragma unroll 3
        for (int pos = 0; pos < 9; pos++) {
            const int ky = pos / 3, kx = pos % 3;
#pragma unroll
            for (int ks = 0; ks < KS; ks++) {
                const int ch32 = ch * KS + ks;
                half8 af[2][WMF];
#pragma unroll
                for (int cv = 0; cv < 2; cv++)
#pragma unroll
                for (int mf = 0; mf < WMF; mf++)
                    af[cv][mf] = *(const half8*)(wbase +
                        ((long)(((cv * 9 + pos) * NCH32 + ch32) * MFg + mf)) * 512);
#pragma unroll
                for (int nf = 0; nf < WNF; nf++) {
                    int po = (pbase[nf] + ky * PW + kx) * LINE + ks * 64 + g * 16;
                    half8 b1 = *(const half8*)(lds + po);
                    half8 b2 = b1 * b1;               // v_pk_mul_f16
#pragma unroll
                    for (int mf = 0; mf < WMF; mf++) {
                        accA[mf][nf] = __builtin_amdgcn_mfma_f32_16x16x32_f16(af[0][mf], b1, accA[mf][nf], 0, 0, 0);
                        accB[mf][nf] = __builtin_amdgcn_mfma_f32_16x16x32_f16(af[1][mf], b2, accB[mf][nf], 0, 0, 0);
                    }
                }
            }
        }
        __syncthreads();
    }

    // ---- epilogue ----
    if constexpr (MODE == 4) {
        unsigned short* out = (unsigned short*)outp;
#pragma unroll
        for (int mf = 0; mf < WMF; mf++) {
            int co = ct * MTILE + (wm * WMF + mf) * 16 + g * 4;
#pragma unroll
            for (int nf = 0; nf < WNF; nf++) {
                int n = (wn * WNF + nf) * 16 + ln;
                int img = n / (ROWS * Wout), rem = n % (ROWS * Wout);
                int y = y0 + rem / Wout, x = rem % Wout;
                int b = b0 + img;
#pragma unroll
                for (int r = 0; r < 4; r++) {
                    int c = co + r;
                    float m = accA[mf][nf][r] + bias[c];
                    float v = ones_g[(c * Hout + y) * Wout + x] - accB[mf][nf][r];
                    long oi = (((long)b * Co + c) * Hout + y) * Wout + x;
                    out[oi] = f2h(m + sqrtf(v + EPSV) * epsb[oi]);
                }
            }
        }
    } else {
        unsigned short* out = (unsigned short*)outp;
#pragma unroll
        for (int pass = 0; pass < NPASS; pass++) {
            __syncthreads();
#pragma unroll
            for (int mf = 0; mf < WMF; mf++) {
                int cob = (wm * WMF + mf) * 16 + g * 4;
                int cg = ct * MTILE + cob;
#pragma unroll
                for (int nf = 0; nf < WNF; nf++) {
                    int nb = (wn * WNF + nf) * 16;
                    if (nb < pass * PASSN || nb >= (pass + 1) * PASSN) continue;
                    int n = nb + ln;
                    int img = n / (ROWS * Wout), rem = n % (ROWS * Wout);
                    int y = y0 + rem / Wout, x = rem % Wout;
                    int b = b0 + img;
                    unsigned int pk2[2];
#pragma unroll
                    for (int r = 0; r < 4; r++) {
                        int c = cg + r;
                        float m = accA[mf][nf][r] + bias[c];
                        float val;
                        if constexpr (MODE == 0) {
                            val = erff(m * rsqrtf(accB[mf][nf][r] + EPSV) * INV_SQRT2);
                        } else if constexpr (MODE == 1) {
                            float v = ones_g[(c * Hout + y) * Wout + x] - accB[mf][nf][r];
                            val = erff(m * rsqrtf(v + EPSV) * INV_SQRT2);
                        } else { // MODE 3
                            float v = ones_g[(c * Hout + y) * Wout + x] - accB[mf][nf][r];
                            float ev = epsb[(((long)b * Co + c) * Hout + y) * Wout + x];
                            val = m + sqrtf(v + EPSV) * ev;
                        }
                        unsigned int hv = f2h(val);
                        if (r & 1) pk2[r >> 1] |= hv << 16; else pk2[r >> 1] = hv;
                    }
                    int nl = n - pass * PASSN;
                    *(unsigned int*)(lds + (nl * TSTR + cob) * 2) = pk2[0];
                    *(unsigned int*)(lds + (nl * TSTR + cob) * 2 + 4) = pk2[1];
                }
            }
            __syncthreads();
            for (int i = tid; i < PASSN * (MTILE / 8); i += BLK) {
                int nl = i / (MTILE / 8);
                int n = pass * PASSN + nl;
                int c8 = (i % (MTILE / 8)) * 8;
                int img = n / (ROWS * Wout), rem = n % (ROWS * Wout);
                int y = y0 + rem / Wout, x = rem % Wout;
                int b = b0 + img;
                uint4 val = *(const uint4*)(lds + (nl * TSTR + c8) * 2);
                long oa = (((long)b * Hout + y) * Wout + x) * Co + ct * MTILE + c8;
                *(uint4*)(out + oa) = val;
            }
        }
    }
}

// ---------------------------------------------------------------------------
// BatchNorm (fp16 activations, partial-sum based, no atomics)
// ---------------------------------------------------------------------------
__global__ void bn_part_nhwc(const unsigned short* __restrict__ h, float* __restrict__ part,
                             int C, int rpc) {
    int c = threadIdx.x;
    long r0 = (long)blockIdx.x * rpc;
    float s = 0.f, s2 = 0.f;
    for (int r = 0; r < rpc; r++) {
        float v = h2f(h[(r0 + r) * C + c]);
        s += v; s2 += v * v;
    }
    part[(long)blockIdx.x * 2 * C + c] = s;
    part[(long)blockIdx.x * 2 * C + C + c] = s2;
}

__global__ void bn_part_nchw(const unsigned short* __restrict__ h, float* __restrict__ part,
                             int ipc) {
    int c = threadIdx.x;
    int b0 = blockIdx.x * ipc;
    float s = 0.f, s2 = 0.f;
    for (int b = 0; b < ipc; b++) {
        const unsigned short* p = h + ((long)(b0 + b) * 512 + c) * 16;
        uint4 v0 = *(const uint4*)p;
        uint4 v1 = *(const uint4*)(p + 8);
        unsigned int* vp0 = (unsigned int*)&v0;
        unsigned int* vp1 = (unsigned int*)&v1;
#pragma unroll
        for (int e = 0; e < 4; e++) {
            float a = h2f((unsigned short)(vp0[e] & 0xffffu)), bb = h2f((unsigned short)(vp0[e] >> 16));
            float cc = h2f((unsigned short)(vp1[e] & 0xffffu)), d = h2f((unsigned short)(vp1[e] >> 16));
            s += a + bb + cc + d;
            s2 += a * a + bb * bb + cc * cc + d * d;
        }
    }
    part[(long)blockIdx.x * 1024 + c] = s;
    part[(long)blockIdx.x * 1024 + 512 + c] = s2;
}

__global__ void bn_fin(const float* __restrict__ part, const float* __restrict__ gamma,
                       const float* __restrict__ beta, float* __restrict__ sc,
                       float* __restrict__ sh, int C, int chunks, float invN) {
    int c = blockIdx.x * 256 + threadIdx.x;
    if (c >= C) return;
    float s = 0.f, s2 = 0.f;
    for (int j = 0; j < chunks; j++) {
        s += part[(long)j * 2 * C + c];
        s2 += part[(long)j * 2 * C + C + c];
    }
    float mean = s * invN;
    float var = s2 * invN - mean * mean;
    float k = gamma[c] * rsqrtf(var + BNEPS);
    sc[c] = k;
    sh[c] = beta[c] - mean * k;
}

__global__ void bn_app_nhwc(unsigned short* __restrict__ h, const float* __restrict__ sc,
                            const float* __restrict__ sh) {
    int i = blockIdx.x * 256 + threadIdx.x;   // 2097152 total
    int cb = (i & 31) * 8;
    uint4 v = *(uint4*)(h + (long)i * 8);
    float4 s0 = *(const float4*)(sc + cb), s1 = *(const float4*)(sc + cb + 4);
    float4 t0 = *(const float4*)(sh + cb), t1 = *(const float4*)(sh + cb + 4);
    float scl[8] = {s0.x, s0.y, s0.z, s0.w, s1.x, s1.y, s1.z, s1.w};
    float shf[8] = {t0.x, t0.y, t0.z, t0.w, t1.x, t1.y, t1.z, t1.w};
    unsigned int* vp = (unsigned int*)&v;
#pragma unroll
    for (int e = 0; e < 4; e++) {
        float lo = h2f((unsigned short)(vp[e] & 0xffffu));
        float hi = h2f((unsigned short)(vp[e] >> 16));
        lo = fmaf(lo, scl[2 * e], shf[2 * e]);     lo = lo > 0.f ? lo : 0.f;
        hi = fmaf(hi, scl[2 * e + 1], shf[2 * e + 1]); hi = hi > 0.f ? hi : 0.f;
        vp[e] = (unsigned int)f2h(lo) | (((unsigned int)f2h(hi)) << 16);
    }
    *(uint4*)(h + (long)i * 8) = v;
}

__global__ void bn_app_nchw(unsigned short* __restrict__ h, const float* __restrict__ sc,
                            const float* __restrict__ sh) {
    int i = blockIdx.x * 256 + threadIdx.x;   // 524288 total
    int c = (i >> 1) & 511;
    float k = sc[c], t = sh[c];
    uint4 v = *(uint4*)(h + (long)i * 8);
    unsigned int* vp = (unsigned int*)&v;
#pragma unroll
    for (int e = 0; e < 4; e++) {
        float lo = h2f((unsigned short)(vp[e] & 0xffffu));
        float hi = h2f((unsigned short)(vp[e] >> 16));
        lo = fmaf(lo, k, t); lo = lo > 0.f ? lo : 0.f;
        hi = fmaf(hi, k, t); hi = hi > 0.f ? hi : 0.f;
        vp[e] = (unsigned int)f2h(lo) | (((unsigned int)f2h(hi)) << 16);
    }
    *(uint4*)(h + (long)i * 8) = v;
}

// ---------------------------------------------------------------------------
// FC1 fp16 MFMA split-K + reduce
// ---------------------------------------------------------------------------
__global__ __launch_bounds__(256) void fc1_mfma(const unsigned short* __restrict__ Ab,
                                                const unsigned short* __restrict__ Wp,
                                                float* __restrict__ pbuf) {
    __shared__ char lds[2 * 64 * 80];
    const int tid = threadIdx.x;
    const int lane = tid & 63;
    const int wv = tid >> 6;
    const int g = lane >> 4, ln = lane & 15;
    const int ot = blockIdx.x, bt = blockIdx.y, s = blockIdx.z;
    const int b0 = bt * 64;
    const int k0g = s * 1024;

    f32x4 acc[2][4];
#pragma unroll
    for (int c = 0; c < 2; c++)
#pragma unroll
    for (int nf = 0; nf < 4; nf++) acc[c][nf] = (f32x4){0.f, 0.f, 0.f, 0.f};

    for (int k0 = 0; k0 < 1024; k0 += 64) {
        __syncthreads();
        for (int i = tid; i < 512; i += 256) {
            int row = i >> 3, kk = (i >> 2) & 1, seg = i & 3;
            uint4 v = *(const uint4*)(Ab + ((long)(b0 + row) * 8192 + k0g + k0 + kk * 32 + seg * 8));
            *(uint4*)(lds + (kk * 64 + row) * 80 + seg * 16) = v;
        }
        __syncthreads();
#pragma unroll
        for (int kk = 0; kk < 2; kk++) {
            int kt = (k0g + k0) / 32 + kk;
            half8 af[2];
#pragma unroll
            for (int c = 0; c < 2; c++) {
                int mf = ot * 8 + wv * 2 + c;
                af[c] = *(const half8*)(Wp + (((long)kt * 64 + mf) * 64 + lane) * 8);
            }
            half8 bf[4];
#pragma unroll
            for (int nf = 0; nf < 4; nf++)
                bf[nf] = *(const half8*)(lds + (kk * 64 + nf * 16 + ln) * 80 + g * 16);
#pragma unroll
            for (int c = 0; c < 2; c++)
#pragma unroll
            for (int nf = 0; nf < 4; nf++)
                acc[c][nf] = __builtin_amdgcn_mfma_f32_16x16x32_f16(af[c], bf[nf], acc[c][nf], 0, 0, 0);
        }
    }
#pragma unroll
    for (int c = 0; c < 2; c++) {
        int o = ot * 128 + (wv * 2 + c) * 16 + g * 4;
#pragma unroll
        for (int nf = 0; nf < 4; nf++) {
            int b = b0 + nf * 16 + ln;
            *(f32x4*)(pbuf + ((long)s * 256 + b) * 1024 + o) = acc[c][nf];
        }
    }
}

__global__ void fc1_reduce(const float* __restrict__ pbuf, const float* __restrict__ bias,
                           float* __restrict__ out) {
    int idx = blockIdx.x * 256 + threadIdx.x;
    float s = 0.f;
#pragma unroll
    for (int j = 0; j < 8; j++) s += pbuf[(long)j * 262144 + idx];
    s += bias[idx & 1023];
    out[idx] = s > 0.f ? s : 0.f;
}

__global__ void fc2_k(const float* __restrict__ A, const float* __restrict__ W,
                      const float* __restrict__ b2, float* __restrict__ out) {
    int bb = blockIdx.x;
    int tid = threadIdx.x;
    float acc[10];
#pragma unroll
    for (int o = 0; o < 10; o++) acc[o] = 0.f;
    const float* arow = A + (long)bb * 1024;
    for (int k = tid; k < 1024; k += 256) {
        float a = arow[k];
#pragma unroll
        for (int o = 0; o < 10; o++) acc[o] = fmaf(a, W[o * 1024 + k], acc[o]);
    }
#pragma unroll
    for (int o = 0; o < 10; o++)
        for (int off = 32; off > 0; off >>= 1) acc[o] += __shfl_down(acc[o], off);
    __shared__ float red[10][4];
    int wid = tid >> 6, lane = tid & 63;
    if (lane == 0) {
#pragma unroll
        for (int o = 0; o < 10; o++) red[o][wid] = acc[o];
    }
    __syncthreads();
    if (tid < 10)
        out[bb * 10 + tid] = red[tid][0] + red[tid][1] + red[tid][2] + red[tid][3] + b2[tid];
}

// ---------------------------------------------------------------------------
extern "C" void kernel_launch(void* const* d_in, const int* in_sizes, int n_in,
                              void* d_out, int out_size, void* d_ws, size_t ws_size,
                              hipStream_t stream) {
    const float* x  = (const float*)d_in[0];
    const float* a1 = (const float*)d_in[1];  const float* b1 = (const float*)d_in[2];  const float* c1 = (const float*)d_in[3];
    const float* a2 = (const float*)d_in[4];  const float* b2 = (const float*)d_in[5];  const float* c2 = (const float*)d_in[6];
    const float* a3 = (const float*)d_in[7];  const float* b3 = (const float*)d_in[8];  const float* c3 = (const float*)d_in[9];
    const float* a4 = (const float*)d_in[10]; const float* b4 = (const float*)d_in[11]; const float* c4 = (const float*)d_in[12];
    const float* a5 = (const float*)d_in[13]; const float* b5 = (const float*)d_in[14]; const float* c5 = (const float*)d_in[15];
    const float* a6 = (const float*)d_in[16]; const float* b6 = (const float*)d_in[17]; const float* c6 = (const float*)d_in[18];
    const float* g3 = (const float*)d_in[19]; const float* be3 = (const float*)d_in[20];
    const float* g6 = (const float*)d_in[21]; const float* be6 = (const float*)d_in[22];
    const float* fc1w = (const float*)d_in[23]; const float* fc1b = (const float*)d_in[24];
    const float* fc2w = (const float*)d_in[25]; const float* fc2b = (const float*)d_in[26];
    const float* eps3 = (const float*)d_in[27]; const float* eps6 = (const float*)d_in[28];
    (void)in_sizes; (void)n_in; (void)out_size; (void)ws_size;

    float* w = (float*)d_ws;
    size_t off = 0;
    auto alloc = [&](size_t n) { float* p = w + off; off += n; return p; };
    unsigned short* pk2 = (unsigned short*)alloc(147456);
    unsigned short* pk3 = (unsigned short*)alloc(294912);
    unsigned short* pk4 = (unsigned short*)alloc(589824);
    unsigned short* pk5 = (unsigned short*)alloc(1179648);
    unsigned short* pk6 = (unsigned short*)alloc(2359296);
    unsigned short* pkL1 = (unsigned short*)alloc(4096);
    float* wa1 = alloc(3456); float* wb1 = alloc(3456);
    float* ss2 = alloc(1152); float* ss3 = alloc(2304);
    float* ss5 = alloc(4608); float* ss6 = alloc(4608);
    float* og2 = alloc(32768); float* og3 = alloc(65536);
    float* og5 = alloc(32768); float* og6 = alloc(8192);
    float* part3 = alloc(131072);
    float* part6 = alloc(65536);
    float* sc3 = alloc(256); float* sh3 = alloc(256);
    float* sc6 = alloc(512); float* sh6 = alloc(512);
    float* A  = alloc(16777216);
    float* Bb = alloc(4194304);
    float* Cc = alloc(8388608);
    float* Dd = alloc(2097152);
    float* Ee = alloc(4194304);

    unsigned short* ex1 = (unsigned short*)A;
    unsigned short* pkF = (unsigned short*)A;
    float*          pbuf = A + 4194304;
    unsigned short* ex2 = (unsigned short*)Bb;
    float*          fco = Bb;
    unsigned short* h6b = (unsigned short*)(Bb + 524288);
    unsigned short* colsL1 = (unsigned short*)Cc;
    unsigned short* h3b = (unsigned short*)Cc;
    unsigned short* ex4 = (unsigned short*)Dd;
    unsigned short* ex5 = (unsigned short*)Ee;

    // ---- prep ----
    prep_w<<<14, 256, 0, stream>>>(a1, b1, wa1, wb1, 3456);
    prep_packL1<<<4, 256, 0, stream>>>(wa1, wb1, pkL1);
    prep_pack<<<72,  256, 0, stream>>>(a2, b2, pk2, 128, 128, 1, 18432);
    prep_pack<<<144, 256, 0, stream>>>(a3, b3, pk3, 128, 256, 1, 36864);
    prep_pack<<<288, 256, 0, stream>>>(a4, b4, pk4, 256, 256, 0, 73728);
    prep_pack<<<576, 256, 0, stream>>>(a5, b5, pk5, 256, 512, 1, 147456);
    prep_pack<<<1152,256, 0, stream>>>(a6, b6, pk6, 512, 512, 1, 294912);
    prep_s<<<128, 64, 0, stream>>>(a2, ss2, 128);
    prep_s<<<256, 64, 0, stream>>>(a3, ss3, 128);
    prep_s<<<512, 64, 0, stream>>>(a5, ss5, 256);
    prep_s<<<512, 64, 0, stream>>>(a6, ss6, 512);
    prep_ones<<<128, 256, 0, stream>>>(ss2, og2, 128, 16, 16, 32, 32, 2, 32768);
    prep_ones<<<256, 256, 0, stream>>>(ss3, og3, 256, 16, 16, 16, 16, 1, 65536);
    prep_ones<<<128, 256, 0, stream>>>(ss5, og5, 512, 8, 8, 8, 8, 1, 32768);
    prep_ones<<<32,  256, 0, stream>>>(ss6, og6, 512, 4, 4, 8, 8, 2, 8192);

    // ---- network ----
    // L1: im2col + MFMA GEMM -> ex1 [256,32,32,128] NHWC fp16
    l1_im2col<<<1024, 256, 0, stream>>>(x, colsL1);
    conv1_mfma<<<2048, 512, 0, stream>>>(colsL1, pkL1, c1, ex1);
    // L2: [256,32,32,128] -> [256,16,16,128]
    conv_mfma<128,32,32,128,16,16,2, 8,1,128,32,128,1><<<512, 512, 0, stream>>>(ex1, pk2, c2, og2, nullptr, ex2);
    // L3: -> h3b [256,16,16,256] NHWC fp16 (sampled)
    conv_mfma<128,16,16,256,16,16,1, 8,2,256,64,128,3><<<512, 512, 0, stream>>>(ex2, pk3, c3, og3, eps3, h3b);
    // FC1 weight pack into A (ex1 dead after L2)
    prep_fc1<<<4096, 256, 0, stream>>>(fc1w, pkF);
    // BN3 (fp16 NHWC, in place)
    bn_part_nhwc<<<256, 256, 0, stream>>>(h3b, part3, 256, 256);
    bn_fin<<<1, 256, 0, stream>>>(part3, g3, be3, sc3, sh3, 256, 256, 1.f / 65536.f);
    bn_app_nhwc<<<8192, 256, 0, stream>>>(h3b, sc3, sh3);
    // L4: [256,16,16,256] -> [256,8,8,256]
    conv_mfma<256,16,16,256, 8, 8,2, 8,1,64,32,128,0><<<512, 512, 0, stream>>>(h3b, pk4, c4, nullptr, nullptr, ex4);
    // L5: -> [256,8,8,512]
    conv_mfma<256, 8, 8,512, 8, 8,1, 8,2,128,32,128,1><<<512, 512, 0, stream>>>(ex4, pk5, c5, og5, nullptr, ex5);
    // L6: -> h6b [256,512,4,4] NCHW fp16 (sampled)  MTILE=64 -> CT=8, grid 512
    conv_mfma<512, 8, 8,512, 4, 4,2, 4,4,64,32,64,4><<<512, 512, 0, stream>>>(ex5, pk6, c6, og6, eps6, h6b);
    // BN6 (fp16 NCHW, in place)
    bn_part_nchw<<<64, 512, 0, stream>>>(h6b, part6, 4);
    bn_fin<<<2, 256, 0, stream>>>(part6, g6, be6, sc6, sh6, 512, 64, 1.f / 4096.f);
    bn_app_nchw<<<2048, 256, 0, stream>>>(h6b, sc6, sh6);
    // FC1 + FC2
    fc1_mfma<<<dim3(8, 4, 8), 256, 0, stream>>>(h6b, pkF, pbuf);
    fc1_reduce<<<1024, 256, 0, stream>>>(pbuf, fc1b, fco);
    fc2_k<<<256, 256, 0, stream>>>(fco, fc2w, fc2b, (float*)d_out);
}

// Round 12
// 790.514 us; speedup vs baseline: 1.3698x; 1.0037x over previous
//
#include <hip/hip_runtime.h>
#include <hip/hip_bf16.h>
#include <math.h>

#define EPSV 1e-10f
#define BNEPS 1e-5f
#define INV_SQRT2 0.70710678118654752440f

typedef __attribute__((ext_vector_type(8))) short short8;
typedef __attribute__((ext_vector_type(4))) float f32x4;
typedef _Float16 half8 __attribute__((ext_vector_type(8)));

__device__ __forceinline__ unsigned short f2h(float f) {
    _Float16 h = (_Float16)f;                      // RNE
    return __builtin_bit_cast(unsigned short, h);
}
__device__ __forceinline__ float h2f(unsigned short u) {
    _Float16 h = __builtin_bit_cast(_Float16, u);
    return (float)h;
}

// ---------------------------------------------------------------------------
// L1 weight prep (fp32)
// ---------------------------------------------------------------------------
__global__ void prep_w(const float* __restrict__ a, const float* __restrict__ b,
                       float* __restrict__ WA, float* __restrict__ WB, int n) {
    for (int i = blockIdx.x * blockDim.x + threadIdx.x; i < n; i += gridDim.x * blockDim.x) {
        float p0 = 1.f / (1.f + expf(-a[i]));
        float sb = 1.f / (1.f + expf(-b[i]));
        float p1 = (1.f - p0) * sb;
        float ew = 2.f * p1 - (1.f - p0);
        float ew2 = 1.f - p0;
        WA[i] = ew;
        WB[i] = ew2 - ew * ew;
    }
}

// L1 weights -> MFMA A-fragment order (fp16), K=32 (27 used), 2cv x 8mf
__global__ void prep_packL1(const float* __restrict__ wa, const float* __restrict__ wb,
                            unsigned short* __restrict__ pk) {
    int idx = blockIdx.x * 256 + threadIdx.x;   // 1024 total
    if (idx >= 1024) return;
    int lane = idx & 63;
    int mf = (idx >> 6) & 7;
    int cv = idx >> 9;
    int co = mf * 16 + (lane & 15);
    int k0 = (lane >> 4) * 8;
    const float* src = (cv ? wb : wa) + co * 27;
    unsigned int o[4] = {0, 0, 0, 0};
#pragma unroll
    for (int j = 0; j < 8; j++) {
        int k = k0 + j;
        if (k < 27) {
            unsigned int h = f2h(src[k]);
            o[j >> 1] |= h << ((j & 1) * 16);
        }
    }
    uint4 v; v.x = o[0]; v.y = o[1]; v.z = o[2]; v.w = o[3];
    *(uint4*)(pk + (long)idx * 8) = v;
}

// ---------------------------------------------------------------------------
// Pack ternary-stat weights into MFMA A-fragment order (fp16).
// ---------------------------------------------------------------------------
__global__ void prep_pack(const float* __restrict__ a, const float* __restrict__ b,
                          unsigned short* __restrict__ pk, int Ci, int Co, int ver2, int total) {
    int idx = blockIdx.x * 256 + threadIdx.x;
    if (idx >= total) return;
    int lane = idx & 63;
    int MFg = Co >> 4, NCH = Ci >> 5;
    int mfch = idx >> 6;
    int mf = mfch % MFg;
    int chpos = mfch / MFg;
    int ch = chpos % NCH;
    int pos = chpos / NCH;
    int co = mf * 16 + (lane & 15);
    int cib = ch * 32 + (lane >> 4) * 8;
    unsigned int wa[4], wb[4];
#pragma unroll
    for (int j = 0; j < 8; j++) {
        long s = ((long)co * Ci + cib + j) * 9 + pos;
        float p0 = 1.f / (1.f + expf(-a[s]));
        float sb = 1.f / (1.f + expf(-b[s]));
        float p1 = (1.f - p0) * sb;
        float ew = 2.f * p1 - (1.f - p0);
        float ew2 = 1.f - p0;
        unsigned int ha = f2h(ew);
        unsigned int hb = f2h(ver2 ? ew * ew : ew2 - ew * ew);
        if (j & 1) { wa[j >> 1] |= ha << 16; wb[j >> 1] |= hb << 16; }
        else       { wa[j >> 1] = ha;        wb[j >> 1] = hb; }
    }
    long b0 = (((long)(0 * 9 + pos) * NCH + ch) * MFg + mf) * 64 + lane;
    long b1 = (((long)(1 * 9 + pos) * NCH + ch) * MFg + mf) * 64 + lane;
    uint4 va; va.x = wa[0]; va.y = wa[1]; va.z = wa[2]; va.w = wa[3];
    uint4 vb; vb.x = wb[0]; vb.y = wb[1]; vb.z = wb[2]; vb.w = wb[3];
    *(uint4*)(pk + b0 * 8) = va;
    *(uint4*)(pk + b1 * 8) = vb;
}

// ssum[co][k] = sum_ci sigmoid(-alpha)
__global__ void prep_s(const float* __restrict__ alpha, float* __restrict__ s, int Ci) {
    int co = blockIdx.x;
    int lane = threadIdx.x;
    float acc[9];
#pragma unroll
    for (int k = 0; k < 9; k++) acc[k] = 0.f;
    for (int ci = lane; ci < Ci; ci += 64) {
        const float* p = alpha + ((long)co * Ci + ci) * 9;
#pragma unroll
        for (int k = 0; k < 9; k++) acc[k] += 1.f / (1.f + expf(p[k]));
    }
#pragma unroll
    for (int k = 0; k < 9; k++) {
        for (int off = 32; off > 0; off >>= 1) acc[k] += __shfl_down(acc[k], off);
    }
    if (lane == 0) {
#pragma unroll
        for (int k = 0; k < 9; k++) s[co * 9 + k] = acc[k];
    }
}

__global__ void prep_ones(const float* __restrict__ ssum, float* __restrict__ og,
                          int Co, int Hout, int Wout, int Hin, int Win, int stride, int total) {
    int idx = blockIdx.x * 256 + threadIdx.x;
    if (idx >= total) return;
    int x = idx % Wout, y = (idx / Wout) % Hout, co = idx / (Wout * Hout);
    float s = 0.f;
    for (int ky = 0; ky < 3; ky++) {
        int yi = stride * y - 1 + ky;
        if (yi < 0 || yi >= Hin) continue;
        for (int kx = 0; kx < 3; kx++) {
            int xi = stride * x - 1 + kx;
            if (xi < 0 || xi >= Win) continue;
            s += ssum[co * 9 + ky * 3 + kx];
        }
    }
    og[idx] = s;
}

// ---------------------------------------------------------------------------
// FC1 weight pack: fp32 [1024][8192] -> fp16 A-fragment order
// ---------------------------------------------------------------------------
__global__ void prep_fc1(const float* __restrict__ W, unsigned short* __restrict__ pk) {
    int idx = blockIdx.x * 256 + threadIdx.x;
    int lane = idx & 63;
    int mf = (idx >> 6) & 63;
    int kt = idx >> 12;
    int o = mf * 16 + (lane & 15);
    long k = (long)kt * 32 + (lane >> 4) * 8;
    const float* src = W + (long)o * 8192 + k;
    float4 f0 = *(const float4*)src;
    float4 f1 = *(const float4*)(src + 4);
    uint4 v;
    v.x = (unsigned)f2h(f0.x) | ((unsigned)f2h(f0.y) << 16);
    v.y = (unsigned)f2h(f0.z) | ((unsigned)f2h(f0.w) << 16);
    v.z = (unsigned)f2h(f1.x) | ((unsigned)f2h(f1.y) << 16);
    v.w = (unsigned)f2h(f1.z) | ((unsigned)f2h(f1.w) << 16);
    *(uint4*)(pk + (long)idx * 8) = v;
}

// ---------------------------------------------------------------------------
// L1 im2col: x [256,3,32,32] fp32 -> cols[n][32] fp16, n = b*1024+y*32+x
// ---------------------------------------------------------------------------
__global__ void l1_im2col(const float* __restrict__ x, unsigned short* __restrict__ cols) {
    int n = blockIdx.x * 256 + threadIdx.x;   // 262144
    int b = n >> 10, y = (n >> 5) & 31, xx = n & 31;
    unsigned int o[16];
#pragma unroll
    for (int i = 0; i < 16; i++) o[i] = 0;
#pragma unroll
    for (int ci = 0; ci < 3; ci++)
#pragma unroll
    for (int ky = 0; ky < 3; ky++) {
        int yy = y - 1 + ky;
        if (yy < 0 || yy > 31) continue;
#pragma unroll
        for (int kx = 0; kx < 3; kx++) {
            int xc = xx - 1 + kx;
            if (xc < 0 || xc > 31) continue;
            float v = x[((b * 3 + ci) * 32 + yy) * 32 + xc];
            int k = ci * 9 + ky * 3 + kx;
            o[k >> 1] |= ((unsigned int)f2h(v)) << ((k & 1) * 16);
        }
    }
    uint4* dst = (uint4*)(cols + (long)n * 32);
    uint4 v0; v0.x = o[0];  v0.y = o[1];  v0.z = o[2];  v0.w = o[3];
    uint4 v1; v1.x = o[4];  v1.y = o[5];  v1.z = o[6];  v1.w = o[7];
    uint4 v2; v2.x = o[8];  v2.y = o[9];  v2.z = o[10]; v2.w = o[11];
    uint4 v3; v3.x = o[12]; v3.y = o[13]; v3.z = o[14]; v3.w = o[15];
    dst[0] = v0; dst[1] = v1; dst[2] = v2; dst[3] = v3;
}

// ---------------------------------------------------------------------------
// L1 MFMA GEMM: out[n][128] = erf((cols@wa + bias) / sqrt(cols^2@wb + eps) /sqrt2)
// ---------------------------------------------------------------------------
__global__ __launch_bounds__(512) void conv1_mfma(const unsigned short* __restrict__ cols,
        const unsigned short* __restrict__ Wp, const float* __restrict__ bias,
        unsigned short* __restrict__ out) {
    constexpr int LINE = 80;     // 32 halfs + pad
    constexpr int TSTR = 136;
    __shared__ char lds[128 * TSTR * 2];
    const int tid = threadIdx.x, lane = tid & 63, wv = tid >> 6;
    const int wm = wv & 1, wn = wv >> 1;
    const int g = lane >> 4, ln = lane & 15;
    const long n0 = (long)blockIdx.x * 128;

    for (int i = tid; i < 128 * 4; i += 512) {
        int r = i >> 2, c = i & 3;
        uint4 v = *(const uint4*)(cols + (n0 + r) * 32 + c * 8);
        *(uint4*)(lds + r * LINE + c * 16) = v;
    }
    __syncthreads();

    half8 af[2][4];
#pragma unroll
    for (int cv = 0; cv < 2; cv++)
#pragma unroll
    for (int m = 0; m < 4; m++)
        af[cv][m] = *(const half8*)(Wp + ((long)((cv * 8 + wm * 4 + m) * 64 + lane)) * 8);

    f32x4 accA[4][2], accB[4][2];
#pragma unroll
    for (int m = 0; m < 4; m++)
#pragma unroll
    for (int nf = 0; nf < 2; nf++) {
        accA[m][nf] = (f32x4){0.f, 0.f, 0.f, 0.f};
        accB[m][nf] = (f32x4){0.f, 0.f, 0.f, 0.f};
    }
#pragma unroll
    for (int nf = 0; nf < 2; nf++) {
        int r = wn * 32 + nf * 16 + ln;
        half8 b1 = *(const half8*)(lds + r * LINE + g * 16);
        half8 b2 = b1 * b1;
#pragma unroll
        for (int m = 0; m < 4; m++) {
            accA[m][nf] = __builtin_amdgcn_mfma_f32_16x16x32_f16(af[0][m], b1, accA[m][nf], 0, 0, 0);
            accB[m][nf] = __builtin_amdgcn_mfma_f32_16x16x32_f16(af[1][m], b2, accB[m][nf], 0, 0, 0);
        }
    }
    __syncthreads();
#pragma unroll
    for (int m = 0; m < 4; m++) {
        int cob = (wm * 4 + m) * 16 + g * 4;
#pragma unroll
        for (int nf = 0; nf < 2; nf++) {
            int nl = wn * 32 + nf * 16 + ln;
            unsigned int pk2[2];
#pragma unroll
            for (int r = 0; r < 4; r++) {
                float mm = accA[m][nf][r] + bias[cob + r];
                float vv = accB[m][nf][r];
                unsigned int hv = f2h(erff(mm * rsqrtf(vv + EPSV) * INV_SQRT2));
                if (r & 1) pk2[r >> 1] |= hv << 16; else pk2[r >> 1] = hv;
            }
            *(unsigned int*)(lds + (nl * TSTR + cob) * 2) = pk2[0];
            *(unsigned int*)(lds + (nl * TSTR + cob) * 2 + 4) = pk2[1];
        }
    }
    __syncthreads();
    for (int i = tid; i < 128 * 16; i += 512) {
        int nl = i >> 4, c8 = (i & 15) * 8;
        uint4 v = *(const uint4*)(lds + (nl * TSTR + c8) * 2);
        *(uint4*)(out + (n0 + nl) * 128 + c8) = v;
    }
}

// ---------------------------------------------------------------------------
// MFMA implicit-GEMM fused LRnet conv. NHWC fp16 input. 512 thr.
// T14 async-stage: issue next-chunk global loads into regs BEFORE compute,
// write to LDS after the read barrier. Stage addresses precomputed once.
// MODE 0: lrconv  -> erf -> NHWC fp16   (v = convB)
// MODE 1: ver2    -> erf -> NHWC fp16   (v = ones - convB)
// MODE 3: ver2 + sample -> NHWC fp16    (out = m + sqrt(v+eps)*epsb)
// MODE 4: ver2 + sample -> NCHW fp16
// ---------------------------------------------------------------------------
template<int Ci, int Hin, int Win, int Co, int Hout, int Wout, int STRIDE,
         int ROWS, int IPB, int NTILE, int CHUNK, int MTILE, int MODE>
__global__ __launch_bounds__(512) void conv_mfma(
    const unsigned short* __restrict__ in,
    const unsigned short* __restrict__ wpk,
    const float* __restrict__ bias,
    const float* __restrict__ ones_g,
    const float* __restrict__ epsb,
    void* __restrict__ outp)
{
    constexpr int BLK = 512;
    constexpr int PROWS = STRIDE * (ROWS - 1) + 3;
    constexpr int PW = Win + 2;
    constexpr int POS = IPB * PROWS * PW;
    constexpr int NCH32 = Ci / 32;
    constexpr int NCHL = Ci / CHUNK;
    constexpr int KS = CHUNK / 32;
    constexpr int MFg = Co / 16;
    constexpr int NF = NTILE / 16;
    constexpr int WMF = MTILE / 32;
    constexpr int WNF = NF / 4;
    constexpr int CT = Co / MTILE;
    constexpr int RG = Hout / ROWS;
    constexpr int LINE = CHUNK * 2 + 16;
    constexpr int TSTR = MTILE + 8;
    constexpr int PASSN = (NTILE < 128) ? NTILE : 128;
    constexpr int NPASS = (MODE == 4) ? 0 : NTILE / PASSN;
    constexpr int STAGE_B = POS * LINE;
    constexpr int TR_B = (MODE == 4) ? 0 : PASSN * TSTR * 2;
    constexpr int LDS_B = STAGE_B > TR_B ? STAGE_B : TR_B;
    constexpr int NV = POS * (CHUNK / 8);          // uint4 stage slots
    constexpr int NLD = (NV + BLK - 1) / BLK;      // per-thread loads
    static_assert(8 % CT == 0, "ct swizzle");
    static_assert(WNF * 4 == NF, "wnf");
    static_assert(WMF * 32 == MTILE, "wmf");
    static_assert(NCHL * CHUNK == Ci, "chunk");
    static_assert(LDS_B <= 65536, "lds");
    __shared__ char lds[LDS_B];

    const int tid = threadIdx.x;
    const int lane = tid & 63;
    const int wv = tid >> 6;
    const int wm = wv & 1, wn = wv >> 1;
    const int g = lane >> 4, ln = lane & 15;

    const int bid = blockIdx.x;
    const int xcd = bid & 7;
    constexpr int XPC = 8 / CT;
    const int ct = xcd % CT;
    const int nt = (bid >> 3) * XPC + xcd / CT;
    const int b0 = (nt / RG) * IPB;
    const int y0 = (nt % RG) * ROWS;

    int pbase[WNF];
#pragma unroll
    for (int nf = 0; nf < WNF; nf++) {
        int n = (wn * WNF + nf) * 16 + ln;
        int img = n / (ROWS * Wout);
        int rem = n % (ROWS * Wout);
        int yr = rem / Wout, xo = rem % Wout;
        pbase[nf] = (img * PROWS + STRIDE * yr) * PW + STRIDE * xo;
    }

    // ---- precompute per-thread stage addresses (ch-invariant) ----
    const unsigned short* gsrc[NLD];
    int ldst[NLD];
#pragma unroll
    for (int j = 0; j < NLD; j++) {
        int i = tid + j * BLK;
        gsrc[j] = nullptr; ldst[j] = 0;
        if (i < NV) {
            int p = i / (CHUNK / 8), c = i % (CHUNK / 8);
            int img = p / (PROWS * PW);
            int r = p % (PROWS * PW);
            int prow = r / PW, px = r % PW;
            int yin = STRIDE * y0 - 1 + prow;
            int xin = px - 1;
            ldst[j] = p * LINE + c * 16;
            if (yin >= 0 && yin < Hin && xin >= 0 && xin < Win)
                gsrc[j] = in + (((long)(b0 + img) * Hin + yin) * Win + xin) * Ci + c * 8;
        }
    }

    f32x4 accA[WMF][WNF], accB[WMF][WNF];
#pragma unroll
    for (int mf = 0; mf < WMF; mf++)
#pragma unroll
    for (int nf = 0; nf < WNF; nf++) {
        accA[mf][nf] = (f32x4){0.f, 0.f, 0.f, 0.f};
        accB[mf][nf] = (f32x4){0.f, 0.f, 0.f, 0.f};
    }

    const unsigned short* wbase = wpk + ((long)(ct * (MTILE / 16) + wm * WMF) * 64 + lane) * 8;

    // issue chunk-0 loads
    uint4 regs[NLD];
#pragma unroll
    for (int j = 0; j < NLD; j++) {
        uint4 v; v.x = 0; v.y = 0; v.z = 0; v.w = 0;
        if (tid + j * BLK < NV && gsrc[j]) v = *(const uint4*)(gsrc[j]);
        regs[j] = v;
    }

    for (int ch = 0; ch < NCHL; ch++) {
        // ---- write chunk ch (waits vmcnt on regs) ----
#pragma unroll
        for (int j = 0; j < NLD; j++)
            if (tid + j * BLK < NV) *(uint4*)(lds + ldst[j]) = regs[j];
        __syncthreads();
        // ---- issue chunk ch+1 loads (in flight during compute) ----
        if (ch + 1 < NCHL) {
#pragma unroll
            for (int j = 0; j < NLD; j++) {
                uint4 v; v.x = 0; v.y = 0; v.z = 0; v.w = 0;
                if (tid + j * BLK < NV && gsrc[j])
                    v = *(const uint4*)(gsrc[j] + (long)(ch + 1) * CHUNK);
                regs[j] = v;
            }
        }
        // ---- compute chunk ch: 9 kernel positions x KS k-substeps ----
#pragma unroll 3
        for (int pos = 0; pos < 9; pos++) {
            const int ky = pos / 3, kx = pos % 3;
#pragma unroll
            for (int ks = 0; ks < KS; ks++) {
                const int ch32 = ch * KS + ks;
                half8 af[2][WMF];
#pragma unroll
                for (int cv = 0; cv < 2; cv++)
#pragma unroll
                for (int mf = 0; mf < WMF; mf++)
                    af[cv][mf] = *(const half8*)(wbase +
                        ((long)(((cv * 9 + pos) * NCH32 + ch32) * MFg + mf)) * 512);
#pragma unroll
                for (int nf = 0; nf < WNF; nf++) {
                    int po = (pbase[nf] + ky * PW + kx) * LINE + ks * 64 + g * 16;
                    half8 b1 = *(const half8*)(lds + po);
                    half8 b2 = b1 * b1;               // v_pk_mul_f16
#pragma unroll
                    for (int mf = 0; mf < WMF; mf++) {
                        accA[mf][nf] = __builtin_amdgcn_mfma_f32_16x16x32_f16(af[0][mf], b1, accA[mf][nf], 0, 0, 0);
                        accB[mf][nf] = __builtin_amdgcn_mfma_f32_16x16x32_f16(af[1][mf], b2, accB[mf][nf], 0, 0, 0);
                    }
                }
            }
        }
        __syncthreads();
    }

    // ---- epilogue ----
    if constexpr (MODE == 4) {
        unsigned short* out = (unsigned short*)outp;
#pragma unroll
        for (int mf = 0; mf < WMF; mf++) {
            int co = ct * MTILE + (wm * WMF + mf) * 16 + g * 4;
#pragma unroll
            for (int nf = 0; nf < WNF; nf++) {
                int n = (wn * WNF + nf) * 16 + ln;
                int img = n / (ROWS * Wout), rem = n % (ROWS * Wout);
                int y = y0 + rem / Wout, x = rem % Wout;
                int b = b0 + img;
#pragma unroll
                for (int r = 0; r < 4; r++) {
                    int c = co + r;
                    float m = accA[mf][nf][r] + bias[c];
                    float v = ones_g[(c * Hout + y) * Wout + x] - accB[mf][nf][r];
                    long oi = (((long)b * Co + c) * Hout + y) * Wout + x;
                    out[oi] = f2h(m + sqrtf(v + EPSV) * epsb[oi]);
                }
            }
        }
    } else {
        unsigned short* out = (unsigned short*)outp;
#pragma unroll
        for (int pass = 0; pass < NPASS; pass++) {
            __syncthreads();
#pragma unroll
            for (int mf = 0; mf < WMF; mf++) {
                int cob = (wm * WMF + mf) * 16 + g * 4;
                int cg = ct * MTILE + cob;
#pragma unroll
                for (int nf = 0; nf < WNF; nf++) {
                    int nb = (wn * WNF + nf) * 16;
                    if (nb < pass * PASSN || nb >= (pass + 1) * PASSN) continue;
                    int n = nb + ln;
                    int img = n / (ROWS * Wout), rem = n % (ROWS * Wout);
                    int y = y0 + rem / Wout, x = rem % Wout;
                    int b = b0 + img;
                    unsigned int pk2[2];
#pragma unroll
                    for (int r = 0; r < 4; r++) {
                        int c = cg + r;
                        float m = accA[mf][nf][r] + bias[c];
                        float val;
                        if constexpr (MODE == 0) {
                            val = erff(m * rsqrtf(accB[mf][nf][r] + EPSV) * INV_SQRT2);
                        } else if constexpr (MODE == 1) {
                            float v = ones_g[(c * Hout + y) * Wout + x] - accB[mf][nf][r];
                            val = erff(m * rsqrtf(v + EPSV) * INV_SQRT2);
                        } else { // MODE 3
                            float v = ones_g[(c * Hout + y) * Wout + x] - accB[mf][nf][r];
                            float ev = epsb[(((long)b * Co + c) * Hout + y) * Wout + x];
                            val = m + sqrtf(v + EPSV) * ev;
                        }
                        unsigned int hv = f2h(val);
                        if (r & 1) pk2[r >> 1] |= hv << 16; else pk2[r >> 1] = hv;
                    }
                    int nl = n - pass * PASSN;
                    *(unsigned int*)(lds + (nl * TSTR + cob) * 2) = pk2[0];
                    *(unsigned int*)(lds + (nl * TSTR + cob) * 2 + 4) = pk2[1];
                }
            }
            __syncthreads();
            for (int i = tid; i < PASSN * (MTILE / 8); i += BLK) {
                int nl = i / (MTILE / 8);
                int n = pass * PASSN + nl;
                int c8 = (i % (MTILE / 8)) * 8;
                int img = n / (ROWS * Wout), rem = n % (ROWS * Wout);
                int y = y0 + rem / Wout, x = rem % Wout;
                int b = b0 + img;
                uint4 val = *(const uint4*)(lds + (nl * TSTR + c8) * 2);
                long oa = (((long)b * Hout + y) * Wout + x) * Co + ct * MTILE + c8;
                *(uint4*)(out + oa) = val;
            }
        }
    }
}

// ---------------------------------------------------------------------------
// BatchNorm (fp16 activations, partial-sum based, no atomics)
// ---------------------------------------------------------------------------
__global__ void bn_part_nhwc(const unsigned short* __restrict__ h, float* __restrict__ part,
                             int C, int rpc) {
    int c = threadIdx.x;
    long r0 = (long)blockIdx.x * rpc;
    float s = 0.f, s2 = 0.f;
    for (int r = 0; r < rpc; r++) {
        float v = h2f(h[(r0 + r) * C + c]);
        s += v; s2 += v * v;
    }
    part[(long)blockIdx.x * 2 * C + c] = s;
    part[(long)blockIdx.x * 2 * C + C + c] = s2;
}

__global__ void bn_part_nchw(const unsigned short* __restrict__ h, float* __restrict__ part,
                             int ipc) {
    int c = threadIdx.x;
    int b0 = blockIdx.x * ipc;
    float s = 0.f, s2 = 0.f;
    for (int b = 0; b < ipc; b++) {
        const unsigned short* p = h + ((long)(b0 + b) * 512 + c) * 16;
        uint4 v0 = *(const uint4*)p;
        uint4 v1 = *(const uint4*)(p + 8);
        unsigned int* vp0 = (unsigned int*)&v0;
        unsigned int* vp1 = (unsigned int*)&v1;
#pragma unroll
        for (int e = 0; e < 4; e++) {
            float a = h2f((unsigned short)(vp0[e] & 0xffffu)), bb = h2f((unsigned short)(vp0[e] >> 16));
            float cc = h2f((unsigned short)(vp1[e] & 0xffffu)), d = h2f((unsigned short)(vp1[e] >> 16));
            s += a + bb + cc + d;
            s2 += a * a + bb * bb + cc * cc + d * d;
        }
    }
    part[(long)blockIdx.x * 1024 + c] = s;
    part[(long)blockIdx.x * 1024 + 512 + c] = s2;
}

__global__ void bn_fin(const float* __restrict__ part, const float* __restrict__ gamma,
                       const float* __restrict__ beta, float* __restrict__ sc,
                       float* __restrict__ sh, int C, int chunks, float invN) {
    int c = blockIdx.x * 256 + threadIdx.x;
    if (c >= C) return;
    float s = 0.f, s2 = 0.f;
    for (int j = 0; j < chunks; j++) {
        s += part[(long)j * 2 * C + c];
        s2 += part[(long)j * 2 * C + C + c];
    }
    float mean = s * invN;
    float var = s2 * invN - mean * mean;
    float k = gamma[c] * rsqrtf(var + BNEPS);
    sc[c] = k;
    sh[c] = beta[c] - mean * k;
}

__global__ void bn_app_nhwc(unsigned short* __restrict__ h, const float* __restrict__ sc,
                            const float* __restrict__ sh) {
    int i = blockIdx.x * 256 + threadIdx.x;   // 2097152 total
    int cb = (i & 31) * 8;
    uint4 v = *(uint4*)(h + (long)i * 8);
    float4 s0 = *(const float4*)(sc + cb), s1 = *(const float4*)(sc + cb + 4);
    float4 t0 = *(const float4*)(sh + cb), t1 = *(const float4*)(sh + cb + 4);
    float scl[8] = {s0.x, s0.y, s0.z, s0.w, s1.x, s1.y, s1.z, s1.w};
    float shf[8] = {t0.x, t0.y, t0.z, t0.w, t1.x, t1.y, t1.z, t1.w};
    unsigned int* vp = (unsigned int*)&v;
#pragma unroll
    for (int e = 0; e < 4; e++) {
        float lo = h2f((unsigned short)(vp[e] & 0xffffu));
        float hi = h2f((unsigned short)(vp[e] >> 16));
        lo = fmaf(lo, scl[2 * e], shf[2 * e]);     lo = lo > 0.f ? lo : 0.f;
        hi = fmaf(hi, scl[2 * e + 1], shf[2 * e + 1]); hi = hi > 0.f ? hi : 0.f;
        vp[e] = (unsigned int)f2h(lo) | (((unsigned int)f2h(hi)) << 16);
    }
    *(uint4*)(h + (long)i * 8) = v;
}

__global__ void bn_app_nchw(unsigned short* __restrict__ h, const float* __restrict__ sc,
                            const float* __restrict__ sh) {
    int i = blockIdx.x * 256 + threadIdx.x;   // 524288 total
    int c = (i >> 1) & 511;
    float k = sc[c], t = sh[c];
    uint4 v = *(uint4*)(h + (long)i * 8);
    unsigned int* vp = (unsigned int*)&v;
#pragma unroll
    for (int e = 0; e < 4; e++) {
        float lo = h2f((unsigned short)(vp[e] & 0xffffu));
        float hi = h2f((unsigned short)(vp[e] >> 16));
        lo = fmaf(lo, k, t); lo = lo > 0.f ? lo : 0.f;
        hi = fmaf(hi, k, t); hi = hi > 0.f ? hi : 0.f;
        vp[e] = (unsigned int)f2h(lo) | (((unsigned int)f2h(hi)) << 16);
    }
    *(uint4*)(h + (long)i * 8) = v;
}

// ---------------------------------------------------------------------------
// FC1 fp16 MFMA split-K + reduce
// ---------------------------------------------------------------------------
__global__ __launch_bounds__(256) void fc1_mfma(const unsigned short* __restrict__ Ab,
                                                const unsigned short* __restrict__ Wp,
                                                float* __restrict__ pbuf) {
    __shared__ char lds[2 * 64 * 80];
    const int tid = threadIdx.x;
    const int lane = tid & 63;
    const int wv = tid >> 6;
    const int g = lane >> 4, ln = lane & 15;
    const int ot = blockIdx.x, bt = blockIdx.y, s = blockIdx.z;
    const int b0 = bt * 64;
    const int k0g = s * 1024;

    f32x4 acc[2][4];
#pragma unroll
    for (int c = 0; c < 2; c++)
#pragma unroll
    for (int nf = 0; nf < 4; nf++) acc[c][nf] = (f32x4){0.f, 0.f, 0.f, 0.f};

    for (int k0 = 0; k0 < 1024; k0 += 64) {
        __syncthreads();
        for (int i = tid; i < 512; i += 256) {
            int row = i >> 3, kk = (i >> 2) & 1, seg = i & 3;
            uint4 v = *(const uint4*)(Ab + ((long)(b0 + row) * 8192 + k0g + k0 + kk * 32 + seg * 8));
            *(uint4*)(lds + (kk * 64 + row) * 80 + seg * 16) = v;
        }
        __syncthreads();
#pragma unroll
        for (int kk = 0; kk < 2; kk++) {
            int kt = (k0g + k0) / 32 + kk;
            half8 af[2];
#pragma unroll
            for (int c = 0; c < 2; c++) {
                int mf = ot * 8 + wv * 2 + c;
                af[c] = *(const half8*)(Wp + (((long)kt * 64 + mf) * 64 + lane) * 8);
            }
            half8 bf[4];
#pragma unroll
            for (int nf = 0; nf < 4; nf++)
                bf[nf] = *(const half8*)(lds + (kk * 64 + nf * 16 + ln) * 80 + g * 16);
#pragma unroll
            for (int c = 0; c < 2; c++)
#pragma unroll
            for (int nf = 0; nf < 4; nf++)
                acc[c][nf] = __builtin_amdgcn_mfma_f32_16x16x32_f16(af[c], bf[nf], acc[c][nf], 0, 0, 0);
        }
    }
#pragma unroll
    for (int c = 0; c < 2; c++) {
        int o = ot * 128 + (wv * 2 + c) * 16 + g * 4;
#pragma unroll
        for (int nf = 0; nf < 4; nf++) {
            int b = b0 + nf * 16 + ln;
            *(f32x4*)(pbuf + ((long)s * 256 + b) * 1024 + o) = acc[c][nf];
        }
    }
}

__global__ void fc1_reduce(const float* __restrict__ pbuf, const float* __restrict__ bias,
                           float* __restrict__ out) {
    int idx = blockIdx.x * 256 + threadIdx.x;
    float s = 0.f;
#pragma unroll
    for (int j = 0; j < 8; j++) s += pbuf[(long)j * 262144 + idx];
    s += bias[idx & 1023];
    out[idx] = s > 0.f ? s : 0.f;
}

__global__ void fc2_k(const float* __restrict__ A, const float* __restrict__ W,
                      const float* __restrict__ b2, float* __restrict__ out) {
    int bb = blockIdx.x;
    int tid = threadIdx.x;
    float acc[10];
#pragma unroll
    for (int o = 0; o < 10; o++) acc[o] = 0.f;
    const float* arow = A + (long)bb * 1024;
    for (int k = tid; k < 1024; k += 256) {
        float a = arow[k];
#pragma unroll
        for (int o = 0; o < 10; o++) acc[o] = fmaf(a, W[o * 1024 + k], acc[o]);
    }
#pragma unroll
    for (int o = 0; o < 10; o++)
        for (int off = 32; off > 0; off >>= 1) acc[o] += __shfl_down(acc[o], off);
    __shared__ float red[10][4];
    int wid = tid >> 6, lane = tid & 63;
    if (lane == 0) {
#pragma unroll
        for (int o = 0; o < 10; o++) red[o][wid] = acc[o];
    }
    __syncthreads();
    if (tid < 10)
        out[bb * 10 + tid] = red[tid][0] + red[tid][1] + red[tid][2] + red[tid][3] + b2[tid];
}

// ---------------------------------------------------------------------------
extern "C" void kernel_launch(void* const* d_in, const int* in_sizes, int n_in,
                              void* d_out, int out_size, void* d_ws, size_t ws_size,
                              hipStream_t stream) {
    const float* x  = (const float*)d_in[0];
    const float* a1 = (const float*)d_in[1];  const float* b1 = (const float*)d_in[2];  const float* c1 = (const float*)d_in[3];
    const float* a2 = (const float*)d_in[4];  const float* b2 = (const float*)d_in[5];  const float* c2 = (const float*)d_in[6];
    const float* a3 = (const float*)d_in[7];  const float* b3 = (const float*)d_in[8];  const float* c3 = (const float*)d_in[9];
    const float* a4 = (const float*)d_in[10]; const float* b4 = (const float*)d_in[11]; const float* c4 = (const float*)d_in[12];
    const float* a5 = (const float*)d_in[13]; const float* b5 = (const float*)d_in[14]; const float* c5 = (const float*)d_in[15];
    const float* a6 = (const float*)d_in[16]; const float* b6 = (const float*)d_in[17]; const float* c6 = (const float*)d_in[18];
    const float* g3 = (const float*)d_in[19]; const float* be3 = (const float*)d_in[20];
    const float* g6 = (const float*)d_in[21]; const float* be6 = (const float*)d_in[22];
    const float* fc1w = (const float*)d_in[23]; const float* fc1b = (const float*)d_in[24];
    const float* fc2w = (const float*)d_in[25]; const float* fc2b = (const float*)d_in[26];
    const float* eps3 = (const float*)d_in[27]; const float* eps6 = (const float*)d_in[28];
    (void)in_sizes; (void)n_in; (void)out_size; (void)ws_size;

    float* w = (float*)d_ws;
    size_t off = 0;
    auto alloc = [&](size_t n) { float* p = w + off; off += n; return p; };
    unsigned short* pk2 = (unsigned short*)alloc(147456);
    unsigned short* pk3 = (unsigned short*)alloc(294912);
    unsigned short* pk4 = (unsigned short*)alloc(589824);
    unsigned short* pk5 = (unsigned short*)alloc(1179648);
    unsigned short* pk6 = (unsigned short*)alloc(2359296);
    unsigned short* pkL1 = (unsigned short*)alloc(4096);
    float* wa1 = alloc(3456); float* wb1 = alloc(3456);
    float* ss2 = alloc(1152); float* ss3 = alloc(2304);
    float* ss5 = alloc(4608); float* ss6 = alloc(4608);
    float* og2 = alloc(32768); float* og3 = alloc(65536);
    float* og5 = alloc(32768); float* og6 = alloc(8192);
    float* part3 = alloc(131072);
    float* part6 = alloc(65536);
    float* sc3 = alloc(256); float* sh3 = alloc(256);
    float* sc6 = alloc(512); float* sh6 = alloc(512);
    float* A  = alloc(16777216);
    float* Bb = alloc(4194304);
    float* Cc = alloc(8388608);
    float* Dd = alloc(2097152);
    float* Ee = alloc(4194304);

    unsigned short* ex1 = (unsigned short*)A;
    unsigned short* pkF = (unsigned short*)A;
    float*          pbuf = A + 4194304;
    unsigned short* ex2 = (unsigned short*)Bb;
    float*          fco = Bb;
    unsigned short* h6b = (unsigned short*)(Bb + 524288);
    unsigned short* colsL1 = (unsigned short*)Cc;
    unsigned short* h3b = (unsigned short*)Cc;
    unsigned short* ex4 = (unsigned short*)Dd;
    unsigned short* ex5 = (unsigned short*)Ee;

    // ---- prep ----
    prep_w<<<14, 256, 0, stream>>>(a1, b1, wa1, wb1, 3456);
    prep_packL1<<<4, 256, 0, stream>>>(wa1, wb1, pkL1);
    prep_pack<<<72,  256, 0, stream>>>(a2, b2, pk2, 128, 128, 1, 18432);
    prep_pack<<<144, 256, 0, stream>>>(a3, b3, pk3, 128, 256, 1, 36864);
    prep_pack<<<288, 256, 0, stream>>>(a4, b4, pk4, 256, 256, 0, 73728);
    prep_pack<<<576, 256, 0, stream>>>(a5, b5, pk5, 256, 512, 1, 147456);
    prep_pack<<<1152,256, 0, stream>>>(a6, b6, pk6, 512, 512, 1, 294912);
    prep_s<<<128, 64, 0, stream>>>(a2, ss2, 128);
    prep_s<<<256, 64, 0, stream>>>(a3, ss3, 128);
    prep_s<<<512, 64, 0, stream>>>(a5, ss5, 256);
    prep_s<<<512, 64, 0, stream>>>(a6, ss6, 512);
    prep_ones<<<128, 256, 0, stream>>>(ss2, og2, 128, 16, 16, 32, 32, 2, 32768);
    prep_ones<<<256, 256, 0, stream>>>(ss3, og3, 256, 16, 16, 16, 16, 1, 65536);
    prep_ones<<<128, 256, 0, stream>>>(ss5, og5, 512, 8, 8, 8, 8, 1, 32768);
    prep_ones<<<32,  256, 0, stream>>>(ss6, og6, 512, 4, 4, 8, 8, 2, 8192);

    // ---- network ----
    // L1: im2col + MFMA GEMM -> ex1 [256,32,32,128] NHWC fp16
    l1_im2col<<<1024, 256, 0, stream>>>(x, colsL1);
    conv1_mfma<<<2048, 512, 0, stream>>>(colsL1, pkL1, c1, ex1);
    // L2: [256,32,32,128] -> [256,16,16,128]
    conv_mfma<128,32,32,128,16,16,2, 8,1,128,32,128,1><<<512, 512, 0, stream>>>(ex1, pk2, c2, og2, nullptr, ex2);
    // L3: -> h3b [256,16,16,256] NHWC fp16 (sampled)
    conv_mfma<128,16,16,256,16,16,1, 8,2,256,64,128,3><<<512, 512, 0, stream>>>(ex2, pk3, c3, og3, eps3, h3b);
    // FC1 weight pack into A (ex1 dead after L2)
    prep_fc1<<<4096, 256, 0, stream>>>(fc1w, pkF);
    // BN3 (fp16 NHWC, in place)
    bn_part_nhwc<<<256, 256, 0, stream>>>(h3b, part3, 256, 256);
    bn_fin<<<1, 256, 0, stream>>>(part3, g3, be3, sc3, sh3, 256, 256, 1.f / 65536.f);
    bn_app_nhwc<<<8192, 256, 0, stream>>>(h3b, sc3, sh3);
    // L4: [256,16,16,256] -> [256,8,8,256]
    conv_mfma<256,16,16,256, 8, 8,2, 8,1,64,32,128,0><<<512, 512, 0, stream>>>(h3b, pk4, c4, nullptr, nullptr, ex4);
    // L5: -> [256,8,8,512]
    conv_mfma<256, 8, 8,512, 8, 8,1, 8,2,128,32,128,1><<<512, 512, 0, stream>>>(ex4, pk5, c5, og5, nullptr, ex5);
    // L6: -> h6b [256,512,4,4] NCHW fp16 (sampled)  MTILE=64 -> CT=8, grid 512
    conv_mfma<512, 8, 8,512, 4, 4,2, 4,4,64,32,64,4><<<512, 512, 0, stream>>>(ex5, pk6, c6, og6, eps6, h6b);
    // BN6 (fp16 NCHW, in place)
    bn_part_nchw<<<64, 512, 0, stream>>>(h6b, part6, 4);
    bn_fin<<<2, 256, 0, stream>>>(part6, g6, be6, sc6, sh6, 512, 64, 1.f / 4096.f);
    bn_app_nchw<<<2048, 256, 0, stream>>>(h6b, sc6, sh6);
    // FC1 + FC2
    fc1_mfma<<<dim3(8, 4, 8), 256, 0, stream>>>(h6b, pkF, pbuf);
    fc1_reduce<<<1024, 256, 0, stream>>>(pbuf, fc1b, fco);
    fc2_k<<<256, 256, 0, stream>>>(fco, fc2w, fc2b, (float*)d_out);
}

// Round 13
// 744.299 us; speedup vs baseline: 1.4549x; 1.0621x over previous
//
#include <hip/hip_runtime.h>
#include <hip/hip_bf16.h>
#include <math.h>

#define EPSV 1e-10f
#define BNEPS 1e-5f
#define INV_SQRT2 0.70710678118654752440f

typedef __attribute__((ext_vector_type(8))) short short8;
typedef __attribute__((ext_vector_type(4))) float f32x4;
typedef _Float16 half8 __attribute__((ext_vector_type(8)));

__device__ __forceinline__ unsigned short f2h(float f) {
    _Float16 h = (_Float16)f;                      // RNE
    return __builtin_bit_cast(unsigned short, h);
}
__device__ __forceinline__ float h2f(unsigned short u) {
    _Float16 h = __builtin_bit_cast(_Float16, u);
    return (float)h;
}

// ---------------------------------------------------------------------------
// L1 weight prep (fp32)
// ---------------------------------------------------------------------------
__global__ void prep_w(const float* __restrict__ a, const float* __restrict__ b,
                       float* __restrict__ WA, float* __restrict__ WB, int n) {
    for (int i = blockIdx.x * blockDim.x + threadIdx.x; i < n; i += gridDim.x * blockDim.x) {
        float p0 = 1.f / (1.f + expf(-a[i]));
        float sb = 1.f / (1.f + expf(-b[i]));
        float p1 = (1.f - p0) * sb;
        float ew = 2.f * p1 - (1.f - p0);
        float ew2 = 1.f - p0;
        WA[i] = ew;
        WB[i] = ew2 - ew * ew;
    }
}

// L1 weights -> MFMA A-fragment order (fp16), K=32 (27 used), 2cv x 8mf
__global__ void prep_packL1(const float* __restrict__ wa, const float* __restrict__ wb,
                            unsigned short* __restrict__ pk) {
    int idx = blockIdx.x * 256 + threadIdx.x;   // 1024 total
    if (idx >= 1024) return;
    int lane = idx & 63;
    int mf = (idx >> 6) & 7;
    int cv = idx >> 9;
    int co = mf * 16 + (lane & 15);
    int k0 = (lane >> 4) * 8;
    const float* src = (cv ? wb : wa) + co * 27;
    unsigned int o[4] = {0, 0, 0, 0};
#pragma unroll
    for (int j = 0; j < 8; j++) {
        int k = k0 + j;
        if (k < 27) {
            unsigned int h = f2h(src[k]);
            o[j >> 1] |= h << ((j & 1) * 16);
        }
    }
    uint4 v; v.x = o[0]; v.y = o[1]; v.z = o[2]; v.w = o[3];
    *(uint4*)(pk + (long)idx * 8) = v;
}

// ---------------------------------------------------------------------------
// Pack ternary-stat weights into MFMA A-fragment order (fp16).
// ---------------------------------------------------------------------------
__global__ void prep_pack(const float* __restrict__ a, const float* __restrict__ b,
                          unsigned short* __restrict__ pk, int Ci, int Co, int ver2, int total) {
    int idx = blockIdx.x * 256 + threadIdx.x;
    if (idx >= total) return;
    int lane = idx & 63;
    int MFg = Co >> 4, NCH = Ci >> 5;
    int mfch = idx >> 6;
    int mf = mfch % MFg;
    int chpos = mfch / MFg;
    int ch = chpos % NCH;
    int pos = chpos / NCH;
    int co = mf * 16 + (lane & 15);
    int cib = ch * 32 + (lane >> 4) * 8;
    unsigned int wa[4], wb[4];
#pragma unroll
    for (int j = 0; j < 8; j++) {
        long s = ((long)co * Ci + cib + j) * 9 + pos;
        float p0 = 1.f / (1.f + expf(-a[s]));
        float sb = 1.f / (1.f + expf(-b[s]));
        float p1 = (1.f - p0) * sb;
        float ew = 2.f * p1 - (1.f - p0);
        float ew2 = 1.f - p0;
        unsigned int ha = f2h(ew);
        unsigned int hb = f2h(ver2 ? ew * ew : ew2 - ew * ew);
        if (j & 1) { wa[j >> 1] |= ha << 16; wb[j >> 1] |= hb << 16; }
        else       { wa[j >> 1] = ha;        wb[j >> 1] = hb; }
    }
    long b0 = (((long)(0 * 9 + pos) * NCH + ch) * MFg + mf) * 64 + lane;
    long b1 = (((long)(1 * 9 + pos) * NCH + ch) * MFg + mf) * 64 + lane;
    uint4 va; va.x = wa[0]; va.y = wa[1]; va.z = wa[2]; va.w = wa[3];
    uint4 vb; vb.x = wb[0]; vb.y = wb[1]; vb.z = wb[2]; vb.w = wb[3];
    *(uint4*)(pk + b0 * 8) = va;
    *(uint4*)(pk + b1 * 8) = vb;
}

// ssum[co][k] = sum_ci sigmoid(-alpha)
__global__ void prep_s(const float* __restrict__ alpha, float* __restrict__ s, int Ci) {
    int co = blockIdx.x;
    int lane = threadIdx.x;
    float acc[9];
#pragma unroll
    for (int k = 0; k < 9; k++) acc[k] = 0.f;
    for (int ci = lane; ci < Ci; ci += 64) {
        const float* p = alpha + ((long)co * Ci + ci) * 9;
#pragma unroll
        for (int k = 0; k < 9; k++) acc[k] += 1.f / (1.f + expf(p[k]));
    }
#pragma unroll
    for (int k = 0; k < 9; k++) {
        for (int off = 32; off > 0; off >>= 1) acc[k] += __shfl_down(acc[k], off);
    }
    if (lane == 0) {
#pragma unroll
        for (int k = 0; k < 9; k++) s[co * 9 + k] = acc[k];
    }
}

__global__ void prep_ones(const float* __restrict__ ssum, float* __restrict__ og,
                          int Co, int Hout, int Wout, int Hin, int Win, int stride, int total) {
    int idx = blockIdx.x * 256 + threadIdx.x;
    if (idx >= total) return;
    int x = idx % Wout, y = (idx / Wout) % Hout, co = idx / (Wout * Hout);
    float s = 0.f;
    for (int ky = 0; ky < 3; ky++) {
        int yi = stride * y - 1 + ky;
        if (yi < 0 || yi >= Hin) continue;
        for (int kx = 0; kx < 3; kx++) {
            int xi = stride * x - 1 + kx;
            if (xi < 0 || xi >= Win) continue;
            s += ssum[co * 9 + ky * 3 + kx];
        }
    }
    og[idx] = s;
}

// ---------------------------------------------------------------------------
// FC1 weight pack: fp32 [1024][8192] -> fp16 A-fragment order
// ---------------------------------------------------------------------------
__global__ void prep_fc1(const float* __restrict__ W, unsigned short* __restrict__ pk) {
    int idx = blockIdx.x * 256 + threadIdx.x;
    int lane = idx & 63;
    int mf = (idx >> 6) & 63;
    int kt = idx >> 12;
    int o = mf * 16 + (lane & 15);
    long k = (long)kt * 32 + (lane >> 4) * 8;
    const float* src = W + (long)o * 8192 + k;
    float4 f0 = *(const float4*)src;
    float4 f1 = *(const float4*)(src + 4);
    uint4 v;
    v.x = (unsigned)f2h(f0.x) | ((unsigned)f2h(f0.y) << 16);
    v.y = (unsigned)f2h(f0.z) | ((unsigned)f2h(f0.w) << 16);
    v.z = (unsigned)f2h(f1.x) | ((unsigned)f2h(f1.y) << 16);
    v.w = (unsigned)f2h(f1.z) | ((unsigned)f2h(f1.w) << 16);
    *(uint4*)(pk + (long)idx * 8) = v;
}

// ---------------------------------------------------------------------------
// L1 im2col: x [256,3,32,32] fp32 -> cols[n][32] fp16
// ---------------------------------------------------------------------------
__global__ void l1_im2col(const float* __restrict__ x, unsigned short* __restrict__ cols) {
    int n = blockIdx.x * 256 + threadIdx.x;   // 262144
    int b = n >> 10, y = (n >> 5) & 31, xx = n & 31;
    unsigned int o[16];
#pragma unroll
    for (int i = 0; i < 16; i++) o[i] = 0;
#pragma unroll
    for (int ci = 0; ci < 3; ci++)
#pragma unroll
    for (int ky = 0; ky < 3; ky++) {
        int yy = y - 1 + ky;
        if (yy < 0 || yy > 31) continue;
#pragma unroll
        for (int kx = 0; kx < 3; kx++) {
            int xc = xx - 1 + kx;
            if (xc < 0 || xc > 31) continue;
            float v = x[((b * 3 + ci) * 32 + yy) * 32 + xc];
            int k = ci * 9 + ky * 3 + kx;
            o[k >> 1] |= ((unsigned int)f2h(v)) << ((k & 1) * 16);
        }
    }
    uint4* dst = (uint4*)(cols + (long)n * 32);
    uint4 v0; v0.x = o[0];  v0.y = o[1];  v0.z = o[2];  v0.w = o[3];
    uint4 v1; v1.x = o[4];  v1.y = o[5];  v1.z = o[6];  v1.w = o[7];
    uint4 v2; v2.x = o[8];  v2.y = o[9];  v2.z = o[10]; v2.w = o[11];
    uint4 v3; v3.x = o[12]; v3.y = o[13]; v3.z = o[14]; v3.w = o[15];
    dst[0] = v0; dst[1] = v1; dst[2] = v2; dst[3] = v3;
}

// ---------------------------------------------------------------------------
// L1 MFMA GEMM
// ---------------------------------------------------------------------------
__global__ __launch_bounds__(512) void conv1_mfma(const unsigned short* __restrict__ cols,
        const unsigned short* __restrict__ Wp, const float* __restrict__ bias,
        unsigned short* __restrict__ out) {
    constexpr int LINE = 80;
    constexpr int TSTR = 136;
    __shared__ char lds[128 * TSTR * 2];
    const int tid = threadIdx.x, lane = tid & 63, wv = tid >> 6;
    const int wm = wv & 1, wn = wv >> 1;
    const int g = lane >> 4, ln = lane & 15;
    const long n0 = (long)blockIdx.x * 128;

    for (int i = tid; i < 128 * 4; i += 512) {
        int r = i >> 2, c = i & 3;
        uint4 v = *(const uint4*)(cols + (n0 + r) * 32 + c * 8);
        *(uint4*)(lds + r * LINE + c * 16) = v;
    }
    __syncthreads();

    half8 af[2][4];
#pragma unroll
    for (int cv = 0; cv < 2; cv++)
#pragma unroll
    for (int m = 0; m < 4; m++)
        af[cv][m] = *(const half8*)(Wp + ((long)((cv * 8 + wm * 4 + m) * 64 + lane)) * 8);

    f32x4 accA[4][2], accB[4][2];
#pragma unroll
    for (int m = 0; m < 4; m++)
#pragma unroll
    for (int nf = 0; nf < 2; nf++) {
        accA[m][nf] = (f32x4){0.f, 0.f, 0.f, 0.f};
        accB[m][nf] = (f32x4){0.f, 0.f, 0.f, 0.f};
    }
#pragma unroll
    for (int nf = 0; nf < 2; nf++) {
        int r = wn * 32 + nf * 16 + ln;
        half8 b1 = *(const half8*)(lds + r * LINE + g * 16);
        half8 b2 = b1 * b1;
#pragma unroll
        for (int m = 0; m < 4; m++) {
            accA[m][nf] = __builtin_amdgcn_mfma_f32_16x16x32_f16(af[0][m], b1, accA[m][nf], 0, 0, 0);
            accB[m][nf] = __builtin_amdgcn_mfma_f32_16x16x32_f16(af[1][m], b2, accB[m][nf], 0, 0, 0);
        }
    }
    __syncthreads();
#pragma unroll
    for (int m = 0; m < 4; m++) {
        int cob = (wm * 4 + m) * 16 + g * 4;
#pragma unroll
        for (int nf = 0; nf < 2; nf++) {
            int nl = wn * 32 + nf * 16 + ln;
            unsigned int pk2[2];
#pragma unroll
            for (int r = 0; r < 4; r++) {
                float mm = accA[m][nf][r] + bias[cob + r];
                float vv = accB[m][nf][r];
                unsigned int hv = f2h(erff(mm * rsqrtf(vv + EPSV) * INV_SQRT2));
                if (r & 1) pk2[r >> 1] |= hv << 16; else pk2[r >> 1] = hv;
            }
            *(unsigned int*)(lds + (nl * TSTR + cob) * 2) = pk2[0];
            *(unsigned int*)(lds + (nl * TSTR + cob) * 2 + 4) = pk2[1];
        }
    }
    __syncthreads();
    for (int i = tid; i < 128 * 16; i += 512) {
        int nl = i >> 4, c8 = (i & 15) * 8;
        uint4 v = *(const uint4*)(lds + (nl * TSTR + c8) * 2);
        *(uint4*)(out + (n0 + nl) * 128 + c8) = v;
    }
}

// ---------------------------------------------------------------------------
// MFMA implicit-GEMM fused LRnet conv. NHWC fp16 input. 512 thr.
// Wave split 4M x 2N (halves A-fragment L2 traffic vs 2M x 4N).
// T14 async-stage kept. MODEs as before.
// ---------------------------------------------------------------------------
template<int Ci, int Hin, int Win, int Co, int Hout, int Wout, int STRIDE,
         int ROWS, int IPB, int NTILE, int CHUNK, int MTILE, int MODE>
__global__ __launch_bounds__(512) void conv_mfma(
    const unsigned short* __restrict__ in,
    const unsigned short* __restrict__ wpk,
    const float* __restrict__ bias,
    const float* __restrict__ ones_g,
    const float* __restrict__ epsb,
    void* __restrict__ outp)
{
    constexpr int BLK = 512;
    constexpr int PROWS = STRIDE * (ROWS - 1) + 3;
    constexpr int PW = Win + 2;
    constexpr int POS = IPB * PROWS * PW;
    constexpr int NCH32 = Ci / 32;
    constexpr int NCHL = Ci / CHUNK;
    constexpr int KS = CHUNK / 32;
    constexpr int MFg = Co / 16;
    constexpr int NF = NTILE / 16;
    constexpr int WMF = MTILE / 64;          // 4 M-wave groups
    constexpr int WNF = NF / 2;              // 2 N-wave groups
    constexpr int CT = Co / MTILE;
    constexpr int RG = Hout / ROWS;
    constexpr int LINE = CHUNK * 2 + 16;
    constexpr int TSTR = MTILE + 8;
    constexpr int PASSN = (NTILE < 128) ? NTILE : 128;
    constexpr int NPASS = (MODE == 4) ? 0 : NTILE / PASSN;
    constexpr int STAGE_B = POS * LINE;
    constexpr int TR_B = (MODE == 4) ? 0 : PASSN * TSTR * 2;
    constexpr int LDS_B = STAGE_B > TR_B ? STAGE_B : TR_B;
    constexpr int NV = POS * (CHUNK / 8);
    constexpr int NLD = (NV + BLK - 1) / BLK;
    static_assert(8 % CT == 0, "ct swizzle");
    static_assert(WNF * 2 == NF, "wnf");
    static_assert(WMF * 64 == MTILE, "wmf");
    static_assert(NCHL * CHUNK == Ci, "chunk");
    static_assert(LDS_B <= 65536, "lds");
    __shared__ char lds[LDS_B];

    const int tid = threadIdx.x;
    const int lane = tid & 63;
    const int wv = tid >> 6;
    const int wm = wv & 3, wn = wv >> 2;     // 4M x 2N
    const int g = lane >> 4, ln = lane & 15;

    const int bid = blockIdx.x;
    const int xcd = bid & 7;
    constexpr int XPC = 8 / CT;
    const int ct = xcd % CT;
    const int nt = (bid >> 3) * XPC + xcd / CT;
    const int b0 = (nt / RG) * IPB;
    const int y0 = (nt % RG) * ROWS;

    int pbase[WNF];
#pragma unroll
    for (int nf = 0; nf < WNF; nf++) {
        int n = (wn * WNF + nf) * 16 + ln;
        int img = n / (ROWS * Wout);
        int rem = n % (ROWS * Wout);
        int yr = rem / Wout, xo = rem % Wout;
        pbase[nf] = (img * PROWS + STRIDE * yr) * PW + STRIDE * xo;
    }

    // ---- precompute per-thread stage addresses (ch-invariant) ----
    const unsigned short* gsrc[NLD];
    int ldst[NLD];
#pragma unroll
    for (int j = 0; j < NLD; j++) {
        int i = tid + j * BLK;
        gsrc[j] = nullptr; ldst[j] = 0;
        if (i < NV) {
            int p = i / (CHUNK / 8), c = i % (CHUNK / 8);
            int img = p / (PROWS * PW);
            int r = p % (PROWS * PW);
            int prow = r / PW, px = r % PW;
            int yin = STRIDE * y0 - 1 + prow;
            int xin = px - 1;
            ldst[j] = p * LINE + c * 16;
            if (yin >= 0 && yin < Hin && xin >= 0 && xin < Win)
                gsrc[j] = in + (((long)(b0 + img) * Hin + yin) * Win + xin) * Ci + c * 8;
        }
    }

    f32x4 accA[WMF][WNF], accB[WMF][WNF];
#pragma unroll
    for (int mf = 0; mf < WMF; mf++)
#pragma unroll
    for (int nf = 0; nf < WNF; nf++) {
        accA[mf][nf] = (f32x4){0.f, 0.f, 0.f, 0.f};
        accB[mf][nf] = (f32x4){0.f, 0.f, 0.f, 0.f};
    }

    const unsigned short* wbase = wpk + ((long)(ct * (MTILE / 16) + wm * WMF) * 64 + lane) * 8;

    // issue chunk-0 loads
    uint4 regs[NLD];
#pragma unroll
    for (int j = 0; j < NLD; j++) {
        uint4 v; v.x = 0; v.y = 0; v.z = 0; v.w = 0;
        if (tid + j * BLK < NV && gsrc[j]) v = *(const uint4*)(gsrc[j]);
        regs[j] = v;
    }

    for (int ch = 0; ch < NCHL; ch++) {
        // ---- write chunk ch ----
#pragma unroll
        for (int j = 0; j < NLD; j++)
            if (tid + j * BLK < NV) *(uint4*)(lds + ldst[j]) = regs[j];
        __syncthreads();
        // ---- issue chunk ch+1 loads ----
        if (ch + 1 < NCHL) {
#pragma unroll
            for (int j = 0; j < NLD; j++) {
                uint4 v; v.x = 0; v.y = 0; v.z = 0; v.w = 0;
                if (tid + j * BLK < NV && gsrc[j])
                    v = *(const uint4*)(gsrc[j] + (long)(ch + 1) * CHUNK);
                regs[j] = v;
            }
        }
        // ---- compute chunk ch ----
#pragma unroll 3
        for (int pos = 0; pos < 9; pos++) {
            const int ky = pos / 3, kx = pos % 3;
#pragma unroll
            for (int ks = 0; ks < KS; ks++) {
                const int ch32 = ch * KS + ks;
                half8 af[2][WMF];
#pragma unroll
                for (int cv = 0; cv < 2; cv++)
#pragma unroll
                for (int mf = 0; mf < WMF; mf++)
                    af[cv][mf] = *(const half8*)(wbase +
                        ((long)(((cv * 9 + pos) * NCH32 + ch32) * MFg + mf)) * 512);
#pragma unroll
                for (int nf = 0; nf < WNF; nf++) {
                    int po = (pbase[nf] + ky * PW + kx) * LINE + ks * 64 + g * 16;
                    half8 b1 = *(const half8*)(lds + po);
                    half8 b2 = b1 * b1;               // v_pk_mul_f16
#pragma unroll
                    for (int mf = 0; mf < WMF; mf++) {
                        accA[mf][nf] = __builtin_amdgcn_mfma_f32_16x16x32_f16(af[0][mf], b1, accA[mf][nf], 0, 0, 0);
                        accB[mf][nf] = __builtin_amdgcn_mfma_f32_16x16x32_f16(af[1][mf], b2, accB[mf][nf], 0, 0, 0);
                    }
                }
            }
        }
        __syncthreads();
    }

    // ---- epilogue ----
    if constexpr (MODE == 4) {
        unsigned short* out = (unsigned short*)outp;
#pragma unroll
        for (int mf = 0; mf < WMF; mf++) {
            int co = ct * MTILE + (wm * WMF + mf) * 16 + g * 4;
#pragma unroll
            for (int nf = 0; nf < WNF; nf++) {
                int n = (wn * WNF + nf) * 16 + ln;
                int img = n / (ROWS * Wout), rem = n % (ROWS * Wout);
                int y = y0 + rem / Wout, x = rem % Wout;
                int b = b0 + img;
#pragma unroll
                for (int r = 0; r < 4; r++) {
                    int c = co + r;
                    float m = accA[mf][nf][r] + bias[c];
                    float v = ones_g[(c * Hout + y) * Wout + x] - accB[mf][nf][r];
                    long oi = (((long)b * Co + c) * Hout + y) * Wout + x;
                    out[oi] = f2h(m + sqrtf(v + EPSV) * epsb[oi]);
                }
            }
        }
    } else {
        unsigned short* out = (unsigned short*)outp;
#pragma unroll
        for (int pass = 0; pass < NPASS; pass++) {
            __syncthreads();
#pragma unroll
            for (int mf = 0; mf < WMF; mf++) {
                int cob = (wm * WMF + mf) * 16 + g * 4;
                int cg = ct * MTILE + cob;
#pragma unroll
                for (int nf = 0; nf < WNF; nf++) {
                    int nb = (wn * WNF + nf) * 16;
                    if (nb < pass * PASSN || nb >= (pass + 1) * PASSN) continue;
                    int n = nb + ln;
                    int img = n / (ROWS * Wout), rem = n % (ROWS * Wout);
                    int y = y0 + rem / Wout, x = rem % Wout;
                    int b = b0 + img;
                    unsigned int pk2[2];
#pragma unroll
                    for (int r = 0; r < 4; r++) {
                        int c = cg + r;
                        float m = accA[mf][nf][r] + bias[c];
                        float val;
                        if constexpr (MODE == 0) {
                            val = erff(m * rsqrtf(accB[mf][nf][r] + EPSV) * INV_SQRT2);
                        } else if constexpr (MODE == 1) {
                            float v = ones_g[(c * Hout + y) * Wout + x] - accB[mf][nf][r];
                            val = erff(m * rsqrtf(v + EPSV) * INV_SQRT2);
                        } else { // MODE 3
                            float v = ones_g[(c * Hout + y) * Wout + x] - accB[mf][nf][r];
                            float ev = epsb[(((long)b * Co + c) * Hout + y) * Wout + x];
                            val = m + sqrtf(v + EPSV) * ev;
                        }
                        unsigned int hv = f2h(val);
                        if (r & 1) pk2[r >> 1] |= hv << 16; else pk2[r >> 1] = hv;
                    }
                    int nl = n - pass * PASSN;
                    *(unsigned int*)(lds + (nl * TSTR + cob) * 2) = pk2[0];
                    *(unsigned int*)(lds + (nl * TSTR + cob) * 2 + 4) = pk2[1];
                }
            }
            __syncthreads();
            for (int i = tid; i < PASSN * (MTILE / 8); i += BLK) {
                int nl = i / (MTILE / 8);
                int n = pass * PASSN + nl;
                int c8 = (i % (MTILE / 8)) * 8;
                int img = n / (ROWS * Wout), rem = n % (ROWS * Wout);
                int y = y0 + rem / Wout, x = rem % Wout;
                int b = b0 + img;
                uint4 val = *(const uint4*)(lds + (nl * TSTR + c8) * 2);
                long oa = (((long)b * Hout + y) * Wout + x) * Co + ct * MTILE + c8;
                *(uint4*)(out + oa) = val;
            }
        }
    }
}

// ---------------------------------------------------------------------------
// BatchNorm (fp16 activations, partial-sum based, no atomics)
// ---------------------------------------------------------------------------
__global__ void bn_part_nhwc(const unsigned short* __restrict__ h, float* __restrict__ part,
                             int C, int rpc) {
    int c = threadIdx.x;
    long r0 = (long)blockIdx.x * rpc;
    float s = 0.f, s2 = 0.f;
    for (int r = 0; r < rpc; r++) {
        float v = h2f(h[(r0 + r) * C + c]);
        s += v; s2 += v * v;
    }
    part[(long)blockIdx.x * 2 * C + c] = s;
    part[(long)blockIdx.x * 2 * C + C + c] = s2;
}

__global__ void bn_part_nchw(const unsigned short* __restrict__ h, float* __restrict__ part,
                             int ipc) {
    int c = threadIdx.x;
    int b0 = blockIdx.x * ipc;
    float s = 0.f, s2 = 0.f;
    for (int b = 0; b < ipc; b++) {
        const unsigned short* p = h + ((long)(b0 + b) * 512 + c) * 16;
        uint4 v0 = *(const uint4*)p;
        uint4 v1 = *(const uint4*)(p + 8);
        unsigned int* vp0 = (unsigned int*)&v0;
        unsigned int* vp1 = (unsigned int*)&v1;
#pragma unroll
        for (int e = 0; e < 4; e++) {
            float a = h2f((unsigned short)(vp0[e] & 0xffffu)), bb = h2f((unsigned short)(vp0[e] >> 16));
            float cc = h2f((unsigned short)(vp1[e] & 0xffffu)), d = h2f((unsigned short)(vp1[e] >> 16));
            s += a + bb + cc + d;
            s2 += a * a + bb * bb + cc * cc + d * d;
        }
    }
    part[(long)blockIdx.x * 1024 + c] = s;
    part[(long)blockIdx.x * 1024 + 512 + c] = s2;
}

__global__ void bn_fin(const float* __restrict__ part, const float* __restrict__ gamma,
                       const float* __restrict__ beta, float* __restrict__ sc,
                       float* __restrict__ sh, int C, int chunks, float invN) {
    int c = blockIdx.x * 256 + threadIdx.x;
    if (c >= C) return;
    float s = 0.f, s2 = 0.f;
    for (int j = 0; j < chunks; j++) {
        s += part[(long)j * 2 * C + c];
        s2 += part[(long)j * 2 * C + C + c];
    }
    float mean = s * invN;
    float var = s2 * invN - mean * mean;
    float k = gamma[c] * rsqrtf(var + BNEPS);
    sc[c] = k;
    sh[c] = beta[c] - mean * k;
}

__global__ void bn_app_nhwc(unsigned short* __restrict__ h, const float* __restrict__ sc,
                            const float* __restrict__ sh) {
    int i = blockIdx.x * 256 + threadIdx.x;   // 2097152 total
    int cb = (i & 31) * 8;
    uint4 v = *(uint4*)(h + (long)i * 8);
    float4 s0 = *(const float4*)(sc + cb), s1 = *(const float4*)(sc + cb + 4);
    float4 t0 = *(const float4*)(sh + cb), t1 = *(const float4*)(sh + cb + 4);
    float scl[8] = {s0.x, s0.y, s0.z, s0.w, s1.x, s1.y, s1.z, s1.w};
    float shf[8] = {t0.x, t0.y, t0.z, t0.w, t1.x, t1.y, t1.z, t1.w};
    unsigned int* vp = (unsigned int*)&v;
#pragma unroll
    for (int e = 0; e < 4; e++) {
        float lo = h2f((unsigned short)(vp[e] & 0xffffu));
        float hi = h2f((unsigned short)(vp[e] >> 16));
        lo = fmaf(lo, scl[2 * e], shf[2 * e]);     lo = lo > 0.f ? lo : 0.f;
        hi = fmaf(hi, scl[2 * e + 1], shf[2 * e + 1]); hi = hi > 0.f ? hi : 0.f;
        vp[e] = (unsigned int)f2h(lo) | (((unsigned int)f2h(hi)) << 16);
    }
    *(uint4*)(h + (long)i * 8) = v;
}

__global__ void bn_app_nchw(unsigned short* __restrict__ h, const float* __restrict__ sc,
                            const float* __restrict__ sh) {
    int i = blockIdx.x * 256 + threadIdx.x;   // 524288 total
    int c = (i >> 1) & 511;
    float k = sc[c], t = sh[c];
    uint4 v = *(uint4*)(h + (long)i * 8);
    unsigned int* vp = (unsigned int*)&v;
#pragma unroll
    for (int e = 0; e < 4; e++) {
        float lo = h2f((unsigned short)(vp[e] & 0xffffu));
        float hi = h2f((unsigned short)(vp[e] >> 16));
        lo = fmaf(lo, k, t); lo = lo > 0.f ? lo : 0.f;
        hi = fmaf(hi, k, t); hi = hi > 0.f ? hi : 0.f;
        vp[e] = (unsigned int)f2h(lo) | (((unsigned int)f2h(hi)) << 16);
    }
    *(uint4*)(h + (long)i * 8) = v;
}

// ---------------------------------------------------------------------------
// FC1 fp16 MFMA split-K + reduce
// ---------------------------------------------------------------------------
__global__ __launch_bounds__(256) void fc1_mfma(const unsigned short* __restrict__ Ab,
                                                const unsigned short* __restrict__ Wp,
                                                float* __restrict__ pbuf) {
    __shared__ char lds[2 * 64 * 80];
    const int tid = threadIdx.x;
    const int lane = tid & 63;
    const int wv = tid >> 6;
    const int g = lane >> 4, ln = lane & 15;
    const int ot = blockIdx.x, bt = blockIdx.y, s = blockIdx.z;
    const int b0 = bt * 64;
    const int k0g = s * 1024;

    f32x4 acc[2][4];
#pragma unroll
    for (int c = 0; c < 2; c++)
#pragma unroll
    for (int nf = 0; nf < 4; nf++) acc[c][nf] = (f32x4){0.f, 0.f, 0.f, 0.f};

    for (int k0 = 0; k0 < 1024; k0 += 64) {
        __syncthreads();
        for (int i = tid; i < 512; i += 256) {
            int row = i >> 3, kk = (i >> 2) & 1, seg = i & 3;
            uint4 v = *(const uint4*)(Ab + ((long)(b0 + row) * 8192 + k0g + k0 + kk * 32 + seg * 8));
            *(uint4*)(lds + (kk * 64 + row) * 80 + seg * 16) = v;
        }
        __syncthreads();
#pragma unroll
        for (int kk = 0; kk < 2; kk++) {
            int kt = (k0g + k0) / 32 + kk;
            half8 af[2];
#pragma unroll
            for (int c = 0; c < 2; c++) {
                int mf = ot * 8 + wv * 2 + c;
                af[c] = *(const half8*)(Wp + (((long)kt * 64 + mf) * 64 + lane) * 8);
            }
            half8 bf[4];
#pragma unroll
            for (int nf = 0; nf < 4; nf++)
                bf[nf] = *(const half8*)(lds + (kk * 64 + nf * 16 + ln) * 80 + g * 16);
#pragma unroll
            for (int c = 0; c < 2; c++)
#pragma unroll
            for (int nf = 0; nf < 4; nf++)
                acc[c][nf] = __builtin_amdgcn_mfma_f32_16x16x32_f16(af[c], bf[nf], acc[c][nf], 0, 0, 0);
        }
    }
#pragma unroll
    for (int c = 0; c < 2; c++) {
        int o = ot * 128 + (wv * 2 + c) * 16 + g * 4;
#pragma unroll
        for (int nf = 0; nf < 4; nf++) {
            int b = b0 + nf * 16 + ln;
            *(f32x4*)(pbuf + ((long)s * 256 + b) * 1024 + o) = acc[c][nf];
        }
    }
}

__global__ void fc1_reduce(const float* __restrict__ pbuf, const float* __restrict__ bias,
                           float* __restrict__ out) {
    int idx = blockIdx.x * 256 + threadIdx.x;
    float s = 0.f;
#pragma unroll
    for (int j = 0; j < 8; j++) s += pbuf[(long)j * 262144 + idx];
    s += bias[idx & 1023];
    out[idx] = s > 0.f ? s : 0.f;
}

__global__ void fc2_k(const float* __restrict__ A, const float* __restrict__ W,
                      const float* __restrict__ b2, float* __restrict__ out) {
    int bb = blockIdx.x;
    int tid = threadIdx.x;
    float acc[10];
#pragma unroll
    for (int o = 0; o < 10; o++) acc[o] = 0.f;
    const float* arow = A + (long)bb * 1024;
    for (int k = tid; k < 1024; k += 256) {
        float a = arow[k];
#pragma unroll
        for (int o = 0; o < 10; o++) acc[o] = fmaf(a, W[o * 1024 + k], acc[o]);
    }
#pragma unroll
    for (int o = 0; o < 10; o++)
        for (int off = 32; off > 0; off >>= 1) acc[o] += __shfl_down(acc[o], off);
    __shared__ float red[10][4];
    int wid = tid >> 6, lane = tid & 63;
    if (lane == 0) {
#pragma unroll
        for (int o = 0; o < 10; o++) red[o][wid] = acc[o];
    }
    __syncthreads();
    if (tid < 10)
        out[bb * 10 + tid] = red[tid][0] + red[tid][1] + red[tid][2] + red[tid][3] + b2[tid];
}

// ---------------------------------------------------------------------------
extern "C" void kernel_launch(void* const* d_in, const int* in_sizes, int n_in,
                              void* d_out, int out_size, void* d_ws, size_t ws_size,
                              hipStream_t stream) {
    const float* x  = (const float*)d_in[0];
    const float* a1 = (const float*)d_in[1];  const float* b1 = (const float*)d_in[2];  const float* c1 = (const float*)d_in[3];
    const float* a2 = (const float*)d_in[4];  const float* b2 = (const float*)d_in[5];  const float* c2 = (const float*)d_in[6];
    const float* a3 = (const float*)d_in[7];  const float* b3 = (const float*)d_in[8];  const float* c3 = (const float*)d_in[9];
    const float* a4 = (const float*)d_in[10]; const float* b4 = (const float*)d_in[11]; const float* c4 = (const float*)d_in[12];
    const float* a5 = (const float*)d_in[13]; const float* b5 = (const float*)d_in[14]; const float* c5 = (const float*)d_in[15];
    const float* a6 = (const float*)d_in[16]; const float* b6 = (const float*)d_in[17]; const float* c6 = (const float*)d_in[18];
    const float* g3 = (const float*)d_in[19]; const float* be3 = (const float*)d_in[20];
    const float* g6 = (const float*)d_in[21]; const float* be6 = (const float*)d_in[22];
    const float* fc1w = (const float*)d_in[23]; const float* fc1b = (const float*)d_in[24];
    const float* fc2w = (const float*)d_in[25]; const float* fc2b = (const float*)d_in[26];
    const float* eps3 = (const float*)d_in[27]; const float* eps6 = (const float*)d_in[28];
    (void)in_sizes; (void)n_in; (void)out_size; (void)ws_size;

    float* w = (float*)d_ws;
    size_t off = 0;
    auto alloc = [&](size_t n) { float* p = w + off; off += n; return p; };
    unsigned short* pk2 = (unsigned short*)alloc(147456);
    unsigned short* pk3 = (unsigned short*)alloc(294912);
    unsigned short* pk4 = (unsigned short*)alloc(589824);
    unsigned short* pk5 = (unsigned short*)alloc(1179648);
    unsigned short* pk6 = (unsigned short*)alloc(2359296);
    unsigned short* pkL1 = (unsigned short*)alloc(4096);
    float* wa1 = alloc(3456); float* wb1 = alloc(3456);
    float* ss2 = alloc(1152); float* ss3 = alloc(2304);
    float* ss5 = alloc(4608); float* ss6 = alloc(4608);
    float* og2 = alloc(32768); float* og3 = alloc(65536);
    float* og5 = alloc(32768); float* og6 = alloc(8192);
    float* part3 = alloc(131072);
    float* part6 = alloc(65536);
    float* sc3 = alloc(256); float* sh3 = alloc(256);
    float* sc6 = alloc(512); float* sh6 = alloc(512);
    float* A  = alloc(16777216);
    float* Bb = alloc(4194304);
    float* Cc = alloc(8388608);
    float* Dd = alloc(2097152);
    float* Ee = alloc(4194304);

    unsigned short* ex1 = (unsigned short*)A;
    unsigned short* pkF = (unsigned short*)A;
    float*          pbuf = A + 4194304;
    unsigned short* ex2 = (unsigned short*)Bb;
    float*          fco = Bb;
    unsigned short* h6b = (unsigned short*)(Bb + 524288);
    unsigned short* colsL1 = (unsigned short*)Cc;
    unsigned short* h3b = (unsigned short*)Cc;
    unsigned short* ex4 = (unsigned short*)Dd;
    unsigned short* ex5 = (unsigned short*)Ee;

    // ---- prep ----
    prep_w<<<14, 256, 0, stream>>>(a1, b1, wa1, wb1, 3456);
    prep_packL1<<<4, 256, 0, stream>>>(wa1, wb1, pkL1);
    prep_pack<<<72,  256, 0, stream>>>(a2, b2, pk2, 128, 128, 1, 18432);
    prep_pack<<<144, 256, 0, stream>>>(a3, b3, pk3, 128, 256, 1, 36864);
    prep_pack<<<288, 256, 0, stream>>>(a4, b4, pk4, 256, 256, 0, 73728);
    prep_pack<<<576, 256, 0, stream>>>(a5, b5, pk5, 256, 512, 1, 147456);
    prep_pack<<<1152,256, 0, stream>>>(a6, b6, pk6, 512, 512, 1, 294912);
    prep_s<<<128, 64, 0, stream>>>(a2, ss2, 128);
    prep_s<<<256, 64, 0, stream>>>(a3, ss3, 128);
    prep_s<<<512, 64, 0, stream>>>(a5, ss5, 256);
    prep_s<<<512, 64, 0, stream>>>(a6, ss6, 512);
    prep_ones<<<128, 256, 0, stream>>>(ss2, og2, 128, 16, 16, 32, 32, 2, 32768);
    prep_ones<<<256, 256, 0, stream>>>(ss3, og3, 256, 16, 16, 16, 16, 1, 65536);
    prep_ones<<<128, 256, 0, stream>>>(ss5, og5, 512, 8, 8, 8, 8, 1, 32768);
    prep_ones<<<32,  256, 0, stream>>>(ss6, og6, 512, 4, 4, 8, 8, 2, 8192);

    // ---- network ----
    l1_im2col<<<1024, 256, 0, stream>>>(x, colsL1);
    conv1_mfma<<<2048, 512, 0, stream>>>(colsL1, pkL1, c1, ex1);
    // L2
    conv_mfma<128,32,32,128,16,16,2, 8,1,128,32,128,1><<<512, 512, 0, stream>>>(ex1, pk2, c2, og2, nullptr, ex2);
    // L3
    conv_mfma<128,16,16,256,16,16,1, 8,2,256,64,128,3><<<512, 512, 0, stream>>>(ex2, pk3, c3, og3, eps3, h3b);
    prep_fc1<<<4096, 256, 0, stream>>>(fc1w, pkF);
    // BN3
    bn_part_nhwc<<<256, 256, 0, stream>>>(h3b, part3, 256, 256);
    bn_fin<<<1, 256, 0, stream>>>(part3, g3, be3, sc3, sh3, 256, 256, 1.f / 65536.f);
    bn_app_nhwc<<<8192, 256, 0, stream>>>(h3b, sc3, sh3);
    // L4
    conv_mfma<256,16,16,256, 8, 8,2, 8,1,64,32,128,0><<<512, 512, 0, stream>>>(h3b, pk4, c4, nullptr, nullptr, ex4);
    // L5
    conv_mfma<256, 8, 8,512, 8, 8,1, 8,2,128,32,128,1><<<512, 512, 0, stream>>>(ex4, pk5, c5, og5, nullptr, ex5);
    // L6
    conv_mfma<512, 8, 8,512, 4, 4,2, 4,4,64,32,64,4><<<512, 512, 0, stream>>>(ex5, pk6, c6, og6, eps6, h6b);
    // BN6
    bn_part_nchw<<<64, 512, 0, stream>>>(h6b, part6, 4);
    bn_fin<<<2, 256, 0, stream>>>(part6, g6, be6, sc6, sh6, 512, 64, 1.f / 4096.f);
    bn_app_nchw<<<2048, 256, 0, stream>>>(h6b, sc6, sh6);
    // FC1 + FC2
    fc1_mfma<<<dim3(8, 4, 8), 256, 0, stream>>>(h6b, pkF, pbuf);
    fc1_reduce<<<1024, 256, 0, stream>>>(pbuf, fc1b, fco);
    fc2_k<<<256, 256, 0, stream>>>(fco, fc2w, fc2b, (float*)d_out);
}

// Round 14
// 734.084 us; speedup vs baseline: 1.4751x; 1.0139x over previous
//
#include <hip/hip_runtime.h>
#include <hip/hip_bf16.h>
#include <math.h>

#define EPSV 1e-10f
#define BNEPS 1e-5f
#define INV_SQRT2 0.70710678118654752440f

typedef __attribute__((ext_vector_type(8))) short short8;
typedef __attribute__((ext_vector_type(4))) float f32x4;
typedef _Float16 half8 __attribute__((ext_vector_type(8)));

__device__ __forceinline__ unsigned short f2h(float f) {
    _Float16 h = (_Float16)f;                      // RNE
    return __builtin_bit_cast(unsigned short, h);
}
__device__ __forceinline__ float h2f(unsigned short u) {
    _Float16 h = __builtin_bit_cast(_Float16, u);
    return (float)h;
}

// ---------------------------------------------------------------------------
// L1 weight prep (fp32)
// ---------------------------------------------------------------------------
__global__ void prep_w(const float* __restrict__ a, const float* __restrict__ b,
                       float* __restrict__ WA, float* __restrict__ WB, int n) {
    for (int i = blockIdx.x * blockDim.x + threadIdx.x; i < n; i += gridDim.x * blockDim.x) {
        float p0 = 1.f / (1.f + expf(-a[i]));
        float sb = 1.f / (1.f + expf(-b[i]));
        float p1 = (1.f - p0) * sb;
        float ew = 2.f * p1 - (1.f - p0);
        float ew2 = 1.f - p0;
        WA[i] = ew;
        WB[i] = ew2 - ew * ew;
    }
}

// L1 weights -> MFMA A-fragment order (fp16), K=32 (27 used), 2cv x 8mf
__global__ void prep_packL1(const float* __restrict__ wa, const float* __restrict__ wb,
                            unsigned short* __restrict__ pk) {
    int idx = blockIdx.x * 256 + threadIdx.x;   // 1024 total
    if (idx >= 1024) return;
    int lane = idx & 63;
    int mf = (idx >> 6) & 7;
    int cv = idx >> 9;
    int co = mf * 16 + (lane & 15);
    int k0 = (lane >> 4) * 8;
    const float* src = (cv ? wb : wa) + co * 27;
    unsigned int o[4] = {0, 0, 0, 0};
#pragma unroll
    for (int j = 0; j < 8; j++) {
        int k = k0 + j;
        if (k < 27) {
            unsigned int h = f2h(src[k]);
            o[j >> 1] |= h << ((j & 1) * 16);
        }
    }
    uint4 v; v.x = o[0]; v.y = o[1]; v.z = o[2]; v.w = o[3];
    *(uint4*)(pk + (long)idx * 8) = v;
}

// ---------------------------------------------------------------------------
// Pack ternary-stat weights into MFMA A-fragment order (fp16).
// ---------------------------------------------------------------------------
__global__ void prep_pack(const float* __restrict__ a, const float* __restrict__ b,
                          unsigned short* __restrict__ pk, int Ci, int Co, int ver2, int total) {
    int idx = blockIdx.x * 256 + threadIdx.x;
    if (idx >= total) return;
    int lane = idx & 63;
    int MFg = Co >> 4, NCH = Ci >> 5;
    int mfch = idx >> 6;
    int mf = mfch % MFg;
    int chpos = mfch / MFg;
    int ch = chpos % NCH;
    int pos = chpos / NCH;
    int co = mf * 16 + (lane & 15);
    int cib = ch * 32 + (lane >> 4) * 8;
    unsigned int wa[4], wb[4];
#pragma unroll
    for (int j = 0; j < 8; j++) {
        long s = ((long)co * Ci + cib + j) * 9 + pos;
        float p0 = 1.f / (1.f + expf(-a[s]));
        float sb = 1.f / (1.f + expf(-b[s]));
        float p1 = (1.f - p0) * sb;
        float ew = 2.f * p1 - (1.f - p0);
        float ew2 = 1.f - p0;
        unsigned int ha = f2h(ew);
        unsigned int hb = f2h(ver2 ? ew * ew : ew2 - ew * ew);
        if (j & 1) { wa[j >> 1] |= ha << 16; wb[j >> 1] |= hb << 16; }
        else       { wa[j >> 1] = ha;        wb[j >> 1] = hb; }
    }
    long b0 = (((long)(0 * 9 + pos) * NCH + ch) * MFg + mf) * 64 + lane;
    long b1 = (((long)(1 * 9 + pos) * NCH + ch) * MFg + mf) * 64 + lane;
    uint4 va; va.x = wa[0]; va.y = wa[1]; va.z = wa[2]; va.w = wa[3];
    uint4 vb; vb.x = wb[0]; vb.y = wb[1]; vb.z = wb[2]; vb.w = wb[3];
    *(uint4*)(pk + b0 * 8) = va;
    *(uint4*)(pk + b1 * 8) = vb;
}

// ssum[co][k] = sum_ci sigmoid(-alpha)
__global__ void prep_s(const float* __restrict__ alpha, float* __restrict__ s, int Ci) {
    int co = blockIdx.x;
    int lane = threadIdx.x;
    float acc[9];
#pragma unroll
    for (int k = 0; k < 9; k++) acc[k] = 0.f;
    for (int ci = lane; ci < Ci; ci += 64) {
        const float* p = alpha + ((long)co * Ci + ci) * 9;
#pragma unroll
        for (int k = 0; k < 9; k++) acc[k] += 1.f / (1.f + expf(p[k]));
    }
#pragma unroll
    for (int k = 0; k < 9; k++) {
        for (int off = 32; off > 0; off >>= 1) acc[k] += __shfl_down(acc[k], off);
    }
    if (lane == 0) {
#pragma unroll
        for (int k = 0; k < 9; k++) s[co * 9 + k] = acc[k];
    }
}

__global__ void prep_ones(const float* __restrict__ ssum, float* __restrict__ og,
                          int Co, int Hout, int Wout, int Hin, int Win, int stride, int total) {
    int idx = blockIdx.x * 256 + threadIdx.x;
    if (idx >= total) return;
    int x = idx % Wout, y = (idx / Wout) % Hout, co = idx / (Wout * Hout);
    float s = 0.f;
    for (int ky = 0; ky < 3; ky++) {
        int yi = stride * y - 1 + ky;
        if (yi < 0 || yi >= Hin) continue;
        for (int kx = 0; kx < 3; kx++) {
            int xi = stride * x - 1 + kx;
            if (xi < 0 || xi >= Win) continue;
            s += ssum[co * 9 + ky * 3 + kx];
        }
    }
    og[idx] = s;
}

// ---------------------------------------------------------------------------
// FC1 weight pack: fp32 [1024][8192] -> fp16 A-fragment order
// ---------------------------------------------------------------------------
__global__ void prep_fc1(const float* __restrict__ W, unsigned short* __restrict__ pk) {
    int idx = blockIdx.x * 256 + threadIdx.x;
    int lane = idx & 63;
    int mf = (idx >> 6) & 63;
    int kt = idx >> 12;
    int o = mf * 16 + (lane & 15);
    long k = (long)kt * 32 + (lane >> 4) * 8;
    const float* src = W + (long)o * 8192 + k;
    float4 f0 = *(const float4*)src;
    float4 f1 = *(const float4*)(src + 4);
    uint4 v;
    v.x = (unsigned)f2h(f0.x) | ((unsigned)f2h(f0.y) << 16);
    v.y = (unsigned)f2h(f0.z) | ((unsigned)f2h(f0.w) << 16);
    v.z = (unsigned)f2h(f1.x) | ((unsigned)f2h(f1.y) << 16);
    v.w = (unsigned)f2h(f1.z) | ((unsigned)f2h(f1.w) << 16);
    *(uint4*)(pk + (long)idx * 8) = v;
}

// ---------------------------------------------------------------------------
// L1 im2col: x [256,3,32,32] fp32 -> cols[n][32] fp16
// ---------------------------------------------------------------------------
__global__ void l1_im2col(const float* __restrict__ x, unsigned short* __restrict__ cols) {
    int n = blockIdx.x * 256 + threadIdx.x;   // 262144
    int b = n >> 10, y = (n >> 5) & 31, xx = n & 31;
    unsigned int o[16];
#pragma unroll
    for (int i = 0; i < 16; i++) o[i] = 0;
#pragma unroll
    for (int ci = 0; ci < 3; ci++)
#pragma unroll
    for (int ky = 0; ky < 3; ky++) {
        int yy = y - 1 + ky;
        if (yy < 0 || yy > 31) continue;
#pragma unroll
        for (int kx = 0; kx < 3; kx++) {
            int xc = xx - 1 + kx;
            if (xc < 0 || xc > 31) continue;
            float v = x[((b * 3 + ci) * 32 + yy) * 32 + xc];
            int k = ci * 9 + ky * 3 + kx;
            o[k >> 1] |= ((unsigned int)f2h(v)) << ((k & 1) * 16);
        }
    }
    uint4* dst = (uint4*)(cols + (long)n * 32);
    uint4 v0; v0.x = o[0];  v0.y = o[1];  v0.z = o[2];  v0.w = o[3];
    uint4 v1; v1.x = o[4];  v1.y = o[5];  v1.z = o[6];  v1.w = o[7];
    uint4 v2; v2.x = o[8];  v2.y = o[9];  v2.z = o[10]; v2.w = o[11];
    uint4 v3; v3.x = o[12]; v3.y = o[13]; v3.z = o[14]; v3.w = o[15];
    dst[0] = v0; dst[1] = v1; dst[2] = v2; dst[3] = v3;
}

// ---------------------------------------------------------------------------
// L1 MFMA GEMM
// ---------------------------------------------------------------------------
__global__ __launch_bounds__(512) void conv1_mfma(const unsigned short* __restrict__ cols,
        const unsigned short* __restrict__ Wp, const float* __restrict__ bias,
        unsigned short* __restrict__ out) {
    constexpr int LINE = 80;
    constexpr int TSTR = 136;
    __shared__ char lds[128 * TSTR * 2];
    const int tid = threadIdx.x, lane = tid & 63, wv = tid >> 6;
    const int wm = wv & 1, wn = wv >> 1;
    const int g = lane >> 4, ln = lane & 15;
    const long n0 = (long)blockIdx.x * 128;

    for (int i = tid; i < 128 * 4; i += 512) {
        int r = i >> 2, c = i & 3;
        uint4 v = *(const uint4*)(cols + (n0 + r) * 32 + c * 8);
        *(uint4*)(lds + r * LINE + c * 16) = v;
    }
    __syncthreads();

    half8 af[2][4];
#pragma unroll
    for (int cv = 0; cv < 2; cv++)
#pragma unroll
    for (int m = 0; m < 4; m++)
        af[cv][m] = *(const half8*)(Wp + ((long)((cv * 8 + wm * 4 + m) * 64 + lane)) * 8);

    f32x4 accA[4][2], accB[4][2];
#pragma unroll
    for (int m = 0; m < 4; m++)
#pragma unroll
    for (int nf = 0; nf < 2; nf++) {
        accA[m][nf] = (f32x4){0.f, 0.f, 0.f, 0.f};
        accB[m][nf] = (f32x4){0.f, 0.f, 0.f, 0.f};
    }
#pragma unroll
    for (int nf = 0; nf < 2; nf++) {
        int r = wn * 32 + nf * 16 + ln;
        half8 b1 = *(const half8*)(lds + r * LINE + g * 16);
        half8 b2 = b1 * b1;
#pragma unroll
        for (int m = 0; m < 4; m++) {
            accA[m][nf] = __builtin_amdgcn_mfma_f32_16x16x32_f16(af[0][m], b1, accA[m][nf], 0, 0, 0);
            accB[m][nf] = __builtin_amdgcn_mfma_f32_16x16x32_f16(af[1][m], b2, accB[m][nf], 0, 0, 0);
        }
    }
    __syncthreads();
#pragma unroll
    for (int m = 0; m < 4; m++) {
        int cob = (wm * 4 + m) * 16 + g * 4;
#pragma unroll
        for (int nf = 0; nf < 2; nf++) {
            int nl = wn * 32 + nf * 16 + ln;
            unsigned int pk2[2];
#pragma unroll
            for (int r = 0; r < 4; r++) {
                float mm = accA[m][nf][r] + bias[cob + r];
                float vv = accB[m][nf][r];
                unsigned int hv = f2h(erff(mm * rsqrtf(vv + EPSV) * INV_SQRT2));
                if (r & 1) pk2[r >> 1] |= hv << 16; else pk2[r >> 1] = hv;
            }
            *(unsigned int*)(lds + (nl * TSTR + cob) * 2) = pk2[0];
            *(unsigned int*)(lds + (nl * TSTR + cob) * 2 + 4) = pk2[1];
        }
    }
    __syncthreads();
    for (int i = tid; i < 128 * 16; i += 512) {
        int nl = i >> 4, c8 = (i & 15) * 8;
        uint4 v = *(const uint4*)(lds + (nl * TSTR + c8) * 2);
        *(uint4*)(out + (n0 + nl) * 128 + c8) = v;
    }
}

// ---------------------------------------------------------------------------
// MFMA implicit-GEMM fused LRnet conv. NHWC fp16 input. 512 thr.
// Wave split MW x (8/MW) (template): MW=2 for big-N layers (L3),
// MW=4 elsewhere (halves A-fragment L2 traffic).
// T14 async-stage kept. MODEs as before.
// ---------------------------------------------------------------------------
template<int Ci, int Hin, int Win, int Co, int Hout, int Wout, int STRIDE,
         int ROWS, int IPB, int NTILE, int CHUNK, int MTILE, int MW, int MODE>
__global__ __launch_bounds__(512) void conv_mfma(
    const unsigned short* __restrict__ in,
    const unsigned short* __restrict__ wpk,
    const float* __restrict__ bias,
    const float* __restrict__ ones_g,
    const float* __restrict__ epsb,
    void* __restrict__ outp)
{
    constexpr int BLK = 512;
    constexpr int PROWS = STRIDE * (ROWS - 1) + 3;
    constexpr int PW = Win + 2;
    constexpr int POS = IPB * PROWS * PW;
    constexpr int NCH32 = Ci / 32;
    constexpr int NCHL = Ci / CHUNK;
    constexpr int KS = CHUNK / 32;
    constexpr int MFg = Co / 16;
    constexpr int NF = NTILE / 16;
    constexpr int NW = 8 / MW;
    constexpr int WMF = MTILE / (16 * MW);
    constexpr int WNF = NF / NW;
    constexpr int CT = Co / MTILE;
    constexpr int RG = Hout / ROWS;
    constexpr int LINE = CHUNK * 2 + 16;
    constexpr int TSTR = MTILE + 8;
    constexpr int PASSN = (NTILE < 128) ? NTILE : 128;
    constexpr int NPASS = (MODE == 4) ? 0 : NTILE / PASSN;
    constexpr int STAGE_B = POS * LINE;
    constexpr int TR_B = (MODE == 4) ? 0 : PASSN * TSTR * 2;
    constexpr int LDS_B = STAGE_B > TR_B ? STAGE_B : TR_B;
    constexpr int NV = POS * (CHUNK / 8);
    constexpr int NLD = (NV + BLK - 1) / BLK;
    static_assert(8 % CT == 0, "ct swizzle");
    static_assert(WNF * NW == NF, "wnf");
    static_assert(WMF * 16 * MW == MTILE, "wmf");
    static_assert(NCHL * CHUNK == Ci, "chunk");
    static_assert(LDS_B <= 65536, "lds");
    __shared__ char lds[LDS_B];

    const int tid = threadIdx.x;
    const int lane = tid & 63;
    const int wv = tid >> 6;
    const int wm = wv % MW, wn = wv / MW;
    const int g = lane >> 4, ln = lane & 15;

    const int bid = blockIdx.x;
    const int xcd = bid & 7;
    constexpr int XPC = 8 / CT;
    const int ct = xcd % CT;
    const int nt = (bid >> 3) * XPC + xcd / CT;
    const int b0 = (nt / RG) * IPB;
    const int y0 = (nt % RG) * ROWS;

    int pbase[WNF];
#pragma unroll
    for (int nf = 0; nf < WNF; nf++) {
        int n = (wn * WNF + nf) * 16 + ln;
        int img = n / (ROWS * Wout);
        int rem = n % (ROWS * Wout);
        int yr = rem / Wout, xo = rem % Wout;
        pbase[nf] = (img * PROWS + STRIDE * yr) * PW + STRIDE * xo;
    }

    // ---- precompute per-thread stage addresses (ch-invariant) ----
    const unsigned short* gsrc[NLD];
    int ldst[NLD];
#pragma unroll
    for (int j = 0; j < NLD; j++) {
        int i = tid + j * BLK;
        gsrc[j] = nullptr; ldst[j] = 0;
        if (i < NV) {
            int p = i / (CHUNK / 8), c = i % (CHUNK / 8);
            int img = p / (PROWS * PW);
            int r = p % (PROWS * PW);
            int prow = r / PW, px = r % PW;
            int yin = STRIDE * y0 - 1 + prow;
            int xin = px - 1;
            ldst[j] = p * LINE + c * 16;
            if (yin >= 0 && yin < Hin && xin >= 0 && xin < Win)
                gsrc[j] = in + (((long)(b0 + img) * Hin + yin) * Win + xin) * Ci + c * 8;
        }
    }

    f32x4 accA[WMF][WNF], accB[WMF][WNF];
#pragma unroll
    for (int mf = 0; mf < WMF; mf++)
#pragma unroll
    for (int nf = 0; nf < WNF; nf++) {
        accA[mf][nf] = (f32x4){0.f, 0.f, 0.f, 0.f};
        accB[mf][nf] = (f32x4){0.f, 0.f, 0.f, 0.f};
    }

    const unsigned short* wbase = wpk + ((long)(ct * (MTILE / 16) + wm * WMF) * 64 + lane) * 8;

    // issue chunk-0 loads
    uint4 regs[NLD];
#pragma unroll
    for (int j = 0; j < NLD; j++) {
        uint4 v; v.x = 0; v.y = 0; v.z = 0; v.w = 0;
        if (tid + j * BLK < NV && gsrc[j]) v = *(const uint4*)(gsrc[j]);
        regs[j] = v;
    }

    for (int ch = 0; ch < NCHL; ch++) {
        // ---- write chunk ch ----
#pragma unroll
        for (int j = 0; j < NLD; j++)
            if (tid + j * BLK < NV) *(uint4*)(lds + ldst[j]) = regs[j];
        __syncthreads();
        // ---- issue chunk ch+1 loads ----
        if (ch + 1 < NCHL) {
#pragma unroll
            for (int j = 0; j < NLD; j++) {
                uint4 v; v.x = 0; v.y = 0; v.z = 0; v.w = 0;
                if (tid + j * BLK < NV && gsrc[j])
                    v = *(const uint4*)(gsrc[j] + (long)(ch + 1) * CHUNK);
                regs[j] = v;
            }
        }
        // ---- compute chunk ch ----
#pragma unroll 3
        for (int pos = 0; pos < 9; pos++) {
            const int ky = pos / 3, kx = pos % 3;
#pragma unroll
            for (int ks = 0; ks < KS; ks++) {
                const int ch32 = ch * KS + ks;
                half8 af[2][WMF];
#pragma unroll
                for (int cv = 0; cv < 2; cv++)
#pragma unroll
                for (int mf = 0; mf < WMF; mf++)
                    af[cv][mf] = *(const half8*)(wbase +
                        ((long)(((cv * 9 + pos) * NCH32 + ch32) * MFg + mf)) * 512);
#pragma unroll
                for (int nf = 0; nf < WNF; nf++) {
                    int po = (pbase[nf] + ky * PW + kx) * LINE + ks * 64 + g * 16;
                    half8 b1 = *(const half8*)(lds + po);
                    half8 b2 = b1 * b1;               // v_pk_mul_f16
#pragma unroll
                    for (int mf = 0; mf < WMF; mf++) {
                        accA[mf][nf] = __builtin_amdgcn_mfma_f32_16x16x32_f16(af[0][mf], b1, accA[mf][nf], 0, 0, 0);
                        accB[mf][nf] = __builtin_amdgcn_mfma_f32_16x16x32_f16(af[1][mf], b2, accB[mf][nf], 0, 0, 0);
                    }
                }
            }
        }
        __syncthreads();
    }

    // ---- epilogue ----
    if constexpr (MODE == 4) {
        unsigned short* out = (unsigned short*)outp;
#pragma unroll
        for (int mf = 0; mf < WMF; mf++) {
            int co = ct * MTILE + (wm * WMF + mf) * 16 + g * 4;
#pragma unroll
            for (int nf = 0; nf < WNF; nf++) {
                int n = (wn * WNF + nf) * 16 + ln;
                int img = n / (ROWS * Wout), rem = n % (ROWS * Wout);
                int y = y0 + rem / Wout, x = rem % Wout;
                int b = b0 + img;
#pragma unroll
                for (int r = 0; r < 4; r++) {
                    int c = co + r;
                    float m = accA[mf][nf][r] + bias[c];
                    float v = ones_g[(c * Hout + y) * Wout + x] - accB[mf][nf][r];
                    long oi = (((long)b * Co + c) * Hout + y) * Wout + x;
                    out[oi] = f2h(m + sqrtf(v + EPSV) * epsb[oi]);
                }
            }
        }
    } else {
        unsigned short* out = (unsigned short*)outp;
#pragma unroll
        for (int pass = 0; pass < NPASS; pass++) {
            __syncthreads();
#pragma unroll
            for (int mf = 0; mf < WMF; mf++) {
                int cob = (wm * WMF + mf) * 16 + g * 4;
                int cg = ct * MTILE + cob;
#pragma unroll
                for (int nf = 0; nf < WNF; nf++) {
                    int nb = (wn * WNF + nf) * 16;
                    if (nb < pass * PASSN || nb >= (pass + 1) * PASSN) continue;
                    int n = nb + ln;
                    int img = n / (ROWS * Wout), rem = n % (ROWS * Wout);
                    int y = y0 + rem / Wout, x = rem % Wout;
                    int b = b0 + img;
                    unsigned int pk2[2];
#pragma unroll
                    for (int r = 0; r < 4; r++) {
                        int c = cg + r;
                        float m = accA[mf][nf][r] + bias[c];
                        float val;
                        if constexpr (MODE == 0) {
                            val = erff(m * rsqrtf(accB[mf][nf][r] + EPSV) * INV_SQRT2);
                        } else if constexpr (MODE == 1) {
                            float v = ones_g[(c * Hout + y) * Wout + x] - accB[mf][nf][r];
                            val = erff(m * rsqrtf(v + EPSV) * INV_SQRT2);
                        } else { // MODE 3
                            float v = ones_g[(c * Hout + y) * Wout + x] - accB[mf][nf][r];
                            float ev = epsb[(((long)b * Co + c) * Hout + y) * Wout + x];
                            val = m + sqrtf(v + EPSV) * ev;
                        }
                        unsigned int hv = f2h(val);
                        if (r & 1) pk2[r >> 1] |= hv << 16; else pk2[r >> 1] = hv;
                    }
                    int nl = n - pass * PASSN;
                    *(unsigned int*)(lds + (nl * TSTR + cob) * 2) = pk2[0];
                    *(unsigned int*)(lds + (nl * TSTR + cob) * 2 + 4) = pk2[1];
                }
            }
            __syncthreads();
            for (int i = tid; i < PASSN * (MTILE / 8); i += BLK) {
                int nl = i / (MTILE / 8);
                int n = pass * PASSN + nl;
                int c8 = (i % (MTILE / 8)) * 8;
                int img = n / (ROWS * Wout), rem = n % (ROWS * Wout);
                int y = y0 + rem / Wout, x = rem % Wout;
                int b = b0 + img;
                uint4 val = *(const uint4*)(lds + (nl * TSTR + c8) * 2);
                long oa = (((long)b * Hout + y) * Wout + x) * Co + ct * MTILE + c8;
                *(uint4*)(out + oa) = val;
            }
        }
    }
}

// ---------------------------------------------------------------------------
// BatchNorm (fp16 activations, partial-sum based, no atomics)
// ---------------------------------------------------------------------------
__global__ void bn_part_nhwc(const unsigned short* __restrict__ h, float* __restrict__ part,
                             int C, int rpc) {
    int c = threadIdx.x;
    long r0 = (long)blockIdx.x * rpc;
    float s = 0.f, s2 = 0.f;
    for (int r = 0; r < rpc; r++) {
        float v = h2f(h[(r0 + r) * C + c]);
        s += v; s2 += v * v;
    }
    part[(long)blockIdx.x * 2 * C + c] = s;
    part[(long)blockIdx.x * 2 * C + C + c] = s2;
}

__global__ void bn_part_nchw(const unsigned short* __restrict__ h, float* __restrict__ part,
                             int ipc) {
    int c = threadIdx.x;
    int b0 = blockIdx.x * ipc;
    float s = 0.f, s2 = 0.f;
    for (int b = 0; b < ipc; b++) {
        const unsigned short* p = h + ((long)(b0 + b) * 512 + c) * 16;
        uint4 v0 = *(const uint4*)p;
        uint4 v1 = *(const uint4*)(p + 8);
        unsigned int* vp0 = (unsigned int*)&v0;
        unsigned int* vp1 = (unsigned int*)&v1;
#pragma unroll
        for (int e = 0; e < 4; e++) {
            float a = h2f((unsigned short)(vp0[e] & 0xffffu)), bb = h2f((unsigned short)(vp0[e] >> 16));
            float cc = h2f((unsigned short)(vp1[e] & 0xffffu)), d = h2f((unsigned short)(vp1[e] >> 16));
            s += a + bb + cc + d;
            s2 += a * a + bb * bb + cc * cc + d * d;
        }
    }
    part[(long)blockIdx.x * 1024 + c] = s;
    part[(long)blockIdx.x * 1024 + 512 + c] = s2;
}

__global__ void bn_fin(const float* __restrict__ part, const float* __restrict__ gamma,
                       const float* __restrict__ beta, float* __restrict__ sc,
                       float* __restrict__ sh, int C, int chunks, float invN) {
    int c = blockIdx.x * 256 + threadIdx.x;
    if (c >= C) return;
    float s = 0.f, s2 = 0.f;
    for (int j = 0; j < chunks; j++) {
        s += part[(long)j * 2 * C + c];
        s2 += part[(long)j * 2 * C + C + c];
    }
    float mean = s * invN;
    float var = s2 * invN - mean * mean;
    float k = gamma[c] * rsqrtf(var + BNEPS);
    sc[c] = k;
    sh[c] = beta[c] - mean * k;
}

__global__ void bn_app_nhwc(unsigned short* __restrict__ h, const float* __restrict__ sc,
                            const float* __restrict__ sh) {
    int i = blockIdx.x * 256 + threadIdx.x;   // 2097152 total
    int cb = (i & 31) * 8;
    uint4 v = *(uint4*)(h + (long)i * 8);
    float4 s0 = *(const float4*)(sc + cb), s1 = *(const float4*)(sc + cb + 4);
    float4 t0 = *(const float4*)(sh + cb), t1 = *(const float4*)(sh + cb + 4);
    float scl[8] = {s0.x, s0.y, s0.z, s0.w, s1.x, s1.y, s1.z, s1.w};
    float shf[8] = {t0.x, t0.y, t0.z, t0.w, t1.x, t1.y, t1.z, t1.w};
    unsigned int* vp = (unsigned int*)&v;
#pragma unroll
    for (int e = 0; e < 4; e++) {
        float lo = h2f((unsigned short)(vp[e] & 0xffffu));
        float hi = h2f((unsigned short)(vp[e] >> 16));
        lo = fmaf(lo, scl[2 * e], shf[2 * e]);     lo = lo > 0.f ? lo : 0.f;
        hi = fmaf(hi, scl[2 * e + 1], shf[2 * e + 1]); hi = hi > 0.f ? hi : 0.f;
        vp[e] = (unsigned int)f2h(lo) | (((unsigned int)f2h(hi)) << 16);
    }
    *(uint4*)(h + (long)i * 8) = v;
}

__global__ void bn_app_nchw(unsigned short* __restrict__ h, const float* __restrict__ sc,
                            const float* __restrict__ sh) {
    int i = blockIdx.x * 256 + threadIdx.x;   // 524288 total
    int c = (i >> 1) & 511;
    float k = sc[c], t = sh[c];
    uint4 v = *(uint4*)(h + (long)i * 8);
    unsigned int* vp = (unsigned int*)&v;
#pragma unroll
    for (int e = 0; e < 4; e++) {
        float lo = h2f((unsigned short)(vp[e] & 0xffffu));
        float hi = h2f((unsigned short)(vp[e] >> 16));
        lo = fmaf(lo, k, t); lo = lo > 0.f ? lo : 0.f;
        hi = fmaf(hi, k, t); hi = hi > 0.f ? hi : 0.f;
        vp[e] = (unsigned int)f2h(lo) | (((unsigned int)f2h(hi)) << 16);
    }
    *(uint4*)(h + (long)i * 8) = v;
}

// ---------------------------------------------------------------------------
// FC1 fp16 MFMA split-K + reduce
// ---------------------------------------------------------------------------
__global__ __launch_bounds__(256) void fc1_mfma(const unsigned short* __restrict__ Ab,
                                                const unsigned short* __restrict__ Wp,
                                                float* __restrict__ pbuf) {
    __shared__ char lds[2 * 64 * 80];
    const int tid = threadIdx.x;
    const int lane = tid & 63;
    const int wv = tid >> 6;
    const int g = lane >> 4, ln = lane & 15;
    const int ot = blockIdx.x, bt = blockIdx.y, s = blockIdx.z;
    const int b0 = bt * 64;
    const int k0g = s * 1024;

    f32x4 acc[2][4];
#pragma unroll
    for (int c = 0; c < 2; c++)
#pragma unroll
    for (int nf = 0; nf < 4; nf++) acc[c][nf] = (f32x4){0.f, 0.f, 0.f, 0.f};

    for (int k0 = 0; k0 < 1024; k0 += 64) {
        __syncthreads();
        for (int i = tid; i < 512; i += 256) {
            int row = i >> 3, kk = (i >> 2) & 1, seg = i & 3;
            uint4 v = *(const uint4*)(Ab + ((long)(b0 + row) * 8192 + k0g + k0 + kk * 32 + seg * 8));
            *(uint4*)(lds + (kk * 64 + row) * 80 + seg * 16) = v;
        }
        __syncthreads();
#pragma unroll
        for (int kk = 0; kk < 2; kk++) {
            int kt = (k0g + k0) / 32 + kk;
            half8 af[2];
#pragma unroll
            for (int c = 0; c < 2; c++) {
                int mf = ot * 8 + wv * 2 + c;
                af[c] = *(const half8*)(Wp + (((long)kt * 64 + mf) * 64 + lane) * 8);
            }
            half8 bf[4];
#pragma unroll
            for (int nf = 0; nf < 4; nf++)
                bf[nf] = *(const half8*)(lds + (kk * 64 + nf * 16 + ln) * 80 + g * 16);
#pragma unroll
            for (int c = 0; c < 2; c++)
#pragma unroll
            for (int nf = 0; nf < 4; nf++)
                acc[c][nf] = __builtin_amdgcn_mfma_f32_16x16x32_f16(af[c], bf[nf], acc[c][nf], 0, 0, 0);
        }
    }
#pragma unroll
    for (int c = 0; c < 2; c++) {
        int o = ot * 128 + (wv * 2 + c) * 16 + g * 4;
#pragma unroll
        for (int nf = 0; nf < 4; nf++) {
            int b = b0 + nf * 16 + ln;
            *(f32x4*)(pbuf + ((long)s * 256 + b) * 1024 + o) = acc[c][nf];
        }
    }
}

__global__ void fc1_reduce(const float* __restrict__ pbuf, const float* __restrict__ bias,
                           float* __restrict__ out) {
    int idx = blockIdx.x * 256 + threadIdx.x;
    float s = 0.f;
#pragma unroll
    for (int j = 0; j < 8; j++) s += pbuf[(long)j * 262144 + idx];
    s += bias[idx & 1023];
    out[idx] = s > 0.f ? s : 0.f;
}

__global__ void fc2_k(const float* __restrict__ A, const float* __restrict__ W,
                      const float* __restrict__ b2, float* __restrict__ out) {
    int bb = blockIdx.x;
    int tid = threadIdx.x;
    float acc[10];
#pragma unroll
    for (int o = 0; o < 10; o++) acc[o] = 0.f;
    const float* arow = A + (long)bb * 1024;
    for (int k = tid; k < 1024; k += 256) {
        float a = arow[k];
#pragma unroll
        for (int o = 0; o < 10; o++) acc[o] = fmaf(a, W[o * 1024 + k], acc[o]);
    }
#pragma unroll
    for (int o = 0; o < 10; o++)
        for (int off = 32; off > 0; off >>= 1) acc[o] += __shfl_down(acc[o], off);
    __shared__ float red[10][4];
    int wid = tid >> 6, lane = tid & 63;
    if (lane == 0) {
#pragma unroll
        for (int o = 0; o < 10; o++) red[o][wid] = acc[o];
    }
    __syncthreads();
    if (tid < 10)
        out[bb * 10 + tid] = red[tid][0] + red[tid][1] + red[tid][2] + red[tid][3] + b2[tid];
}

// ---------------------------------------------------------------------------
extern "C" void kernel_launch(void* const* d_in, const int* in_sizes, int n_in,
                              void* d_out, int out_size, void* d_ws, size_t ws_size,
                              hipStream_t stream) {
    const float* x  = (const float*)d_in[0];
    const float* a1 = (const float*)d_in[1];  const float* b1 = (const float*)d_in[2];  const float* c1 = (const float*)d_in[3];
    const float* a2 = (const float*)d_in[4];  const float* b2 = (const float*)d_in[5];  const float* c2 = (const float*)d_in[6];
    const float* a3 = (const float*)d_in[7];  const float* b3 = (const float*)d_in[8];  const float* c3 = (const float*)d_in[9];
    const float* a4 = (const float*)d_in[10]; const float* b4 = (const float*)d_in[11]; const float* c4 = (const float*)d_in[12];
    const float* a5 = (const float*)d_in[13]; const float* b5 = (const float*)d_in[14]; const float* c5 = (const float*)d_in[15];
    const float* a6 = (const float*)d_in[16]; const float* b6 = (const float*)d_in[17]; const float* c6 = (const float*)d_in[18];
    const float* g3 = (const float*)d_in[19]; const float* be3 = (const float*)d_in[20];
    const float* g6 = (const float*)d_in[21]; const float* be6 = (const float*)d_in[22];
    const float* fc1w = (const float*)d_in[23]; const float* fc1b = (const float*)d_in[24];
    const float* fc2w = (const float*)d_in[25]; const float* fc2b = (const float*)d_in[26];
    const float* eps3 = (const float*)d_in[27]; const float* eps6 = (const float*)d_in[28];
    (void)in_sizes; (void)n_in; (void)out_size; (void)ws_size;

    float* w = (float*)d_ws;
    size_t off = 0;
    auto alloc = [&](size_t n) { float* p = w + off; off += n; return p; };
    unsigned short* pk2 = (unsigned short*)alloc(147456);
    unsigned short* pk3 = (unsigned short*)alloc(294912);
    unsigned short* pk4 = (unsigned short*)alloc(589824);
    unsigned short* pk5 = (unsigned short*)alloc(1179648);
    unsigned short* pk6 = (unsigned short*)alloc(2359296);
    unsigned short* pkL1 = (unsigned short*)alloc(4096);
    float* wa1 = alloc(3456); float* wb1 = alloc(3456);
    float* ss2 = alloc(1152); float* ss3 = alloc(2304);
    float* ss5 = alloc(4608); float* ss6 = alloc(4608);
    float* og2 = alloc(32768); float* og3 = alloc(65536);
    float* og5 = alloc(32768); float* og6 = alloc(8192);
    float* part3 = alloc(131072);
    float* part6 = alloc(65536);
    float* sc3 = alloc(256); float* sh3 = alloc(256);
    float* sc6 = alloc(512); float* sh6 = alloc(512);
    float* A  = alloc(16777216);
    float* Bb = alloc(4194304);
    float* Cc = alloc(8388608);
    float* Dd = alloc(2097152);
    float* Ee = alloc(4194304);

    unsigned short* ex1 = (unsigned short*)A;
    unsigned short* pkF = (unsigned short*)A;
    float*          pbuf = A + 4194304;
    unsigned short* ex2 = (unsigned short*)Bb;
    float*          fco = Bb;
    unsigned short* h6b = (unsigned short*)(Bb + 524288);
    unsigned short* colsL1 = (unsigned short*)Cc;
    unsigned short* h3b = (unsigned short*)Cc;
    unsigned short* ex4 = (unsigned short*)Dd;
    unsigned short* ex5 = (unsigned short*)Ee;

    // ---- prep ----
    prep_w<<<14, 256, 0, stream>>>(a1, b1, wa1, wb1, 3456);
    prep_packL1<<<4, 256, 0, stream>>>(wa1, wb1, pkL1);
    prep_pack<<<72,  256, 0, stream>>>(a2, b2, pk2, 128, 128, 1, 18432);
    prep_pack<<<144, 256, 0, stream>>>(a3, b3, pk3, 128, 256, 1, 36864);
    prep_pack<<<288, 256, 0, stream>>>(a4, b4, pk4, 256, 256, 0, 73728);
    prep_pack<<<576, 256, 0, stream>>>(a5, b5, pk5, 256, 512, 1, 147456);
    prep_pack<<<1152,256, 0, stream>>>(a6, b6, pk6, 512, 512, 1, 294912);
    prep_s<<<128, 64, 0, stream>>>(a2, ss2, 128);
    prep_s<<<256, 64, 0, stream>>>(a3, ss3, 128);
    prep_s<<<512, 64, 0, stream>>>(a5, ss5, 256);
    prep_s<<<512, 64, 0, stream>>>(a6, ss6, 512);
    prep_ones<<<128, 256, 0, stream>>>(ss2, og2, 128, 16, 16, 32, 32, 2, 32768);
    prep_ones<<<256, 256, 0, stream>>>(ss3, og3, 256, 16, 16, 16, 16, 1, 65536);
    prep_ones<<<128, 256, 0, stream>>>(ss5, og5, 512, 8, 8, 8, 8, 1, 32768);
    prep_ones<<<32,  256, 0, stream>>>(ss6, og6, 512, 4, 4, 8, 8, 2, 8192);

    // ---- network ----
    l1_im2col<<<1024, 256, 0, stream>>>(x, colsL1);
    conv1_mfma<<<2048, 512, 0, stream>>>(colsL1, pkL1, c1, ex1);
    // L2  (MW=4)
    conv_mfma<128,32,32,128,16,16,2, 8,1,128,32,128,4,1><<<512, 512, 0, stream>>>(ex1, pk2, c2, og2, nullptr, ex2);
    // L3  (MW=2: big-N layer, proven r12 config)
    conv_mfma<128,16,16,256,16,16,1, 8,2,256,64,128,2,3><<<512, 512, 0, stream>>>(ex2, pk3, c3, og3, eps3, h3b);
    prep_fc1<<<4096, 256, 0, stream>>>(fc1w, pkF);
    // BN3
    bn_part_nhwc<<<256, 256, 0, stream>>>(h3b, part3, 256, 256);
    bn_fin<<<1, 256, 0, stream>>>(part3, g3, be3, sc3, sh3, 256, 256, 1.f / 65536.f);
    bn_app_nhwc<<<8192, 256, 0, stream>>>(h3b, sc3, sh3);
    // L4  (MW=4)
    conv_mfma<256,16,16,256, 8, 8,2, 8,1,64,32,128,4,0><<<512, 512, 0, stream>>>(h3b, pk4, c4, nullptr, nullptr, ex4);
    // L5  (MW=4)
    conv_mfma<256, 8, 8,512, 8, 8,1, 8,2,128,32,128,4,1><<<512, 512, 0, stream>>>(ex4, pk5, c5, og5, nullptr, ex5);
    // L6  (MW=4)
    conv_mfma<512, 8, 8,512, 4, 4,2, 4,4,64,32,64,4,4><<<512, 512, 0, stream>>>(ex5, pk6, c6, og6, eps6, h6b);
    // BN6
    bn_part_nchw<<<64, 512, 0, stream>>>(h6b, part6, 4);
    bn_fin<<<2, 256, 0, stream>>>(part6, g6, be6, sc6, sh6, 512, 64, 1.f / 4096.f);
    bn_app_nchw<<<2048, 256, 0, stream>>>(h6b, sc6, sh6);
    // FC1 + FC2
    fc1_mfma<<<dim3(8, 4, 8), 256, 0, stream>>>(h6b, pkF, pbuf);
    fc1_reduce<<<1024, 256, 0, stream>>>(pbuf, fc1b, fco);
    fc2_k<<<256, 256, 0, stream>>>(fco, fc2w, fc2b, (float*)d_out);
}